// Round 2
// baseline (875.333 us; speedup 1.0000x reference)
//
#include <hip/hip_runtime.h>
#include <cstdint>
#include <cstddef>

#define NNODES 50000
#define NEDGES 800000
#define DH1    256   // H*HID = 4*64
#define DOUT   128

typedef unsigned short u16;

__device__ __forceinline__ float bf2f(unsigned int u) {
  union { unsigned int i; float f; } x; x.i = u << 16; return x.f;
}
__device__ __forceinline__ u16 f2bf(float f) {
  union { float f; unsigned int i; } x; x.f = f;
  unsigned int r = x.i + 0x7fffu + ((x.i >> 16) & 1u);  // round-to-nearest-even
  return (u16)(r >> 16);
}

// ---------------- CSR build ----------------

__global__ __launch_bounds__(256) void count_k(const int* __restrict__ dst, int* __restrict__ cnt) {
  int e = blockIdx.x * 256 + threadIdx.x;
  if (e < NEDGES) atomicAdd(&cnt[dst[e]], 1);
}

__global__ __launch_bounds__(256) void offsets_k(const int* __restrict__ cnt, int* __restrict__ offs,
                                                 int* __restrict__ cursor, int* __restrict__ total) {
  int i = blockIdx.x * 256 + threadIdx.x;
  int lane = threadIdx.x & 63;
  int c = (i < NNODES) ? cnt[i] : 0;
  int incl = c;
  #pragma unroll
  for (int d = 1; d < 64; d <<= 1) {
    int t = __shfl_up(incl, d, 64);
    if (lane >= d) incl += t;
  }
  int wtotal = __shfl(incl, 63, 64);
  int base = 0;
  if (lane == 63) base = atomicAdd(total, wtotal);
  base = __shfl(base, 63, 64);
  int off = base + incl - c;
  if (i < NNODES) { offs[i] = off; cursor[i] = off; }
}

__global__ __launch_bounds__(256) void scatter_k(const int* __restrict__ src, const int* __restrict__ dst,
                                                 const float* __restrict__ ea, int* __restrict__ cursor,
                                                 int* __restrict__ esrc, float* __restrict__ eattr) {
  int e = blockIdx.x * 256 + threadIdx.x;
  if (e >= NEDGES) return;
  int d = dst[e];
  int p = atomicAdd(&cursor[d], 1);
  esrc[p] = src[e];
  eattr[p] = ea[e];
}

// ---------------- GEMM: C0|C1 = A @ [W0|W1] + [B0|B1] ----------------
// A [M,K] f32 row-major; W0 [K,NH], W1 [K,NTOT-NH] f32; thread = 4 cols x 8 rows.

template<int K, int NH, int NTOT, bool OUT_BF16>
__global__ __launch_bounds__(256) void gemm_dual(
    const float* __restrict__ A, int M,
    const float* __restrict__ W0, const float* __restrict__ B0,
    const float* __restrict__ W1, const float* __restrict__ B1,
    void* __restrict__ C0v, void* __restrict__ C1v) {
  constexpr int CG = NTOT / 4;
  constexpr int RG = 256 / CG;
  constexpr int ROWS = RG * 8;
  constexpr int LD1c = (NTOT - NH) > 0 ? (NTOT - NH) : 1;
  __shared__ float xs[ROWS * K];
  const int row0 = blockIdx.x * ROWS;
  for (int idx = threadIdx.x; idx < ROWS * K; idx += 256) {
    int r = idx / K, k = idx - r * K;
    int gr = row0 + r;
    xs[idx] = (gr < M) ? A[(size_t)gr * K + k] : 0.0f;
  }
  __syncthreads();
  const int cg = threadIdx.x % CG;
  const int rg = threadIdx.x / CG;
  const int c0 = cg * 4;
  const bool first = (c0 < NH);
  const float* Wp = first ? (W0 + c0) : (W1 + (c0 - NH));
  const int LD = first ? NH : LD1c;
  float acc[8][4];
  #pragma unroll
  for (int r = 0; r < 8; ++r)
    #pragma unroll
    for (int j = 0; j < 4; ++j) acc[r][j] = 0.f;
  const float* xrow = &xs[rg * 8 * K];
  for (int k = 0; k < K; ++k) {
    float4 w = *reinterpret_cast<const float4*>(Wp + (size_t)k * LD);
    #pragma unroll
    for (int r = 0; r < 8; ++r) {
      float xv = xrow[r * K + k];
      acc[r][0] += xv * w.x; acc[r][1] += xv * w.y;
      acc[r][2] += xv * w.z; acc[r][3] += xv * w.w;
    }
  }
  const float* Bp = first ? (B0 + c0) : (B1 + (c0 - NH));
  float4 bs = *reinterpret_cast<const float4*>(Bp);
  #pragma unroll
  for (int r = 0; r < 8; ++r) {
    int gr = row0 + rg * 8 + r;
    if (gr >= M) continue;
    float o0 = acc[r][0] + bs.x, o1 = acc[r][1] + bs.y;
    float o2 = acc[r][2] + bs.z, o3 = acc[r][3] + bs.w;
    if constexpr (OUT_BF16) {
      u16* C = first ? ((u16*)C0v + (size_t)gr * NH + c0)
                     : ((u16*)C1v + (size_t)gr * LD1c + (c0 - NH));
      uint2 pk;
      pk.x = (unsigned)f2bf(o0) | ((unsigned)f2bf(o1) << 16);
      pk.y = (unsigned)f2bf(o2) | ((unsigned)f2bf(o3) << 16);
      *reinterpret_cast<uint2*>(C) = pk;
    } else {
      float* C = first ? ((float*)C0v + (size_t)gr * NH + c0)
                       : ((float*)C1v + (size_t)gr * LD1c + (c0 - NH));
      float4 st; st.x = o0; st.y = o1; st.z = o2; st.w = o3;
      *reinterpret_cast<float4*>(C) = st;
    }
  }
}

// ---------------- fused GATv2 edge pass: one wave per destination node ----------------
// xl/xr stored bf16; att/We/cb read f32 directly from inputs.

template<int HEADS, int CHAN, bool OUTBF>
__global__ __launch_bounds__(256) void gat_edge(
    const int* __restrict__ offs, const int* __restrict__ cnt,
    const int* __restrict__ esrc, const float* __restrict__ eattr,
    const u16* __restrict__ xl, const u16* __restrict__ xr,
    const float* __restrict__ att, const float* __restrict__ We,
    const float* __restrict__ cb, void* __restrict__ houtv) {
  constexpr int HC = HEADS * CHAN;
  constexpr int EPL = HC / 64;       // elements per lane (4 or 2)
  constexpr int GRP = 64 / HEADS;    // lanes per head group (16 or 64)
  static_assert(EPL * 64 == HC, "layout");
  int node = __builtin_amdgcn_readfirstlane((int)(blockIdx.x * 4 + (threadIdx.x >> 6)));
  if (node >= NNODES) return;
  const int lane = threadIdx.x & 63;
  const int base_c = lane * EPL;
  float xrv[EPL], attv[EPL], wev[EPL];
  #pragma unroll
  for (int j = 0; j < EPL; ++j) {
    xrv[j]  = bf2f(xl != xr ? xr[(size_t)node * HC + base_c + j] : 0);  // placeholder avoided below
  }
  #pragma unroll
  for (int j = 0; j < EPL; ++j) {
    xrv[j]  = bf2f(xr[(size_t)node * HC + base_c + j]);
    attv[j] = att[base_c + j];
    wev[j]  = We[base_c + j];
  }
  const int off = __builtin_amdgcn_readfirstlane(offs[node]);
  const int deg = __builtin_amdgcn_readfirstlane(cnt[node]);

  // pass 1: softmax denominator per head (replicated across the head's lanes)
  float den = 0.f;
  for (int j = 0; j < deg; ++j) {
    int s = esrc[off + j];
    float ea = eattr[off + j];
    float xlv[EPL];
    const u16* xp = xl + (size_t)s * HC + base_c;
    if constexpr (EPL == 4) {
      uint2 raw = *reinterpret_cast<const uint2*>(xp);
      xlv[0] = bf2f(raw.x & 0xffffu); xlv[1] = bf2f(raw.x >> 16);
      xlv[2] = bf2f(raw.y & 0xffffu); xlv[3] = bf2f(raw.y >> 16);
    } else {
      unsigned raw = *reinterpret_cast<const unsigned*>(xp);
      xlv[0] = bf2f(raw & 0xffffu); xlv[1] = bf2f(raw >> 16);
    }
    float part = 0.f;
    #pragma unroll
    for (int jj = 0; jj < EPL; ++jj) {
      float m = xlv[jj] + xrv[jj] + ea * wev[jj];
      m = m > 0.f ? m : 0.2f * m;
      part += m * attv[jj];
    }
    #pragma unroll
    for (int d = 1; d < GRP; d <<= 1) part += __shfl_xor(part, d, 64);
    den += __expf(part);
  }
  float inv = 1.0f / (den + 1e-16f);

  // pass 2: recompute score (xl gather needed anyway), aggregate
  float accv[EPL];
  #pragma unroll
  for (int j = 0; j < EPL; ++j) accv[j] = 0.f;
  for (int j = 0; j < deg; ++j) {
    int s = esrc[off + j];
    float ea = eattr[off + j];
    float xlv[EPL];
    const u16* xp = xl + (size_t)s * HC + base_c;
    if constexpr (EPL == 4) {
      uint2 raw = *reinterpret_cast<const uint2*>(xp);
      xlv[0] = bf2f(raw.x & 0xffffu); xlv[1] = bf2f(raw.x >> 16);
      xlv[2] = bf2f(raw.y & 0xffffu); xlv[3] = bf2f(raw.y >> 16);
    } else {
      unsigned raw = *reinterpret_cast<const unsigned*>(xp);
      xlv[0] = bf2f(raw & 0xffffu); xlv[1] = bf2f(raw >> 16);
    }
    float part = 0.f;
    #pragma unroll
    for (int jj = 0; jj < EPL; ++jj) {
      float m = xlv[jj] + xrv[jj] + ea * wev[jj];
      m = m > 0.f ? m : 0.2f * m;
      part += m * attv[jj];
    }
    #pragma unroll
    for (int d = 1; d < GRP; d <<= 1) part += __shfl_xor(part, d, 64);
    float alpha = __expf(part) * inv;
    #pragma unroll
    for (int jj = 0; jj < EPL; ++jj) accv[jj] += alpha * xlv[jj];
  }
  #pragma unroll
  for (int j = 0; j < EPL; ++j) accv[j] += cb[base_c + j];
  if constexpr (OUTBF) {
    u16* hout = (u16*)houtv + (size_t)node * HC + base_c;
    if constexpr (EPL == 4) {
      uint2 pk;
      pk.x = (unsigned)f2bf(accv[0]) | ((unsigned)f2bf(accv[1]) << 16);
      pk.y = (unsigned)f2bf(accv[2]) | ((unsigned)f2bf(accv[3]) << 16);
      *reinterpret_cast<uint2*>(hout) = pk;
    } else {
      unsigned pk = (unsigned)f2bf(accv[0]) | ((unsigned)f2bf(accv[1]) << 16);
      *reinterpret_cast<unsigned*>(hout) = pk;
    }
  } else {
    float* hout = (float*)houtv + (size_t)node * HC + base_c;
    if constexpr (EPL == 4) {
      float4 st; st.x = accv[0]; st.y = accv[1]; st.z = accv[2]; st.w = accv[3];
      *reinterpret_cast<float4*>(hout) = st;
    } else {
      float2 st; st.x = accv[0]; st.y = accv[1];
      *reinterpret_cast<float2*>(hout) = st;
    }
  }
}

// ---------------- BatchNorm ----------------

template<int NC>
__global__ void bn_stats_bf(const u16* __restrict__ h, float* __restrict__ sum, float* __restrict__ sq) {
  int c = threadIdx.x;
  float s = 0.f, q = 0.f;
  for (int r = blockIdx.x; r < NNODES; r += gridDim.x) {
    float v = bf2f(h[(size_t)r * NC + c]);
    s += v; q += v * v;
  }
  atomicAdd(&sum[c], s);
  atomicAdd(&sq[c], q);
}

template<int NC>
__global__ void bn_stats_f(const float* __restrict__ h, float* __restrict__ sum, float* __restrict__ sq) {
  int c = threadIdx.x;
  float s = 0.f, q = 0.f;
  for (int r = blockIdx.x; r < NNODES; r += gridDim.x) {
    float v = h[(size_t)r * NC + c];
    s += v; q += v * v;
  }
  atomicAdd(&sum[c], s);
  atomicAdd(&sq[c], q);
}

template<int NC>
__global__ void bn_fin(const float* __restrict__ sum, const float* __restrict__ sq,
                       const float* __restrict__ g, const float* __restrict__ b,
                       float* __restrict__ scale, float* __restrict__ shift) {
  int c = threadIdx.x;
  float mu = sum[c] / (float)NNODES;
  float var = sq[c] / (float)NNODES - mu * mu;
  float sc = g[c] * rsqrtf(var + 1e-5f);
  scale[c] = sc;
  shift[c] = b[c] - mu * sc;
}

// h (bf16) -> BN -> PReLU -> bf16 out
template<int NC>
__global__ __launch_bounds__(256) void bn_prelu_apply(
    const u16* __restrict__ h, const float* __restrict__ scale, const float* __restrict__ shift,
    const float* __restrict__ pap, u16* __restrict__ outp, int total) {
  int i = (blockIdx.x * 256 + threadIdx.x) * 4;
  if (i >= total) return;
  float pa = pap[0];
  int c = i & (NC - 1);
  uint2 raw = *reinterpret_cast<const uint2*>(h + i);
  float v0 = bf2f(raw.x & 0xffffu), v1 = bf2f(raw.x >> 16);
  float v2 = bf2f(raw.y & 0xffffu), v3 = bf2f(raw.y >> 16);
  float4 sc = *reinterpret_cast<const float4*>(scale + c);
  float4 sh = *reinterpret_cast<const float4*>(shift + c);
  float o0 = v0 * sc.x + sh.x; o0 = o0 > 0.f ? o0 : pa * o0;
  float o1 = v1 * sc.y + sh.y; o1 = o1 > 0.f ? o1 : pa * o1;
  float o2 = v2 * sc.z + sh.z; o2 = o2 > 0.f ? o2 : pa * o2;
  float o3 = v3 * sc.w + sh.w; o3 = o3 > 0.f ? o3 : pa * o3;
  uint2 pk;
  pk.x = (unsigned)f2bf(o0) | ((unsigned)f2bf(o1) << 16);
  pk.y = (unsigned)f2bf(o2) | ((unsigned)f2bf(o3) << 16);
  *reinterpret_cast<uint2*>(outp + i) = pk;
}

__global__ __launch_bounds__(256) void final_out_k(
    const float* __restrict__ h2, const float* __restrict__ skip,
    const float* __restrict__ scale, const float* __restrict__ shift,
    const float* __restrict__ pap, float* __restrict__ outp, int total) {
  int i = (blockIdx.x * 256 + threadIdx.x) * 4;
  if (i >= total) return;
  float pa = pap[0];
  int c = i & 127;
  float4 v  = *reinterpret_cast<const float4*>(h2 + i);
  float4 sk = *reinterpret_cast<const float4*>(skip + i);
  float4 sc = *reinterpret_cast<const float4*>(scale + c);
  float4 sh = *reinterpret_cast<const float4*>(shift + c);
  float4 o;
  o.x = v.x * sc.x + sh.x; o.x = (o.x > 0.f ? o.x : pa * o.x) + sk.x;
  o.y = v.y * sc.y + sh.y; o.y = (o.y > 0.f ? o.y : pa * o.y) + sk.y;
  o.z = v.z * sc.z + sh.z; o.z = (o.z > 0.f ? o.z : pa * o.z) + sk.z;
  o.w = v.w * sc.w + sh.w; o.w = (o.w > 0.f ? o.w : pa * o.w) + sk.w;
  *reinterpret_cast<float4*>(outp + i) = o;
}

// ---------------- launch ----------------

extern "C" void kernel_launch(void* const* d_in, const int* in_sizes, int n_in,
                              void* d_out, int out_size, void* d_ws, size_t ws_size,
                              hipStream_t stream) {
  (void)in_sizes; (void)n_in; (void)out_size; (void)ws_size;
  const float* x    = (const float*)d_in[0];
  const int*   ei   = (const int*)d_in[1];
  const float* ea   = (const float*)d_in[2];
  const float* Wl1  = (const float*)d_in[3];
  const float* bl1  = (const float*)d_in[4];
  const float* Wr1  = (const float*)d_in[5];
  const float* br1  = (const float*)d_in[6];
  const float* We1  = (const float*)d_in[7];
  const float* att1 = (const float*)d_in[8];
  const float* cb1  = (const float*)d_in[9];
  const float* bng1 = (const float*)d_in[10];
  const float* bnb1 = (const float*)d_in[11];
  const float* pa   = (const float*)d_in[12];
  const float* Wl2  = (const float*)d_in[13];
  const float* bl2  = (const float*)d_in[14];
  const float* Wr2  = (const float*)d_in[15];
  const float* br2  = (const float*)d_in[16];
  const float* We2  = (const float*)d_in[17];
  const float* att2 = (const float*)d_in[18];
  const float* cb2  = (const float*)d_in[19];
  const float* bng2 = (const float*)d_in[20];
  const float* bnb2 = (const float*)d_in[21];
  const float* skW  = (const float*)d_in[22];
  const float* skb  = (const float*)d_in[23];
  const int* srcp = ei;
  const int* dstp = ei + NEDGES;

  char* base = (char*)d_ws;
  size_t off = 0;
  auto alloc = [&](size_t bytes) -> char* {
    char* p = base + off;
    off = (off + bytes + 255) & ~(size_t)255;
    return p;
  };
  size_t zero_ints = 1 + NNODES + 256 + 256 + 128 + 128;
  char* zbase = alloc(zero_ints * 4);
  int*   totalp = (int*)zbase;
  int*   cnt    = totalp + 1;
  float* bnsum1 = (float*)(cnt + NNODES);
  float* bnsq1  = bnsum1 + 256;
  float* bnsum2 = bnsq1 + 256;
  float* bnsq2  = bnsum2 + 128;

  int*   offs    = (int*)alloc((size_t)NNODES * 4);
  int*   cursor  = (int*)alloc((size_t)NNODES * 4);
  int*   esrc    = (int*)alloc((size_t)NEDGES * 4);
  float* eattrp  = (float*)alloc((size_t)NEDGES * 4);
  // three 25.6MB regions, sequentially reused:
  const size_t RBYTES = (size_t)NNODES * DH1 * 2;  // 25.6 MB
  char* regionA = alloc(RBYTES);   // xl1 (bf16) -> h1p (bf16) -> h2 (f32)
  char* regionB = alloc(RBYTES);   // xr1 (bf16) -> skipbuf (f32)
  char* regionC = alloc(RBYTES);   // h1 (bf16)  -> xl2+xr2 (bf16)
  float* bnscale1 = (float*)alloc(256 * 4);
  float* bnshift1 = (float*)alloc(256 * 4);
  float* bnscale2 = (float*)alloc(128 * 4);
  float* bnshift2 = (float*)alloc(128 * 4);

  u16*   xl1     = (u16*)regionA;
  u16*   xr1     = (u16*)regionB;
  u16*   h1      = (u16*)regionC;
  u16*   h1p     = (u16*)regionA;
  u16*   xl2     = (u16*)regionC;
  u16*   xr2     = (u16*)(regionC + (size_t)NNODES * DOUT * 2);
  float* skipbuf = (float*)regionB;
  float* h2      = (float*)regionA;

  hipMemsetAsync(zbase, 0, zero_ints * 4, stream);

  const int EB = (NEDGES + 255) / 256;
  const int NB = (NNODES + 255) / 256;
  count_k<<<EB, 256, 0, stream>>>(dstp, cnt);
  offsets_k<<<NB, 256, 0, stream>>>(cnt, offs, cursor, totalp);
  scatter_k<<<EB, 256, 0, stream>>>(srcp, dstp, ea, cursor, esrc, eattrp);

  // layer 1: xl1|xr1 = x @ [Wl1|Wr1] + [bl1|br1]   (bf16 out)
  gemm_dual<128, 256, 512, true><<<(NNODES + 15) / 16, 256, 0, stream>>>(
      x, NNODES, Wl1, bl1, Wr1, br1, (void*)xl1, (void*)xr1);
  gat_edge<4, 64, true><<<(NNODES + 3) / 4, 256, 0, stream>>>(
      offs, cnt, esrc, eattrp, xl1, xr1, att1, We1, cb1, (void*)h1);
  bn_stats_bf<256><<<800, 256, 0, stream>>>(h1, bnsum1, bnsq1);
  bn_fin<256><<<1, 256, 0, stream>>>(bnsum1, bnsq1, bng1, bnb1, bnscale1, bnshift1);
  bn_prelu_apply<256><<<(NNODES * DH1 / 4 + 255) / 256, 256, 0, stream>>>(
      h1, bnscale1, bnshift1, pa, h1p, NNODES * DH1);

  // layer 2: xl2|xr2 = h1p_f32view @ [Wl2|Wr2] + [bl2|br2]
  // (h1p is bf16; gemm_dual wants f32 A — use a bf16-A variant via a small shim GEMM)
  // Simplest correct path: expand h1p to f32 on the fly inside gemm via template? ->
  // we instead run the same gemm with a bf16 A loader (see gemm_dual_bf below).
  // layer 2 GEMM (bf16 A):
  {
    // reuse gemm_dual with f32 A is not possible; launch bf16-A version
  }
  // skip GEMM (f32 in, f32 out) into regionB
  // ordering: layer2 gemm first (reads h1p in A, writes C), then skip (writes B), then edge pass

  // --- layer 2 GEMM with bf16 A ---
  extern __global__ void gemm2_bf(const u16*, const float*, const float*, const float*, const float*, u16*, u16*);
  gemm2_bf<<<(NNODES + 31) / 32, 256, 0, stream>>>(h1p, Wl2, bl2, Wr2, br2, xl2, xr2);

  gemm_dual<128, 128, 128, false><<<(NNODES + 63) / 64, 256, 0, stream>>>(
      x, NNODES, skW, skb, skW, skb, (void*)skipbuf, (void*)skipbuf);
  gat_edge<1, 128, false><<<(NNODES + 3) / 4, 256, 0, stream>>>(
      offs, cnt, esrc, eattrp, xl2, xr2, att2, We2, cb2, (void*)h2);
  bn_stats_f<128><<<800, 128, 0, stream>>>(h2, bnsum2, bnsq2);
  bn_fin<128><<<1, 128, 0, stream>>>(bnsum2, bnsq2, bng2, bnb2, bnscale2, bnshift2);
  final_out_k<<<(NNODES * DOUT / 4 + 255) / 256, 256, 0, stream>>>(
      h2, skipbuf, bnscale2, bnshift2, pa, (float*)d_out, NNODES * DOUT);
}

// layer-2 GEMM: A bf16 [N,256], W f32 (256,128)x2, out bf16
__global__ __launch_bounds__(256) void gemm2_bf(
    const u16* __restrict__ A, const float* __restrict__ W0, const float* __restrict__ B0,
    const float* __restrict__ W1, const float* __restrict__ B1,
    u16* __restrict__ C0, u16* __restrict__ C1) {
  constexpr int K = 256, NH = 128, NTOT = 256;
  constexpr int CG = NTOT / 4;      // 64
  constexpr int RG = 256 / CG;      // 4
  constexpr int ROWS = RG * 8;      // 32
  __shared__ float xs[ROWS * K];
  const int row0 = blockIdx.x * ROWS;
  for (int idx = threadIdx.x; idx < ROWS * K; idx += 256) {
    int r = idx / K, k = idx - r * K;
    int gr = row0 + r;
    xs[idx] = (gr < NNODES) ? bf2f(A[(size_t)gr * K + k]) : 0.0f;
  }
  __syncthreads();
  const int cg = threadIdx.x % CG;
  const int rg = threadIdx.x / CG;
  const int c0 = cg * 4;
  const bool first = (c0 < NH);
  const float* Wp = first ? (W0 + c0) : (W1 + (c0 - NH));
  float acc[8][4];
  #pragma unroll
  for (int r = 0; r < 8; ++r)
    #pragma unroll
    for (int j = 0; j < 4; ++j) acc[r][j] = 0.f;
  const float* xrow = &xs[rg * 8 * K];
  for (int k = 0; k < K; ++k) {
    float4 w = *reinterpret_cast<const float4*>(Wp + (size_t)k * NH);
    #pragma unroll
    for (int r = 0; r < 8; ++r) {
      float xv = xrow[r * K + k];
      acc[r][0] += xv * w.x; acc[r][1] += xv * w.y;
      acc[r][2] += xv * w.z; acc[r][3] += xv * w.w;
    }
  }
  const float* Bp = first ? (B0 + c0) : (B1 + (c0 - NH));
  float4 bs = *reinterpret_cast<const float4*>(Bp);
  #pragma unroll
  for (int r = 0; r < 8; ++r) {
    int gr = row0 + rg * 8 + r;
    if (gr >= NNODES) continue;
    float o0 = acc[r][0] + bs.x, o1 = acc[r][1] + bs.y;
    float o2 = acc[r][2] + bs.z, o3 = acc[r][3] + bs.w;
    u16* C = first ? (C0 + (size_t)gr * NH + c0) : (C1 + (size_t)gr * NH + (c0 - NH));
    uint2 pk;
    pk.x = (unsigned)f2bf(o0) | ((unsigned)f2bf(o1) << 16);
    pk.y = (unsigned)f2bf(o2) | ((unsigned)f2bf(o3) << 16);
    *reinterpret_cast<uint2*>(C) = pk;
  }
}

// Round 3
// 590.394 us; speedup vs baseline: 1.4826x; 1.4826x over previous
//
#include <hip/hip_runtime.h>
#include <cstdint>
#include <cstddef>

#define NNODES 50000
#define NEDGES 800000
#define DH1    256   // H*HID = 4*64
#define DOUT   128

typedef unsigned short u16;
typedef __bf16 bf16x8 __attribute__((ext_vector_type(8)));
typedef float  f32x4  __attribute__((ext_vector_type(4)));

__device__ __forceinline__ float bf2f(unsigned int u) {
  union { unsigned int i; float f; } x; x.i = u << 16; return x.f;
}
__device__ __forceinline__ u16 f2bf(float f) {
  union { float f; unsigned int i; } x; x.f = f;
  unsigned int r = x.i + 0x7fffu + ((x.i >> 16) & 1u);  // round-to-nearest-even
  return (u16)(r >> 16);
}

// ---------------- CSR build ----------------

__global__ __launch_bounds__(256) void count_k(const int* __restrict__ dst, int* __restrict__ cnt) {
  int e = blockIdx.x * 256 + threadIdx.x;
  if (e < NEDGES) atomicAdd(&cnt[dst[e]], 1);
}

__global__ __launch_bounds__(256) void offsets_k(const int* __restrict__ cnt, int* __restrict__ offs,
                                                 int* __restrict__ cursor, int* __restrict__ total) {
  int i = blockIdx.x * 256 + threadIdx.x;
  int lane = threadIdx.x & 63;
  int c = (i < NNODES) ? cnt[i] : 0;
  int incl = c;
  #pragma unroll
  for (int d = 1; d < 64; d <<= 1) {
    int t = __shfl_up(incl, d, 64);
    if (lane >= d) incl += t;
  }
  int wtotal = __shfl(incl, 63, 64);
  int base = 0;
  if (lane == 63) base = atomicAdd(total, wtotal);
  base = __shfl(base, 63, 64);
  int off = base + incl - c;
  if (i < NNODES) { offs[i] = off; cursor[i] = off; }
}

__global__ __launch_bounds__(256) void scatter_k(const int* __restrict__ src, const int* __restrict__ dst,
                                                 const float* __restrict__ ea, int* __restrict__ cursor,
                                                 int* __restrict__ esrc, float* __restrict__ eattr) {
  int e = blockIdx.x * 256 + threadIdx.x;
  if (e >= NEDGES) return;
  int d = dst[e];
  int p = atomicAdd(&cursor[d], 1);
  esrc[p] = src[e];
  eattr[p] = ea[e];
}

// ---------------- prep: f32 -> bf16 conversions ----------------

__global__ __launch_bounds__(256) void cvt_bf_k(const float* __restrict__ in, u16* __restrict__ out, int total) {
  int i = (blockIdx.x * 256 + threadIdx.x) * 4;
  if (i >= total) return;
  float4 v = *reinterpret_cast<const float4*>(in + i);
  uint2 pk;
  pk.x = (unsigned)f2bf(v.x) | ((unsigned)f2bf(v.y) << 16);
  pk.y = (unsigned)f2bf(v.z) | ((unsigned)f2bf(v.w) << 16);
  *reinterpret_cast<uint2*>(out + i) = pk;
}

// Build Wt[n][k] (bf16) from W0 [K,NH] | W1 [K,NTOT-NH] (f32), and combined bias (f32).
template<int K, int NH, int NTOT>
__global__ __launch_bounds__(256) void prep_w_k(
    const float* __restrict__ W0, const float* __restrict__ W1,
    const float* __restrict__ B0, const float* __restrict__ B1,
    u16* __restrict__ Wt, float* __restrict__ bias) {
  int idx = blockIdx.x * 256 + threadIdx.x;
  if (idx < NTOT) bias[idx] = (idx < NH) ? B0[idx] : B1[idx - NH];
  if (idx >= NTOT * K) return;
  int n = idx / K, k = idx - n * K;
  float v = (n < NH) ? W0[(size_t)k * NH + n]
                     : W1[(size_t)k * (NTOT - NH > 0 ? NTOT - NH : 1) + (n - NH)];
  Wt[idx] = f2bf(v);
}

// ---------------- MFMA GEMM: C0|C1 = A[M,K](bf16) @ Wt[N,K]^T + bias ----------------
// block 512 thr = 8 waves; tile 64 rows x 128 cols; wave w = 16 cols, 4 row-tiles.
// A-frag: m=lane&15, k=quad*8+j ; B-frag: n=lane&15 (row of Wt), k=quad*8+j
// C/D:    row(m)=quad*4+reg, col(n)=lane&15   [measured m89/m91]

template<int K, int NH, int NTOT, bool OUT_BF16>
__global__ __launch_bounds__(512) void gemm_mfma(
    const u16* __restrict__ A, const u16* __restrict__ Wt, const float* __restrict__ bias,
    void* __restrict__ C0v, void* __restrict__ C1v) {
  constexpr int LDA = K + 8;           // +16B pad breaks ds_read_b128 bank conflicts
  constexpr int LD1 = (NTOT - NH) > 0 ? (NTOT - NH) : 1;
  __shared__ u16 As[64 * LDA];
  const int row0 = blockIdx.x * 64;
  const int tid = threadIdx.x;
  // stage A (64 x K bf16), coalesced 8B chunks
  #pragma unroll
  for (int it = 0; it < K / 32; ++it) {
    int chunk = it * 512 + tid;
    int row = (chunk * 4) / K;
    int col = (chunk * 4) % K;
    uint2 v; v.x = 0u; v.y = 0u;
    int gr = row0 + row;
    if (gr < NNODES) v = *reinterpret_cast<const uint2*>(A + (size_t)gr * K + col);
    *reinterpret_cast<uint2*>(&As[row * LDA + col]) = v;
  }
  __syncthreads();
  const int w    = tid >> 6;
  const int lane = tid & 63;
  const int q    = lane >> 4;
  const int l16  = lane & 15;
  const int ncol = blockIdx.y * 128 + w * 16 + l16;   // output column (Wt row)
  f32x4 acc[4];
  #pragma unroll
  for (int rt = 0; rt < 4; ++rt) acc[rt] = (f32x4){0.f, 0.f, 0.f, 0.f};
  const u16* wp = Wt + (size_t)ncol * K + q * 8;
  #pragma unroll
  for (int ks = 0; ks < K / 32; ++ks) {
    bf16x8 b = *reinterpret_cast<const bf16x8*>(wp + ks * 32);
    #pragma unroll
    for (int rt = 0; rt < 4; ++rt) {
      bf16x8 a = *reinterpret_cast<const bf16x8*>(&As[(rt * 16 + l16) * LDA + ks * 32 + q * 8]);
      acc[rt] = __builtin_amdgcn_mfma_f32_16x16x32_bf16(a, b, acc[rt], 0, 0, 0);
    }
  }
  const float bval = bias[ncol];
  const bool first = (ncol < NH);
  #pragma unroll
  for (int rt = 0; rt < 4; ++rt) {
    #pragma unroll
    for (int r = 0; r < 4; ++r) {
      int grow = row0 + rt * 16 + q * 4 + r;
      if (grow >= NNODES) continue;
      float v = acc[rt][r] + bval;
      if constexpr (OUT_BF16) {
        u16* C = first ? ((u16*)C0v + (size_t)grow * NH + ncol)
                       : ((u16*)C1v + (size_t)grow * LD1 + (ncol - NH));
        *C = f2bf(v);
      } else {
        float* C = first ? ((float*)C0v + (size_t)grow * NH + ncol)
                         : ((float*)C1v + (size_t)grow * LD1 + (ncol - NH));
        *C = v;
      }
    }
  }
}

// ---------------- fused GATv2 edge pass: SINGLE pass, one wave per dst node ----------------
// out = (sum_j exp(s_j) * xl_j) / (sum_j exp(s_j) + 1e-16)  -- identical to ref softmax form

template<int HEADS, int CHAN, bool OUTBF>
__global__ __launch_bounds__(256) void gat_edge(
    const int* __restrict__ offs, const int* __restrict__ cnt,
    const int* __restrict__ esrc, const float* __restrict__ eattr,
    const u16* __restrict__ xl, const u16* __restrict__ xr,
    const float* __restrict__ att, const float* __restrict__ We,
    const float* __restrict__ cb, void* __restrict__ houtv) {
  constexpr int HC = HEADS * CHAN;
  constexpr int EPL = HC / 64;       // elements per lane (4 or 2)
  constexpr int GRP = 64 / HEADS;    // lanes per head group (16 or 64)
  static_assert(EPL * 64 == HC, "layout");
  int node = __builtin_amdgcn_readfirstlane((int)(blockIdx.x * 4 + (threadIdx.x >> 6)));
  if (node >= NNODES) return;
  const int lane = threadIdx.x & 63;
  const int base_c = lane * EPL;
  float xrv[EPL], attv[EPL], wev[EPL];
  #pragma unroll
  for (int j = 0; j < EPL; ++j) {
    xrv[j]  = bf2f(xr[(size_t)node * HC + base_c + j]);
    attv[j] = att[base_c + j];
    wev[j]  = We[base_c + j];
  }
  const int off = __builtin_amdgcn_readfirstlane(offs[node]);
  const int deg = __builtin_amdgcn_readfirstlane(cnt[node]);

  float den = 0.f;
  float accv[EPL];
  #pragma unroll
  for (int j = 0; j < EPL; ++j) accv[j] = 0.f;

  for (int j = 0; j < deg; ++j) {
    int s = esrc[off + j];
    float ea = eattr[off + j];
    float xlv[EPL];
    const u16* xp = xl + (size_t)s * HC + base_c;
    if constexpr (EPL == 4) {
      uint2 raw = *reinterpret_cast<const uint2*>(xp);
      xlv[0] = bf2f(raw.x & 0xffffu); xlv[1] = bf2f(raw.x >> 16);
      xlv[2] = bf2f(raw.y & 0xffffu); xlv[3] = bf2f(raw.y >> 16);
    } else {
      unsigned raw = *reinterpret_cast<const unsigned*>(xp);
      xlv[0] = bf2f(raw & 0xffffu); xlv[1] = bf2f(raw >> 16);
    }
    float part = 0.f;
    #pragma unroll
    for (int jj = 0; jj < EPL; ++jj) {
      float m = xlv[jj] + xrv[jj] + ea * wev[jj];
      m = m > 0.f ? m : 0.2f * m;
      part += m * attv[jj];
    }
    #pragma unroll
    for (int d = 1; d < GRP; d <<= 1) part += __shfl_xor(part, d, 64);
    float e = __expf(part);
    den += e;
    #pragma unroll
    for (int jj = 0; jj < EPL; ++jj) accv[jj] += e * xlv[jj];
  }
  float inv = 1.0f / (den + 1e-16f);
  #pragma unroll
  for (int j = 0; j < EPL; ++j) accv[j] = accv[j] * inv + cb[base_c + j];

  if constexpr (OUTBF) {
    u16* hout = (u16*)houtv + (size_t)node * HC + base_c;
    if constexpr (EPL == 4) {
      uint2 pk;
      pk.x = (unsigned)f2bf(accv[0]) | ((unsigned)f2bf(accv[1]) << 16);
      pk.y = (unsigned)f2bf(accv[2]) | ((unsigned)f2bf(accv[3]) << 16);
      *reinterpret_cast<uint2*>(hout) = pk;
    } else {
      unsigned pk = (unsigned)f2bf(accv[0]) | ((unsigned)f2bf(accv[1]) << 16);
      *reinterpret_cast<unsigned*>(hout) = pk;
    }
  } else {
    float* hout = (float*)houtv + (size_t)node * HC + base_c;
    if constexpr (EPL == 4) {
      float4 st; st.x = accv[0]; st.y = accv[1]; st.z = accv[2]; st.w = accv[3];
      *reinterpret_cast<float4*>(hout) = st;
    } else {
      float2 st; st.x = accv[0]; st.y = accv[1];
      *reinterpret_cast<float2*>(hout) = st;
    }
  }
}

// ---------------- BatchNorm ----------------

template<int NC>
__global__ void bn_stats_bf(const u16* __restrict__ h, float* __restrict__ sum, float* __restrict__ sq) {
  int c = threadIdx.x;
  float s = 0.f, q = 0.f;
  for (int r = blockIdx.x; r < NNODES; r += gridDim.x) {
    float v = bf2f(h[(size_t)r * NC + c]);
    s += v; q += v * v;
  }
  atomicAdd(&sum[c], s);
  atomicAdd(&sq[c], q);
}

template<int NC>
__global__ void bn_stats_f(const float* __restrict__ h, float* __restrict__ sum, float* __restrict__ sq) {
  int c = threadIdx.x;
  float s = 0.f, q = 0.f;
  for (int r = blockIdx.x; r < NNODES; r += gridDim.x) {
    float v = h[(size_t)r * NC + c];
    s += v; q += v * v;
  }
  atomicAdd(&sum[c], s);
  atomicAdd(&sq[c], q);
}

template<int NC>
__global__ void bn_fin(const float* __restrict__ sum, const float* __restrict__ sq,
                       const float* __restrict__ g, const float* __restrict__ b,
                       float* __restrict__ scale, float* __restrict__ shift) {
  int c = threadIdx.x;
  float mu = sum[c] / (float)NNODES;
  float var = sq[c] / (float)NNODES - mu * mu;
  float sc = g[c] * rsqrtf(var + 1e-5f);
  scale[c] = sc;
  shift[c] = b[c] - mu * sc;
}

template<int NC>
__global__ __launch_bounds__(256) void bn_prelu_apply(
    const u16* __restrict__ h, const float* __restrict__ scale, const float* __restrict__ shift,
    const float* __restrict__ pap, u16* __restrict__ outp, int total) {
  int i = (blockIdx.x * 256 + threadIdx.x) * 4;
  if (i >= total) return;
  float pa = pap[0];
  int c = i & (NC - 1);
  uint2 raw = *reinterpret_cast<const uint2*>(h + i);
  float v0 = bf2f(raw.x & 0xffffu), v1 = bf2f(raw.x >> 16);
  float v2 = bf2f(raw.y & 0xffffu), v3 = bf2f(raw.y >> 16);
  float4 sc = *reinterpret_cast<const float4*>(scale + c);
  float4 sh = *reinterpret_cast<const float4*>(shift + c);
  float o0 = v0 * sc.x + sh.x; o0 = o0 > 0.f ? o0 : pa * o0;
  float o1 = v1 * sc.y + sh.y; o1 = o1 > 0.f ? o1 : pa * o1;
  float o2 = v2 * sc.z + sh.z; o2 = o2 > 0.f ? o2 : pa * o2;
  float o3 = v3 * sc.w + sh.w; o3 = o3 > 0.f ? o3 : pa * o3;
  uint2 pk;
  pk.x = (unsigned)f2bf(o0) | ((unsigned)f2bf(o1) << 16);
  pk.y = (unsigned)f2bf(o2) | ((unsigned)f2bf(o3) << 16);
  *reinterpret_cast<uint2*>(outp + i) = pk;
}

__global__ __launch_bounds__(256) void final_out_k(
    const float* __restrict__ h2, const float* __restrict__ skip,
    const float* __restrict__ scale, const float* __restrict__ shift,
    const float* __restrict__ pap, float* __restrict__ outp, int total) {
  int i = (blockIdx.x * 256 + threadIdx.x) * 4;
  if (i >= total) return;
  float pa = pap[0];
  int c = i & 127;
  float4 v  = *reinterpret_cast<const float4*>(h2 + i);
  float4 sk = *reinterpret_cast<const float4*>(skip + i);
  float4 sc = *reinterpret_cast<const float4*>(scale + c);
  float4 sh = *reinterpret_cast<const float4*>(shift + c);
  float4 o;
  o.x = v.x * sc.x + sh.x; o.x = (o.x > 0.f ? o.x : pa * o.x) + sk.x;
  o.y = v.y * sc.y + sh.y; o.y = (o.y > 0.f ? o.y : pa * o.y) + sk.y;
  o.z = v.z * sc.z + sh.z; o.z = (o.z > 0.f ? o.z : pa * o.z) + sk.z;
  o.w = v.w * sc.w + sh.w; o.w = (o.w > 0.f ? o.w : pa * o.w) + sk.w;
  *reinterpret_cast<float4*>(outp + i) = o;
}

// ---------------- launch ----------------

extern "C" void kernel_launch(void* const* d_in, const int* in_sizes, int n_in,
                              void* d_out, int out_size, void* d_ws, size_t ws_size,
                              hipStream_t stream) {
  (void)in_sizes; (void)n_in; (void)out_size; (void)ws_size;
  const float* x    = (const float*)d_in[0];
  const int*   ei   = (const int*)d_in[1];
  const float* ea   = (const float*)d_in[2];
  const float* Wl1  = (const float*)d_in[3];
  const float* bl1  = (const float*)d_in[4];
  const float* Wr1  = (const float*)d_in[5];
  const float* br1  = (const float*)d_in[6];
  const float* We1  = (const float*)d_in[7];
  const float* att1 = (const float*)d_in[8];
  const float* cb1  = (const float*)d_in[9];
  const float* bng1 = (const float*)d_in[10];
  const float* bnb1 = (const float*)d_in[11];
  const float* pa   = (const float*)d_in[12];
  const float* Wl2  = (const float*)d_in[13];
  const float* bl2  = (const float*)d_in[14];
  const float* Wr2  = (const float*)d_in[15];
  const float* br2  = (const float*)d_in[16];
  const float* We2  = (const float*)d_in[17];
  const float* att2 = (const float*)d_in[18];
  const float* cb2  = (const float*)d_in[19];
  const float* bng2 = (const float*)d_in[20];
  const float* bnb2 = (const float*)d_in[21];
  const float* skW  = (const float*)d_in[22];
  const float* skb  = (const float*)d_in[23];
  const int* srcp = ei;
  const int* dstp = ei + NEDGES;

  char* base = (char*)d_ws;
  size_t off = 0;
  auto alloc = [&](size_t bytes) -> char* {
    char* p = base + off;
    off = (off + bytes + 255) & ~(size_t)255;
    return p;
  };
  size_t zero_ints = 1 + NNODES + 256 + 256 + 128 + 128;
  char* zbase = alloc(zero_ints * 4);
  int*   totalp = (int*)zbase;
  int*   cnt    = totalp + 1;
  float* bnsum1 = (float*)(cnt + NNODES);
  float* bnsq1  = bnsum1 + 256;
  float* bnsum2 = bnsq1 + 256;
  float* bnsq2  = bnsum2 + 128;

  int*   offs    = (int*)alloc((size_t)NNODES * 4);
  int*   cursor  = (int*)alloc((size_t)NNODES * 4);
  int*   esrc    = (int*)alloc((size_t)NEDGES * 4);
  float* eattrp  = (float*)alloc((size_t)NEDGES * 4);
  const size_t RBYTES = (size_t)NNODES * DH1 * 2;  // 25.6 MB
  char* regionA = alloc(RBYTES);   // xl1 -> h1p -> h2(f32)
  char* regionB = alloc(RBYTES);   // xr1 -> skipbuf(f32)
  char* regionC = alloc(RBYTES);   // h1  -> xl2+xr2
  u16*   xbf    = (u16*)alloc((size_t)NNODES * 128 * 2);   // x in bf16
  u16*   Wt1    = (u16*)alloc(512 * 128 * 2);
  u16*   Wt2    = (u16*)alloc(256 * 256 * 2);
  u16*   Wts    = (u16*)alloc(128 * 128 * 2);
  float* bias1  = (float*)alloc(512 * 4);
  float* bias2  = (float*)alloc(256 * 4);
  float* bnscale1 = (float*)alloc(256 * 4);
  float* bnshift1 = (float*)alloc(256 * 4);
  float* bnscale2 = (float*)alloc(128 * 4);
  float* bnshift2 = (float*)alloc(128 * 4);

  u16*   xl1     = (u16*)regionA;
  u16*   xr1     = (u16*)regionB;
  u16*   h1      = (u16*)regionC;
  u16*   h1p     = (u16*)regionA;
  u16*   xl2     = (u16*)regionC;
  u16*   xr2     = (u16*)(regionC + (size_t)NNODES * DOUT * 2);
  float* skipbuf = (float*)regionB;
  float* h2      = (float*)regionA;

  hipMemsetAsync(zbase, 0, zero_ints * 4, stream);

  const int EB = (NEDGES + 255) / 256;
  const int NB = (NNODES + 255) / 256;
  count_k<<<EB, 256, 0, stream>>>(dstp, cnt);
  offsets_k<<<NB, 256, 0, stream>>>(cnt, offs, cursor, totalp);
  scatter_k<<<EB, 256, 0, stream>>>(srcp, dstp, ea, cursor, esrc, eattrp);

  // prep: bf16 conversions
  cvt_bf_k<<<(NNODES * 128 / 4 + 255) / 256, 256, 0, stream>>>(x, xbf, NNODES * 128);
  prep_w_k<128, 256, 512><<<(512 * 128 + 255) / 256, 256, 0, stream>>>(Wl1, Wr1, bl1, br1, Wt1, bias1);
  prep_w_k<256, 128, 256><<<(256 * 256 + 255) / 256, 256, 0, stream>>>(Wl2, Wr2, bl2, br2, Wt2, bias2);
  prep_w_k<128, 128, 128><<<(128 * 128 + 255) / 256, 256, 0, stream>>>(skW, skW, skb, skb, Wts, bnscale2 /*scratch bias, unused later before overwrite? no—*/);
  // NOTE: skip bias must persist; use its own slot:
  // (bnscale2 is overwritten by bn_fin AFTER final skip use? skipbuf adds bias inside gemm
  //  epilogue which runs before bn_fin<128>. Safe ordering, but keep clarity: skb also f32[128].)

  const int MB64 = (NNODES + 63) / 64;
  // layer 1: xl1|xr1 = xbf @ Wt1^T + bias1  (bf16 out)
  gemm_mfma<128, 256, 512, true><<<dim3(MB64, 4), 512, 0, stream>>>(
      xbf, Wt1, bias1, (void*)xl1, (void*)xr1);
  gat_edge<4, 64, true><<<(NNODES + 3) / 4, 256, 0, stream>>>(
      offs, cnt, esrc, eattrp, xl1, xr1, att1, We1, cb1, (void*)h1);
  bn_stats_bf<256><<<800, 256, 0, stream>>>(h1, bnsum1, bnsq1);
  bn_fin<256><<<1, 256, 0, stream>>>(bnsum1, bnsq1, bng1, bnb1, bnscale1, bnshift1);
  bn_prelu_apply<256><<<(NNODES * DH1 / 4 + 255) / 256, 256, 0, stream>>>(
      h1, bnscale1, bnshift1, pa, h1p, NNODES * DH1);

  // layer 2: xl2|xr2 = h1p @ Wt2^T + bias2 (bf16 out)
  gemm_mfma<256, 128, 256, true><<<dim3(MB64, 2), 512, 0, stream>>>(
      h1p, Wt2, bias2, (void*)xl2, (void*)xr2);
  // skip GEMM: skipbuf = xbf @ Wts^T + skb (f32 out), over dead xr1
  gemm_mfma<128, 128, 128, false><<<dim3(MB64, 1), 512, 0, stream>>>(
      xbf, Wts, bnscale2, (void*)skipbuf, (void*)skipbuf);
  gat_edge<1, 128, false><<<(NNODES + 3) / 4, 256, 0, stream>>>(
      offs, cnt, esrc, eattrp, xl2, xr2, att2, We2, cb2, (void*)h2);
  bn_stats_f<128><<<800, 128, 0, stream>>>(h2, bnsum2, bnsq2);
  bn_fin<128><<<1, 128, 0, stream>>>(bnsum2, bnsq2, bng2, bnb2, bnscale2, bnshift2);
  final_out_k<<<(NNODES * DOUT / 4 + 255) / 256, 256, 0, stream>>>(
      h2, skipbuf, bnscale2, bnshift2, pa, (float*)d_out, NNODES * DOUT);
}

// Round 4
// 558.846 us; speedup vs baseline: 1.5663x; 1.0565x over previous
//
#include <hip/hip_runtime.h>
#include <cstdint>
#include <cstddef>

#define NNODES 50000
#define NEDGES 800000
#define DH1    256   // H*HID = 4*64
#define DOUT   128

typedef unsigned short u16;
typedef __bf16 bf16x8 __attribute__((ext_vector_type(8)));
typedef float  f32x4  __attribute__((ext_vector_type(4)));

__device__ __forceinline__ float bf2f(unsigned int u) {
  union { unsigned int i; float f; } x; x.i = u << 16; return x.f;
}
__device__ __forceinline__ u16 f2bf(float f) {
  union { float f; unsigned int i; } x; x.f = f;
  unsigned int r = x.i + 0x7fffu + ((x.i >> 16) & 1u);  // round-to-nearest-even
  return (u16)(r >> 16);
}

// ---------------- CSR build ----------------

__global__ __launch_bounds__(256) void count_k(const int* __restrict__ dst, int* __restrict__ cnt) {
  int e = blockIdx.x * 256 + threadIdx.x;
  if (e < NEDGES) atomicAdd(&cnt[dst[e]], 1);
}

__global__ __launch_bounds__(256) void offsets_k(const int* __restrict__ cnt, int* __restrict__ offs,
                                                 int* __restrict__ cursor, int* __restrict__ total) {
  int i = blockIdx.x * 256 + threadIdx.x;
  int lane = threadIdx.x & 63;
  int c = (i < NNODES) ? cnt[i] : 0;
  int incl = c;
  #pragma unroll
  for (int d = 1; d < 64; d <<= 1) {
    int t = __shfl_up(incl, d, 64);
    if (lane >= d) incl += t;
  }
  int wtotal = __shfl(incl, 63, 64);
  int base = 0;
  if (lane == 63) base = atomicAdd(total, wtotal);
  base = __shfl(base, 63, 64);
  int off = base + incl - c;
  if (i < NNODES) { offs[i] = off; cursor[i] = off; }
}

// pack (src, attr-bits) into one int2 per edge: single 8B scattered store
__global__ __launch_bounds__(256) void scatter_k(const int* __restrict__ src, const int* __restrict__ dst,
                                                 const float* __restrict__ ea, int* __restrict__ cursor,
                                                 int2* __restrict__ epair) {
  int e = blockIdx.x * 256 + threadIdx.x;
  if (e >= NEDGES) return;
  int d = dst[e];
  int p = atomicAdd(&cursor[d], 1);
  int2 v; v.x = src[e]; v.y = __float_as_int(ea[e]);
  epair[p] = v;
}

// ---------------- prep: conversions ----------------

__global__ __launch_bounds__(256) void cvt_bf_k(const float* __restrict__ in, u16* __restrict__ out, int total) {
  int i = (blockIdx.x * 256 + threadIdx.x) * 4;
  if (i >= total) return;
  float4 v = *reinterpret_cast<const float4*>(in + i);
  uint2 pk;
  pk.x = (unsigned)f2bf(v.x) | ((unsigned)f2bf(v.y) << 16);
  pk.y = (unsigned)f2bf(v.z) | ((unsigned)f2bf(v.w) << 16);
  *reinterpret_cast<uint2*>(out + i) = pk;
}

// all three weight transposes + biases in one launch; grid (256, 3)
__global__ __launch_bounds__(256) void prep_all_k(
    const float* __restrict__ Wl1, const float* __restrict__ Wr1,
    const float* __restrict__ bl1, const float* __restrict__ br1,
    const float* __restrict__ Wl2, const float* __restrict__ Wr2,
    const float* __restrict__ bl2, const float* __restrict__ br2,
    const float* __restrict__ skW, const float* __restrict__ skb,
    u16* __restrict__ Wt1, float* __restrict__ bias1,
    u16* __restrict__ Wt2, float* __restrict__ bias2,
    u16* __restrict__ Wts, float* __restrict__ biasS) {
  int idx = blockIdx.x * 256 + threadIdx.x;
  int which = blockIdx.y;
  if (which == 0) {                         // K=128, NH=256, NTOT=512
    if (idx < 512) bias1[idx] = (idx < 256) ? bl1[idx] : br1[idx - 256];
    int n = idx >> 7, k = idx & 127;
    float v = (n < 256) ? Wl1[k * 256 + n] : Wr1[k * 256 + (n - 256)];
    Wt1[idx] = f2bf(v);
  } else if (which == 1) {                  // K=256, NH=128, NTOT=256
    if (idx < 256) bias2[idx] = (idx < 128) ? bl2[idx] : br2[idx - 128];
    int n = idx >> 8, k = idx & 255;
    float v = (n < 128) ? Wl2[k * 128 + n] : Wr2[k * 128 + (n - 128)];
    Wt2[idx] = f2bf(v);
  } else {                                  // K=128, N=128
    if (idx < 128) biasS[idx] = skb[idx];
    if (idx < 128 * 128) {
      int n = idx >> 7, k = idx & 127;
      Wts[idx] = f2bf(skW[k * 128 + n]);
    }
  }
}

// ---------------- MFMA GEMM: C0|C1 = A[M,K](bf16) @ Wt[N,K]^T + bias ----------------
// block 512 thr = 8 waves; tile 64 rows x 128 cols; wave w = 16 cols, 4 row-tiles.
// A-frag: m=lane&15, k=quad*8+j ; B-frag: n=lane&15 (Wt row), k=quad*8+j
// C/D:    row(m)=quad*4+reg, col(n)=lane&15   [verified round 3]
// Epilogue: acc -> LDS tile (padded) -> coalesced 16B global stores.

template<int K, int NH, int NTOT, bool OUT_BF16>
__global__ __launch_bounds__(512) void gemm_mfma(
    const u16* __restrict__ A, const u16* __restrict__ Wt, const float* __restrict__ bias,
    void* __restrict__ C0v, void* __restrict__ C1v) {
  constexpr int LDA = K + 8;                 // bf16 elements, +16B pad
  constexpr int LD1 = (NTOT - NH) > 0 ? (NTOT - NH) : 1;
  constexpr int CSTR = OUT_BF16 ? 136 : 132; // padded C-tile row stride (elements)
  constexpr size_t ABYTES = (size_t)64 * LDA * 2;
  constexpr size_t CBYTES = (size_t)64 * CSTR * (OUT_BF16 ? 2 : 4);
  constexpr size_t SBYTES = ABYTES > CBYTES ? ABYTES : CBYTES;
  __shared__ __align__(16) char smem[SBYTES];
  u16* As = (u16*)smem;
  const int row0 = blockIdx.x * 64;
  const int tid = threadIdx.x;
  #pragma unroll
  for (int it = 0; it < K / 32; ++it) {
    int chunk = it * 512 + tid;
    int row = (chunk * 4) / K;
    int col = (chunk * 4) % K;
    uint2 v; v.x = 0u; v.y = 0u;
    int gr = row0 + row;
    if (gr < NNODES) v = *reinterpret_cast<const uint2*>(A + (size_t)gr * K + col);
    *reinterpret_cast<uint2*>(&As[row * LDA + col]) = v;
  }
  __syncthreads();
  const int w = tid >> 6, lane = tid & 63, q = lane >> 4, l16 = lane & 15;
  const int tc = w * 16 + l16;               // tile-local output column
  const int ncol = blockIdx.y * 128 + tc;    // global output column (Wt row)
  f32x4 acc[4];
  #pragma unroll
  for (int rt = 0; rt < 4; ++rt) acc[rt] = (f32x4){0.f, 0.f, 0.f, 0.f};
  const u16* wp = Wt + (size_t)ncol * K + q * 8;
  #pragma unroll
  for (int ks = 0; ks < K / 32; ++ks) {
    bf16x8 b = *reinterpret_cast<const bf16x8*>(wp + ks * 32);
    #pragma unroll
    for (int rt = 0; rt < 4; ++rt) {
      bf16x8 a = *reinterpret_cast<const bf16x8*>(&As[(rt * 16 + l16) * LDA + ks * 32 + q * 8]);
      acc[rt] = __builtin_amdgcn_mfma_f32_16x16x32_bf16(a, b, acc[rt], 0, 0, 0);
    }
  }
  const float bval = bias[ncol];
  __syncthreads();                           // all As reads done; reuse smem for C tile
  if constexpr (OUT_BF16) {
    u16* Cs = (u16*)smem;
    #pragma unroll
    for (int rt = 0; rt < 4; ++rt)
      #pragma unroll
      for (int r = 0; r < 4; ++r)
        Cs[(rt * 16 + q * 4 + r) * CSTR + tc] = f2bf(acc[rt][r] + bval);
  } else {
    float* Cs = (float*)smem;
    #pragma unroll
    for (int rt = 0; rt < 4; ++rt)
      #pragma unroll
      for (int r = 0; r < 4; ++r)
        Cs[(rt * 16 + q * 4 + r) * CSTR + tc] = acc[rt][r] + bval;
  }
  __syncthreads();
  const int cb = blockIdx.y * 128;
  const bool first = (cb < NH);
  const int LD = first ? NH : LD1;
  const int cc = first ? cb : (cb - NH);
  if constexpr (OUT_BF16) {
    u16* Cg = (u16*)(first ? C0v : C1v);
    constexpr int CPR = 16;                  // 16 x 16B chunks = 256B per row
    #pragma unroll
    for (int it = 0; it < 64 * CPR / 512; ++it) {
      int ch = it * 512 + tid;
      int row = ch / CPR, co = (ch % CPR) * 8;
      int grow = row0 + row;
      if (grow < NNODES) {
        uint4 v = *reinterpret_cast<const uint4*>(&((u16*)smem)[row * CSTR + co]);
        *reinterpret_cast<uint4*>(Cg + (size_t)grow * LD + cc + co) = v;
      }
    }
  } else {
    float* Cg = (float*)(first ? C0v : C1v);
    constexpr int CPR = 32;                  // 32 x 16B chunks = 512B per row
    #pragma unroll
    for (int it = 0; it < 64 * CPR / 512; ++it) {
      int ch = it * 512 + tid;
      int row = ch / CPR, co = (ch % CPR) * 4;
      int grow = row0 + row;
      if (grow < NNODES) {
        float4 v = *reinterpret_cast<const float4*>(&((float*)smem)[row * CSTR + co]);
        *reinterpret_cast<float4*>(Cg + (size_t)grow * LD + cc + co) = v;
      }
    }
  }
}

// ---------------- fused GATv2 edge pass: SINGLE pass, one wave per dst node ----------------
// batched edge metadata: one coalesced int2 load per 64 edges, shfl-broadcast

template<int HEADS, int CHAN, bool OUTBF>
__global__ __launch_bounds__(256) void gat_edge(
    const int* __restrict__ offs, const int* __restrict__ cnt,
    const int2* __restrict__ epair,
    const u16* __restrict__ xl, const u16* __restrict__ xr,
    const float* __restrict__ att, const float* __restrict__ We,
    const float* __restrict__ cb, void* __restrict__ houtv) {
  constexpr int HC = HEADS * CHAN;
  constexpr int EPL = HC / 64;       // elements per lane (4 or 2)
  constexpr int GRP = 64 / HEADS;    // lanes per head group (16 or 64)
  static_assert(EPL * 64 == HC, "layout");
  int node = __builtin_amdgcn_readfirstlane((int)(blockIdx.x * 4 + (threadIdx.x >> 6)));
  if (node >= NNODES) return;
  const int lane = threadIdx.x & 63;
  const int base_c = lane * EPL;
  float xrv[EPL], attv[EPL], wev[EPL], cbv[EPL];
  #pragma unroll
  for (int j = 0; j < EPL; ++j) {
    xrv[j]  = bf2f(xr[(size_t)node * HC + base_c + j]);
    attv[j] = att[base_c + j];
    wev[j]  = We[base_c + j];
    cbv[j]  = cb[base_c + j];
  }
  const int off = __builtin_amdgcn_readfirstlane(offs[node]);
  const int deg = __builtin_amdgcn_readfirstlane(cnt[node]);

  float den = 0.f;
  float accv[EPL];
  #pragma unroll
  for (int j = 0; j < EPL; ++j) accv[j] = 0.f;

  for (int b = 0; b < deg; b += 64) {
    int nb = deg - b; if (nb > 64) nb = 64;
    int2 pp; pp.x = 0; pp.y = 0;
    if (lane < nb) pp = epair[off + b + lane];
    for (int j = 0; j < nb; ++j) {
      int s = __shfl(pp.x, j, 64);
      float ea = __int_as_float(__shfl(pp.y, j, 64));
      float xlv[EPL];
      const u16* xp = xl + (size_t)s * HC + base_c;
      if constexpr (EPL == 4) {
        uint2 raw = *reinterpret_cast<const uint2*>(xp);
        xlv[0] = bf2f(raw.x & 0xffffu); xlv[1] = bf2f(raw.x >> 16);
        xlv[2] = bf2f(raw.y & 0xffffu); xlv[3] = bf2f(raw.y >> 16);
      } else {
        unsigned raw = *reinterpret_cast<const unsigned*>(xp);
        xlv[0] = bf2f(raw & 0xffffu); xlv[1] = bf2f(raw >> 16);
      }
      float part = 0.f;
      #pragma unroll
      for (int jj = 0; jj < EPL; ++jj) {
        float m = xlv[jj] + xrv[jj] + ea * wev[jj];
        m = m > 0.f ? m : 0.2f * m;
        part += m * attv[jj];
      }
      #pragma unroll
      for (int d = 1; d < GRP; d <<= 1) part += __shfl_xor(part, d, 64);
      float e = __expf(part);
      den += e;
      #pragma unroll
      for (int jj = 0; jj < EPL; ++jj) accv[jj] += e * xlv[jj];
    }
  }
  float inv = 1.0f / (den + 1e-16f);
  #pragma unroll
  for (int j = 0; j < EPL; ++j) accv[j] = accv[j] * inv + cbv[j];

  if constexpr (OUTBF) {
    u16* hout = (u16*)houtv + (size_t)node * HC + base_c;
    if constexpr (EPL == 4) {
      uint2 pk;
      pk.x = (unsigned)f2bf(accv[0]) | ((unsigned)f2bf(accv[1]) << 16);
      pk.y = (unsigned)f2bf(accv[2]) | ((unsigned)f2bf(accv[3]) << 16);
      *reinterpret_cast<uint2*>(hout) = pk;
    } else {
      unsigned pk = (unsigned)f2bf(accv[0]) | ((unsigned)f2bf(accv[1]) << 16);
      *reinterpret_cast<unsigned*>(hout) = pk;
    }
  } else {
    float* hout = (float*)houtv + (size_t)node * HC + base_c;
    if constexpr (EPL == 4) {
      float4 st; st.x = accv[0]; st.y = accv[1]; st.z = accv[2]; st.w = accv[3];
      *reinterpret_cast<float4*>(hout) = st;
    } else {
      float2 st; st.x = accv[0]; st.y = accv[1];
      *reinterpret_cast<float2*>(hout) = st;
    }
  }
}

// ---------------- BatchNorm ----------------

template<int NC>
__global__ void bn_stats_bf(const u16* __restrict__ h, float* __restrict__ sum, float* __restrict__ sq) {
  int c = threadIdx.x;
  float s = 0.f, q = 0.f;
  for (int r = blockIdx.x; r < NNODES; r += gridDim.x) {
    float v = bf2f(h[(size_t)r * NC + c]);
    s += v; q += v * v;
  }
  atomicAdd(&sum[c], s);
  atomicAdd(&sq[c], q);
}

// h (bf16) -> BN(from raw sums) -> PReLU -> bf16
template<int NC>
__global__ __launch_bounds__(256) void bn_prelu_apply(
    const u16* __restrict__ h, const float* __restrict__ sum, const float* __restrict__ sq,
    const float* __restrict__ g, const float* __restrict__ bb_,
    const float* __restrict__ pap, u16* __restrict__ outp, int total) {
  int i = (blockIdx.x * 256 + threadIdx.x) * 4;
  if (i >= total) return;
  const float invN = 1.0f / (float)NNODES;
  float pa = pap[0];
  int c = i & (NC - 1);
  float4 sm = *reinterpret_cast<const float4*>(sum + c);
  float4 qq = *reinterpret_cast<const float4*>(sq + c);
  float4 gg = *reinterpret_cast<const float4*>(g + c);
  float4 bb = *reinterpret_cast<const float4*>(bb_ + c);
  float mu, var, sc[4], sh[4];
  mu = sm.x * invN; var = qq.x * invN - mu * mu; sc[0] = gg.x * rsqrtf(var + 1e-5f); sh[0] = bb.x - mu * sc[0];
  mu = sm.y * invN; var = qq.y * invN - mu * mu; sc[1] = gg.y * rsqrtf(var + 1e-5f); sh[1] = bb.y - mu * sc[1];
  mu = sm.z * invN; var = qq.z * invN - mu * mu; sc[2] = gg.z * rsqrtf(var + 1e-5f); sh[2] = bb.z - mu * sc[2];
  mu = sm.w * invN; var = qq.w * invN - mu * mu; sc[3] = gg.w * rsqrtf(var + 1e-5f); sh[3] = bb.w - mu * sc[3];
  uint2 raw = *reinterpret_cast<const uint2*>(h + i);
  float v0 = bf2f(raw.x & 0xffffu), v1 = bf2f(raw.x >> 16);
  float v2 = bf2f(raw.y & 0xffffu), v3 = bf2f(raw.y >> 16);
  float o0 = v0 * sc[0] + sh[0]; o0 = o0 > 0.f ? o0 : pa * o0;
  float o1 = v1 * sc[1] + sh[1]; o1 = o1 > 0.f ? o1 : pa * o1;
  float o2 = v2 * sc[2] + sh[2]; o2 = o2 > 0.f ? o2 : pa * o2;
  float o3 = v3 * sc[3] + sh[3]; o3 = o3 > 0.f ? o3 : pa * o3;
  uint2 pk;
  pk.x = (unsigned)f2bf(o0) | ((unsigned)f2bf(o1) << 16);
  pk.y = (unsigned)f2bf(o2) | ((unsigned)f2bf(o3) << 16);
  *reinterpret_cast<uint2*>(outp + i) = pk;
}

// h2 (bf16) -> BN(from raw sums) -> PReLU -> + skip(f32) -> f32 out
__global__ __launch_bounds__(256) void final_out_k(
    const u16* __restrict__ h2, const float* __restrict__ skip,
    const float* __restrict__ sum, const float* __restrict__ sq,
    const float* __restrict__ g, const float* __restrict__ bb_,
    const float* __restrict__ pap, float* __restrict__ outp, int total) {
  int i = (blockIdx.x * 256 + threadIdx.x) * 4;
  if (i >= total) return;
  const float invN = 1.0f / (float)NNODES;
  float pa = pap[0];
  int c = i & 127;
  float4 sm = *reinterpret_cast<const float4*>(sum + c);
  float4 qq = *reinterpret_cast<const float4*>(sq + c);
  float4 gg = *reinterpret_cast<const float4*>(g + c);
  float4 bb = *reinterpret_cast<const float4*>(bb_ + c);
  float mu, var, sc[4], sh[4];
  mu = sm.x * invN; var = qq.x * invN - mu * mu; sc[0] = gg.x * rsqrtf(var + 1e-5f); sh[0] = bb.x - mu * sc[0];
  mu = sm.y * invN; var = qq.y * invN - mu * mu; sc[1] = gg.y * rsqrtf(var + 1e-5f); sh[1] = bb.y - mu * sc[1];
  mu = sm.z * invN; var = qq.z * invN - mu * mu; sc[2] = gg.z * rsqrtf(var + 1e-5f); sh[2] = bb.z - mu * sc[2];
  mu = sm.w * invN; var = qq.w * invN - mu * mu; sc[3] = gg.w * rsqrtf(var + 1e-5f); sh[3] = bb.w - mu * sc[3];
  uint2 raw = *reinterpret_cast<const uint2*>(h2 + i);
  float v0 = bf2f(raw.x & 0xffffu), v1 = bf2f(raw.x >> 16);
  float v2 = bf2f(raw.y & 0xffffu), v3 = bf2f(raw.y >> 16);
  float4 sk = *reinterpret_cast<const float4*>(skip + i);
  float4 o;
  o.x = v0 * sc[0] + sh[0]; o.x = (o.x > 0.f ? o.x : pa * o.x) + sk.x;
  o.y = v1 * sc[1] + sh[1]; o.y = (o.y > 0.f ? o.y : pa * o.y) + sk.y;
  o.z = v2 * sc[2] + sh[2]; o.z = (o.z > 0.f ? o.z : pa * o.z) + sk.z;
  o.w = v3 * sc[3] + sh[3]; o.w = (o.w > 0.f ? o.w : pa * o.w) + sk.w;
  *reinterpret_cast<float4*>(outp + i) = o;
}

// ---------------- launch ----------------

extern "C" void kernel_launch(void* const* d_in, const int* in_sizes, int n_in,
                              void* d_out, int out_size, void* d_ws, size_t ws_size,
                              hipStream_t stream) {
  (void)in_sizes; (void)n_in; (void)out_size; (void)ws_size;
  const float* x    = (const float*)d_in[0];
  const int*   ei   = (const int*)d_in[1];
  const float* ea   = (const float*)d_in[2];
  const float* Wl1  = (const float*)d_in[3];
  const float* bl1  = (const float*)d_in[4];
  const float* Wr1  = (const float*)d_in[5];
  const float* br1  = (const float*)d_in[6];
  const float* We1  = (const float*)d_in[7];
  const float* att1 = (const float*)d_in[8];
  const float* cb1  = (const float*)d_in[9];
  const float* bng1 = (const float*)d_in[10];
  const float* bnb1 = (const float*)d_in[11];
  const float* pa   = (const float*)d_in[12];
  const float* Wl2  = (const float*)d_in[13];
  const float* bl2  = (const float*)d_in[14];
  const float* Wr2  = (const float*)d_in[15];
  const float* br2  = (const float*)d_in[16];
  const float* We2  = (const float*)d_in[17];
  const float* att2 = (const float*)d_in[18];
  const float* cb2  = (const float*)d_in[19];
  const float* bng2 = (const float*)d_in[20];
  const float* bnb2 = (const float*)d_in[21];
  const float* skW  = (const float*)d_in[22];
  const float* skb  = (const float*)d_in[23];
  const int* srcp = ei;
  const int* dstp = ei + NEDGES;

  char* base = (char*)d_ws;
  size_t off = 0;
  auto alloc = [&](size_t bytes) -> char* {
    char* p = base + off;
    off = (off + bytes + 255) & ~(size_t)255;
    return p;
  };
  size_t zero_ints = 1 + NNODES + 256 + 256 + 128 + 128;
  char* zbase = alloc(zero_ints * 4);
  int*   totalp = (int*)zbase;
  int*   cnt    = totalp + 1;
  float* bnsum1 = (float*)(cnt + NNODES);
  float* bnsq1  = bnsum1 + 256;
  float* bnsum2 = bnsq1 + 256;
  float* bnsq2  = bnsum2 + 128;

  int*   offs    = (int*)alloc((size_t)NNODES * 4);
  int*   cursor  = (int*)alloc((size_t)NNODES * 4);
  int2*  epair   = (int2*)alloc((size_t)NEDGES * 8);
  const size_t RBYTES = (size_t)NNODES * DH1 * 2;  // 25.6 MB
  char* regionA = alloc(RBYTES);   // xl1(bf16) -> h1p(bf16) -> h2(bf16)
  char* regionB = alloc(RBYTES);   // xr1(bf16) -> skipbuf(f32)
  char* regionC = alloc(RBYTES);   // h1(bf16)  -> xl2+xr2(bf16)
  u16*   xbf    = (u16*)alloc((size_t)NNODES * 128 * 2);
  u16*   Wt1    = (u16*)alloc(512 * 128 * 2);
  u16*   Wt2    = (u16*)alloc(256 * 256 * 2);
  u16*   Wts    = (u16*)alloc(128 * 128 * 2);
  float* bias1  = (float*)alloc(512 * 4);
  float* bias2  = (float*)alloc(256 * 4);
  float* biasS  = (float*)alloc(128 * 4);

  u16*   xl1     = (u16*)regionA;
  u16*   xr1     = (u16*)regionB;
  u16*   h1      = (u16*)regionC;
  u16*   h1p     = (u16*)regionA;
  u16*   xl2     = (u16*)regionC;
  u16*   xr2     = (u16*)(regionC + (size_t)NNODES * DOUT * 2);
  float* skipbuf = (float*)regionB;
  u16*   h2      = (u16*)regionA;

  hipMemsetAsync(zbase, 0, zero_ints * 4, stream);

  const int EB = (NEDGES + 255) / 256;
  const int NB = (NNODES + 255) / 256;
  count_k<<<EB, 256, 0, stream>>>(dstp, cnt);
  offsets_k<<<NB, 256, 0, stream>>>(cnt, offs, cursor, totalp);
  scatter_k<<<EB, 256, 0, stream>>>(srcp, dstp, ea, cursor, epair);

  cvt_bf_k<<<(NNODES * 128 / 4 + 255) / 256, 256, 0, stream>>>(x, xbf, NNODES * 128);
  prep_all_k<<<dim3(256, 3), 256, 0, stream>>>(Wl1, Wr1, bl1, br1, Wl2, Wr2, bl2, br2,
                                               skW, skb, Wt1, bias1, Wt2, bias2, Wts, biasS);

  const int MB64 = (NNODES + 63) / 64;
  // layer 1
  gemm_mfma<128, 256, 512, true><<<dim3(MB64, 4), 512, 0, stream>>>(
      xbf, Wt1, bias1, (void*)xl1, (void*)xr1);
  gat_edge<4, 64, true><<<(NNODES + 3) / 4, 256, 0, stream>>>(
      offs, cnt, epair, xl1, xr1, att1, We1, cb1, (void*)h1);
  bn_stats_bf<256><<<800, 256, 0, stream>>>(h1, bnsum1, bnsq1);
  bn_prelu_apply<256><<<(NNODES * DH1 / 4 + 255) / 256, 256, 0, stream>>>(
      h1, bnsum1, bnsq1, bng1, bnb1, pa, h1p, NNODES * DH1);

  // layer 2 + skip
  gemm_mfma<256, 128, 256, true><<<dim3(MB64, 2), 512, 0, stream>>>(
      h1p, Wt2, bias2, (void*)xl2, (void*)xr2);
  gemm_mfma<128, 128, 128, false><<<dim3(MB64, 1), 512, 0, stream>>>(
      xbf, Wts, biasS, (void*)skipbuf, (void*)skipbuf);
  gat_edge<1, 128, true><<<(NNODES + 3) / 4, 256, 0, stream>>>(
      offs, cnt, epair, xl2, xr2, att2, We2, cb2, (void*)h2);
  bn_stats_bf<128><<<800, 128, 0, stream>>>(h2, bnsum2, bnsq2);
  final_out_k<<<(NNODES * DOUT / 4 + 255) / 256, 256, 0, stream>>>(
      h2, skipbuf, bnsum2, bnsq2, bng2, bnb2, pa, (float*)d_out, NNODES * DOUT);
}

// Round 5
// 545.550 us; speedup vs baseline: 1.6045x; 1.0244x over previous
//
#include <hip/hip_runtime.h>
#include <cstdint>
#include <cstddef>

#define NNODES 50000
#define NEDGES 800000
#define DH1    256   // H*HID = 4*64
#define DOUT   128

typedef unsigned short u16;
typedef __bf16 bf16x8 __attribute__((ext_vector_type(8)));
typedef float  f32x4  __attribute__((ext_vector_type(4)));

__device__ __forceinline__ float bf2f(unsigned int u) {
  union { unsigned int i; float f; } x; x.i = u << 16; return x.f;
}
__device__ __forceinline__ u16 f2bf(float f) {
  union { float f; unsigned int i; } x; x.f = f;
  unsigned int r = x.i + 0x7fffu + ((x.i >> 16) & 1u);  // round-to-nearest-even
  return (u16)(r >> 16);
}

// ---------------- CSR build ----------------

__global__ __launch_bounds__(256) void count_k(const int* __restrict__ dst, int* __restrict__ cnt) {
  int e = blockIdx.x * 256 + threadIdx.x;
  if (e < NEDGES) atomicAdd(&cnt[dst[e]], 1);
}

__global__ __launch_bounds__(256) void offsets_k(const int* __restrict__ cnt, int* __restrict__ offs,
                                                 int* __restrict__ cursor, int* __restrict__ total) {
  int i = blockIdx.x * 256 + threadIdx.x;
  int lane = threadIdx.x & 63;
  int c = (i < NNODES) ? cnt[i] : 0;
  int incl = c;
  #pragma unroll
  for (int d = 1; d < 64; d <<= 1) {
    int t = __shfl_up(incl, d, 64);
    if (lane >= d) incl += t;
  }
  int wtotal = __shfl(incl, 63, 64);
  int base = 0;
  if (lane == 63) base = atomicAdd(total, wtotal);
  base = __shfl(base, 63, 64);
  int off = base + incl - c;
  if (i < NNODES) { offs[i] = off; cursor[i] = off; }
}

// pack (src, attr-bits) into one int2 per edge: single 8B scattered store
__global__ __launch_bounds__(256) void scatter_k(const int* __restrict__ src, const int* __restrict__ dst,
                                                 const float* __restrict__ ea, int* __restrict__ cursor,
                                                 int2* __restrict__ epair) {
  int e = blockIdx.x * 256 + threadIdx.x;
  if (e >= NEDGES) return;
  int d = dst[e];
  int p = atomicAdd(&cursor[d], 1);
  int2 v; v.x = src[e]; v.y = __float_as_int(ea[e]);
  epair[p] = v;
}

// ---------------- prep: conversions ----------------

__global__ __launch_bounds__(256) void cvt_bf_k(const float* __restrict__ in, u16* __restrict__ out, int total) {
  int i = (blockIdx.x * 256 + threadIdx.x) * 4;
  if (i >= total) return;
  float4 v = *reinterpret_cast<const float4*>(in + i);
  uint2 pk;
  pk.x = (unsigned)f2bf(v.x) | ((unsigned)f2bf(v.y) << 16);
  pk.y = (unsigned)f2bf(v.z) | ((unsigned)f2bf(v.w) << 16);
  *reinterpret_cast<uint2*>(out + i) = pk;
}

// all three weight transposes + biases in one launch; grid (256, 3)
__global__ __launch_bounds__(256) void prep_all_k(
    const float* __restrict__ Wl1, const float* __restrict__ Wr1,
    const float* __restrict__ bl1, const float* __restrict__ br1,
    const float* __restrict__ Wl2, const float* __restrict__ Wr2,
    const float* __restrict__ bl2, const float* __restrict__ br2,
    const float* __restrict__ skW, const float* __restrict__ skb,
    u16* __restrict__ Wt1, float* __restrict__ bias1,
    u16* __restrict__ Wt2, float* __restrict__ bias2,
    u16* __restrict__ Wts, float* __restrict__ biasS) {
  int idx = blockIdx.x * 256 + threadIdx.x;
  int which = blockIdx.y;
  if (which == 0) {                         // K=128, NH=256, NTOT=512
    if (idx < 512) bias1[idx] = (idx < 256) ? bl1[idx] : br1[idx - 256];
    int n = idx >> 7, k = idx & 127;
    float v = (n < 256) ? Wl1[k * 256 + n] : Wr1[k * 256 + (n - 256)];
    Wt1[idx] = f2bf(v);
  } else if (which == 1) {                  // K=256, NH=128, NTOT=256
    if (idx < 256) bias2[idx] = (idx < 128) ? bl2[idx] : br2[idx - 128];
    int n = idx >> 8, k = idx & 255;
    float v = (n < 128) ? Wl2[k * 128 + n] : Wr2[k * 128 + (n - 128)];
    Wt2[idx] = f2bf(v);
  } else {                                  // K=128, N=128
    if (idx < 128) biasS[idx] = skb[idx];
    if (idx < 128 * 128) {
      int n = idx >> 7, k = idx & 127;
      Wts[idx] = f2bf(skW[k * 128 + n]);
    }
  }
}

// ---------------- MFMA GEMM: C0|C1 = A[M,K](bf16) @ Wt[N,K]^T + bias ----------------

template<int K, int NH, int NTOT, bool OUT_BF16>
__global__ __launch_bounds__(512) void gemm_mfma(
    const u16* __restrict__ A, const u16* __restrict__ Wt, const float* __restrict__ bias,
    void* __restrict__ C0v, void* __restrict__ C1v) {
  constexpr int LDA = K + 8;                 // bf16 elements, +16B pad
  constexpr int LD1 = (NTOT - NH) > 0 ? (NTOT - NH) : 1;
  constexpr int CSTR = OUT_BF16 ? 136 : 132; // padded C-tile row stride (elements)
  constexpr size_t ABYTES = (size_t)64 * LDA * 2;
  constexpr size_t CBYTES = (size_t)64 * CSTR * (OUT_BF16 ? 2 : 4);
  constexpr size_t SBYTES = ABYTES > CBYTES ? ABYTES : CBYTES;
  __shared__ __align__(16) char smem[SBYTES];
  u16* As = (u16*)smem;
  const int row0 = blockIdx.x * 64;
  const int tid = threadIdx.x;
  #pragma unroll
  for (int it = 0; it < K / 32; ++it) {
    int chunk = it * 512 + tid;
    int row = (chunk * 4) / K;
    int col = (chunk * 4) % K;
    uint2 v; v.x = 0u; v.y = 0u;
    int gr = row0 + row;
    if (gr < NNODES) v = *reinterpret_cast<const uint2*>(A + (size_t)gr * K + col);
    *reinterpret_cast<uint2*>(&As[row * LDA + col]) = v;
  }
  __syncthreads();
  const int w = tid >> 6, lane = tid & 63, q = lane >> 4, l16 = lane & 15;
  const int tc = w * 16 + l16;
  const int ncol = blockIdx.y * 128 + tc;
  f32x4 acc[4];
  #pragma unroll
  for (int rt = 0; rt < 4; ++rt) acc[rt] = (f32x4){0.f, 0.f, 0.f, 0.f};
  const u16* wp = Wt + (size_t)ncol * K + q * 8;
  #pragma unroll
  for (int ks = 0; ks < K / 32; ++ks) {
    bf16x8 b = *reinterpret_cast<const bf16x8*>(wp + ks * 32);
    #pragma unroll
    for (int rt = 0; rt < 4; ++rt) {
      bf16x8 a = *reinterpret_cast<const bf16x8*>(&As[(rt * 16 + l16) * LDA + ks * 32 + q * 8]);
      acc[rt] = __builtin_amdgcn_mfma_f32_16x16x32_bf16(a, b, acc[rt], 0, 0, 0);
    }
  }
  const float bval = bias[ncol];
  __syncthreads();
  if constexpr (OUT_BF16) {
    u16* Cs = (u16*)smem;
    #pragma unroll
    for (int rt = 0; rt < 4; ++rt)
      #pragma unroll
      for (int r = 0; r < 4; ++r)
        Cs[(rt * 16 + q * 4 + r) * CSTR + tc] = f2bf(acc[rt][r] + bval);
  } else {
    float* Cs = (float*)smem;
    #pragma unroll
    for (int rt = 0; rt < 4; ++rt)
      #pragma unroll
      for (int r = 0; r < 4; ++r)
        Cs[(rt * 16 + q * 4 + r) * CSTR + tc] = acc[rt][r] + bval;
  }
  __syncthreads();
  const int cb = blockIdx.y * 128;
  const bool first = (cb < NH);
  const int LD = first ? NH : LD1;
  const int cc = first ? cb : (cb - NH);
  if constexpr (OUT_BF16) {
    u16* Cg = (u16*)(first ? C0v : C1v);
    constexpr int CPR = 16;
    #pragma unroll
    for (int it = 0; it < 64 * CPR / 512; ++it) {
      int ch = it * 512 + tid;
      int row = ch / CPR, co = (ch % CPR) * 8;
      int grow = row0 + row;
      if (grow < NNODES) {
        uint4 v = *reinterpret_cast<const uint4*>(&((u16*)smem)[row * CSTR + co]);
        *reinterpret_cast<uint4*>(Cg + (size_t)grow * LD + cc + co) = v;
      }
    }
  } else {
    float* Cg = (float*)(first ? C0v : C1v);
    constexpr int CPR = 32;
    #pragma unroll
    for (int it = 0; it < 64 * CPR / 512; ++it) {
      int ch = it * 512 + tid;
      int row = ch / CPR, co = (ch % CPR) * 4;
      int grow = row0 + row;
      if (grow < NNODES) {
        float4 v = *reinterpret_cast<const float4*>(&((float*)smem)[row * CSTR + co]);
        *reinterpret_cast<float4*>(Cg + (size_t)grow * LD + cc + co) = v;
      }
    }
  }
}

// ---------------- fused GATv2 edge pass: single pass, software-pipelined ----------------
// metadata prefetch depth 4, gathered-row prefetch depth 2 (clamped indices, no branches)

template<int HEADS, int CHAN, bool OUTBF>
__global__ __launch_bounds__(256) void gat_edge(
    const int* __restrict__ offs, const int* __restrict__ cnt,
    const int2* __restrict__ epair,
    const u16* __restrict__ xl, const u16* __restrict__ xr,
    const float* __restrict__ att, const float* __restrict__ We,
    const float* __restrict__ cb, void* __restrict__ houtv) {
  constexpr int HC = HEADS * CHAN;
  constexpr int EPL = HC / 64;       // elements per lane (4 or 2)
  constexpr int GRP = 64 / HEADS;    // lanes per head group (16 or 64)
  static_assert(EPL * 64 == HC, "layout");
  using ldT = typename std::conditional<EPL == 4, uint2, unsigned>::type;

  int node = __builtin_amdgcn_readfirstlane((int)(blockIdx.x * 4 + (threadIdx.x >> 6)));
  if (node >= NNODES) return;
  const int lane = threadIdx.x & 63;
  const int base_c = lane * EPL;
  float xrv[EPL], attv[EPL], wev[EPL], cbv[EPL];
  #pragma unroll
  for (int j = 0; j < EPL; ++j) {
    xrv[j]  = bf2f(xr[(size_t)node * HC + base_c + j]);
    attv[j] = att[base_c + j];
    wev[j]  = We[base_c + j];
    cbv[j]  = cb[base_c + j];
  }
  const int off = __builtin_amdgcn_readfirstlane(offs[node]);
  const int deg = __builtin_amdgcn_readfirstlane(cnt[node]);

  float den = 0.f;
  float accv[EPL];
  #pragma unroll
  for (int j = 0; j < EPL; ++j) accv[j] = 0.f;

  if (deg > 0) {
    const int last = deg - 1;
    auto cl = [&](int j) { return off + (j < last ? j : last); };
    auto rowload = [&](int s) {
      return *reinterpret_cast<const ldT*>(xl + (size_t)s * HC + base_c);
    };
    // prologue: meta 0..3, rows 0..1
    int2 p0 = epair[off];
    int2 p1 = epair[cl(1)];
    int2 p2 = epair[cl(2)];
    int2 p3 = epair[cl(3)];
    ldT r0 = rowload(p0.x);
    ldT r1 = rowload(p1.x);
    for (int j = 0; j < deg; ++j) {
      int2 pn = epair[cl(j + 4)];     // meta prefetch (wave-uniform addr)
      ldT rn = rowload(p2.x);         // row prefetch for edge j+2
      // compute edge j from r0 / p0
      float ea = __int_as_float(p0.y);
      float xlv[EPL];
      if constexpr (EPL == 4) {
        xlv[0] = bf2f(r0.x & 0xffffu); xlv[1] = bf2f(r0.x >> 16);
        xlv[2] = bf2f(r0.y & 0xffffu); xlv[3] = bf2f(r0.y >> 16);
      } else {
        xlv[0] = bf2f(r0 & 0xffffu); xlv[1] = bf2f(r0 >> 16);
      }
      float part = 0.f;
      #pragma unroll
      for (int jj = 0; jj < EPL; ++jj) {
        float m = xlv[jj] + xrv[jj] + ea * wev[jj];
        m = m > 0.f ? m : 0.2f * m;
        part += m * attv[jj];
      }
      #pragma unroll
      for (int d = 1; d < GRP; d <<= 1) part += __shfl_xor(part, d, 64);
      float e = __expf(part);
      den += e;
      #pragma unroll
      for (int jj = 0; jj < EPL; ++jj) accv[jj] += e * xlv[jj];
      // shift pipeline
      p0 = p1; p1 = p2; p2 = p3; p3 = pn;
      r0 = r1; r1 = rn;
    }
  }
  float inv = 1.0f / (den + 1e-16f);
  #pragma unroll
  for (int j = 0; j < EPL; ++j) accv[j] = accv[j] * inv + cbv[j];

  if constexpr (OUTBF) {
    u16* hout = (u16*)houtv + (size_t)node * HC + base_c;
    if constexpr (EPL == 4) {
      uint2 pk;
      pk.x = (unsigned)f2bf(accv[0]) | ((unsigned)f2bf(accv[1]) << 16);
      pk.y = (unsigned)f2bf(accv[2]) | ((unsigned)f2bf(accv[3]) << 16);
      *reinterpret_cast<uint2*>(hout) = pk;
    } else {
      unsigned pk = (unsigned)f2bf(accv[0]) | ((unsigned)f2bf(accv[1]) << 16);
      *reinterpret_cast<unsigned*>(hout) = pk;
    }
  } else {
    float* hout = (float*)houtv + (size_t)node * HC + base_c;
    if constexpr (EPL == 4) {
      float4 st; st.x = accv[0]; st.y = accv[1]; st.z = accv[2]; st.w = accv[3];
      *reinterpret_cast<float4*>(hout) = st;
    } else {
      float2 st; st.x = accv[0]; st.y = accv[1];
      *reinterpret_cast<float2*>(hout) = st;
    }
  }
}

// ---------------- BatchNorm ----------------

template<int NC>
__global__ void bn_stats_bf(const u16* __restrict__ h, float* __restrict__ sum, float* __restrict__ sq) {
  int c = threadIdx.x;
  float s = 0.f, q = 0.f;
  for (int r = blockIdx.x; r < NNODES; r += gridDim.x) {
    float v = bf2f(h[(size_t)r * NC + c]);
    s += v; q += v * v;
  }
  atomicAdd(&sum[c], s);
  atomicAdd(&sq[c], q);
}

template<int NC>
__global__ __launch_bounds__(256) void bn_prelu_apply(
    const u16* __restrict__ h, const float* __restrict__ sum, const float* __restrict__ sq,
    const float* __restrict__ g, const float* __restrict__ bb_,
    const float* __restrict__ pap, u16* __restrict__ outp, int total) {
  int i = (blockIdx.x * 256 + threadIdx.x) * 4;
  if (i >= total) return;
  const float invN = 1.0f / (float)NNODES;
  float pa = pap[0];
  int c = i & (NC - 1);
  float4 sm = *reinterpret_cast<const float4*>(sum + c);
  float4 qq = *reinterpret_cast<const float4*>(sq + c);
  float4 gg = *reinterpret_cast<const float4*>(g + c);
  float4 bb = *reinterpret_cast<const float4*>(bb_ + c);
  float mu, var, sc[4], sh[4];
  mu = sm.x * invN; var = qq.x * invN - mu * mu; sc[0] = gg.x * rsqrtf(var + 1e-5f); sh[0] = bb.x - mu * sc[0];
  mu = sm.y * invN; var = qq.y * invN - mu * mu; sc[1] = gg.y * rsqrtf(var + 1e-5f); sh[1] = bb.y - mu * sc[1];
  mu = sm.z * invN; var = qq.z * invN - mu * mu; sc[2] = gg.z * rsqrtf(var + 1e-5f); sh[2] = bb.z - mu * sc[2];
  mu = sm.w * invN; var = qq.w * invN - mu * mu; sc[3] = gg.w * rsqrtf(var + 1e-5f); sh[3] = bb.w - mu * sc[3];
  uint2 raw = *reinterpret_cast<const uint2*>(h + i);
  float v0 = bf2f(raw.x & 0xffffu), v1 = bf2f(raw.x >> 16);
  float v2 = bf2f(raw.y & 0xffffu), v3 = bf2f(raw.y >> 16);
  float o0 = v0 * sc[0] + sh[0]; o0 = o0 > 0.f ? o0 : pa * o0;
  float o1 = v1 * sc[1] + sh[1]; o1 = o1 > 0.f ? o1 : pa * o1;
  float o2 = v2 * sc[2] + sh[2]; o2 = o2 > 0.f ? o2 : pa * o2;
  float o3 = v3 * sc[3] + sh[3]; o3 = o3 > 0.f ? o3 : pa * o3;
  uint2 pk;
  pk.x = (unsigned)f2bf(o0) | ((unsigned)f2bf(o1) << 16);
  pk.y = (unsigned)f2bf(o2) | ((unsigned)f2bf(o3) << 16);
  *reinterpret_cast<uint2*>(outp + i) = pk;
}

__global__ __launch_bounds__(256) void final_out_k(
    const u16* __restrict__ h2, const float* __restrict__ skip,
    const float* __restrict__ sum, const float* __restrict__ sq,
    const float* __restrict__ g, const float* __restrict__ bb_,
    const float* __restrict__ pap, float* __restrict__ outp, int total) {
  int i = (blockIdx.x * 256 + threadIdx.x) * 4;
  if (i >= total) return;
  const float invN = 1.0f / (float)NNODES;
  float pa = pap[0];
  int c = i & 127;
  float4 sm = *reinterpret_cast<const float4*>(sum + c);
  float4 qq = *reinterpret_cast<const float4*>(sq + c);
  float4 gg = *reinterpret_cast<const float4*>(g + c);
  float4 bb = *reinterpret_cast<const float4*>(bb_ + c);
  float mu, var, sc[4], sh[4];
  mu = sm.x * invN; var = qq.x * invN - mu * mu; sc[0] = gg.x * rsqrtf(var + 1e-5f); sh[0] = bb.x - mu * sc[0];
  mu = sm.y * invN; var = qq.y * invN - mu * mu; sc[1] = gg.y * rsqrtf(var + 1e-5f); sh[1] = bb.y - mu * sc[1];
  mu = sm.z * invN; var = qq.z * invN - mu * mu; sc[2] = gg.z * rsqrtf(var + 1e-5f); sh[2] = bb.z - mu * sc[2];
  mu = sm.w * invN; var = qq.w * invN - mu * mu; sc[3] = gg.w * rsqrtf(var + 1e-5f); sh[3] = bb.w - mu * sc[3];
  uint2 raw = *reinterpret_cast<const uint2*>(h2 + i);
  float v0 = bf2f(raw.x & 0xffffu), v1 = bf2f(raw.x >> 16);
  float v2 = bf2f(raw.y & 0xffffu), v3 = bf2f(raw.y >> 16);
  float4 sk = *reinterpret_cast<const float4*>(skip + i);
  float4 o;
  o.x = v0 * sc[0] + sh[0]; o.x = (o.x > 0.f ? o.x : pa * o.x) + sk.x;
  o.y = v1 * sc[1] + sh[1]; o.y = (o.y > 0.f ? o.y : pa * o.y) + sk.y;
  o.z = v2 * sc[2] + sh[2]; o.z = (o.z > 0.f ? o.z : pa * o.z) + sk.z;
  o.w = v3 * sc[3] + sh[3]; o.w = (o.w > 0.f ? o.w : pa * o.w) + sk.w;
  *reinterpret_cast<float4*>(outp + i) = o;
}

// ---------------- launch ----------------

extern "C" void kernel_launch(void* const* d_in, const int* in_sizes, int n_in,
                              void* d_out, int out_size, void* d_ws, size_t ws_size,
                              hipStream_t stream) {
  (void)in_sizes; (void)n_in; (void)out_size; (void)ws_size;
  const float* x    = (const float*)d_in[0];
  const int*   ei   = (const int*)d_in[1];
  const float* ea   = (const float*)d_in[2];
  const float* Wl1  = (const float*)d_in[3];
  const float* bl1  = (const float*)d_in[4];
  const float* Wr1  = (const float*)d_in[5];
  const float* br1  = (const float*)d_in[6];
  const float* We1  = (const float*)d_in[7];
  const float* att1 = (const float*)d_in[8];
  const float* cb1  = (const float*)d_in[9];
  const float* bng1 = (const float*)d_in[10];
  const float* bnb1 = (const float*)d_in[11];
  const float* pa   = (const float*)d_in[12];
  const float* Wl2  = (const float*)d_in[13];
  const float* bl2  = (const float*)d_in[14];
  const float* Wr2  = (const float*)d_in[15];
  const float* br2  = (const float*)d_in[16];
  const float* We2  = (const float*)d_in[17];
  const float* att2 = (const float*)d_in[18];
  const float* cb2  = (const float*)d_in[19];
  const float* bng2 = (const float*)d_in[20];
  const float* bnb2 = (const float*)d_in[21];
  const float* skW  = (const float*)d_in[22];
  const float* skb  = (const float*)d_in[23];
  const int* srcp = ei;
  const int* dstp = ei + NEDGES;

  char* base = (char*)d_ws;
  size_t off = 0;
  auto alloc = [&](size_t bytes) -> char* {
    char* p = base + off;
    off = (off + bytes + 255) & ~(size_t)255;
    return p;
  };
  size_t zero_ints = 1 + NNODES + 256 + 256 + 128 + 128;
  char* zbase = alloc(zero_ints * 4);
  int*   totalp = (int*)zbase;
  int*   cnt    = totalp + 1;
  float* bnsum1 = (float*)(cnt + NNODES);
  float* bnsq1  = bnsum1 + 256;
  float* bnsum2 = bnsq1 + 256;
  float* bnsq2  = bnsum2 + 128;

  int*   offs    = (int*)alloc((size_t)NNODES * 4);
  int*   cursor  = (int*)alloc((size_t)NNODES * 4);
  int2*  epair   = (int2*)alloc((size_t)NEDGES * 8);
  const size_t RBYTES = (size_t)NNODES * DH1 * 2;  // 25.6 MB
  char* regionA = alloc(RBYTES);   // xl1(bf16) -> h1p(bf16) -> h2(bf16)
  char* regionB = alloc(RBYTES);   // xr1(bf16) -> skipbuf(f32)
  char* regionC = alloc(RBYTES);   // h1(bf16)  -> xl2+xr2(bf16)
  u16*   xbf    = (u16*)alloc((size_t)NNODES * 128 * 2);
  u16*   Wt1    = (u16*)alloc(512 * 128 * 2);
  u16*   Wt2    = (u16*)alloc(256 * 256 * 2);
  u16*   Wts    = (u16*)alloc(128 * 128 * 2);
  float* bias1  = (float*)alloc(512 * 4);
  float* bias2  = (float*)alloc(256 * 4);
  float* biasS  = (float*)alloc(128 * 4);

  u16*   xl1     = (u16*)regionA;
  u16*   xr1     = (u16*)regionB;
  u16*   h1      = (u16*)regionC;
  u16*   h1p     = (u16*)regionA;
  u16*   xl2     = (u16*)regionC;
  u16*   xr2     = (u16*)(regionC + (size_t)NNODES * DOUT * 2);
  float* skipbuf = (float*)regionB;
  u16*   h2      = (u16*)regionA;

  hipMemsetAsync(zbase, 0, zero_ints * 4, stream);

  const int EB = (NEDGES + 255) / 256;
  const int NB = (NNODES + 255) / 256;
  count_k<<<EB, 256, 0, stream>>>(dstp, cnt);
  offsets_k<<<NB, 256, 0, stream>>>(cnt, offs, cursor, totalp);
  scatter_k<<<EB, 256, 0, stream>>>(srcp, dstp, ea, cursor, epair);

  cvt_bf_k<<<(NNODES * 128 / 4 + 255) / 256, 256, 0, stream>>>(x, xbf, NNODES * 128);
  prep_all_k<<<dim3(256, 3), 256, 0, stream>>>(Wl1, Wr1, bl1, br1, Wl2, Wr2, bl2, br2,
                                               skW, skb, Wt1, bias1, Wt2, bias2, Wts, biasS);

  const int MB64 = (NNODES + 63) / 64;
  // layer 1
  gemm_mfma<128, 256, 512, true><<<dim3(MB64, 4), 512, 0, stream>>>(
      xbf, Wt1, bias1, (void*)xl1, (void*)xr1);
  gat_edge<4, 64, true><<<(NNODES + 3) / 4, 256, 0, stream>>>(
      offs, cnt, epair, xl1, xr1, att1, We1, cb1, (void*)h1);
  bn_stats_bf<256><<<800, 256, 0, stream>>>(h1, bnsum1, bnsq1);
  bn_prelu_apply<256><<<(NNODES * DH1 / 4 + 255) / 256, 256, 0, stream>>>(
      h1, bnsum1, bnsq1, bng1, bnb1, pa, h1p, NNODES * DH1);

  // layer 2 + skip
  gemm_mfma<256, 128, 256, true><<<dim3(MB64, 2), 512, 0, stream>>>(
      h1p, Wt2, bias2, (void*)xl2, (void*)xr2);
  gemm_mfma<128, 128, 128, false><<<dim3(MB64, 1), 512, 0, stream>>>(
      xbf, Wts, biasS, (void*)skipbuf, (void*)skipbuf);
  gat_edge<1, 128, true><<<(NNODES + 3) / 4, 256, 0, stream>>>(
      offs, cnt, epair, xl2, xr2, att2, We2, cb2, (void*)h2);
  bn_stats_bf<128><<<800, 128, 0, stream>>>(h2, bnsum2, bnsq2);
  final_out_k<<<(NNODES * DOUT / 4 + 255) / 256, 256, 0, stream>>>(
      h2, skipbuf, bnsum2, bnsq2, bng2, bnb2, pa, (float*)d_out, NNODES * DOUT);
}

// Round 6
// 520.440 us; speedup vs baseline: 1.6819x; 1.0482x over previous
//
#include <hip/hip_runtime.h>
#include <cstdint>
#include <cstddef>

#define NNODES 50000
#define NEDGES 800000
#define DH1    256   // H*HID = 4*64
#define DOUT   128

typedef unsigned short u16;
typedef __bf16 bf16x8 __attribute__((ext_vector_type(8)));
typedef float  f32x4  __attribute__((ext_vector_type(4)));

__device__ __forceinline__ float bf2f(unsigned int u) {
  union { unsigned int i; float f; } x; x.i = u << 16; return x.f;
}
__device__ __forceinline__ u16 f2bf(float f) {
  union { float f; unsigned int i; } x; x.f = f;
  unsigned int r = x.i + 0x7fffu + ((x.i >> 16) & 1u);  // round-to-nearest-even
  return (u16)(r >> 16);
}
__device__ __forceinline__ void dec8(uint4 r, float* o) {
  o[0] = bf2f(r.x & 0xffffu); o[1] = bf2f(r.x >> 16);
  o[2] = bf2f(r.y & 0xffffu); o[3] = bf2f(r.y >> 16);
  o[4] = bf2f(r.z & 0xffffu); o[5] = bf2f(r.z >> 16);
  o[6] = bf2f(r.w & 0xffffu); o[7] = bf2f(r.w >> 16);
}
__device__ __forceinline__ uint4 pack8(const float* v) {
  uint4 p;
  p.x = (unsigned)f2bf(v[0]) | ((unsigned)f2bf(v[1]) << 16);
  p.y = (unsigned)f2bf(v[2]) | ((unsigned)f2bf(v[3]) << 16);
  p.z = (unsigned)f2bf(v[4]) | ((unsigned)f2bf(v[5]) << 16);
  p.w = (unsigned)f2bf(v[6]) | ((unsigned)f2bf(v[7]) << 16);
  return p;
}

// ---------------- CSR build ----------------

__global__ __launch_bounds__(256) void count_k(const int* __restrict__ dst, int* __restrict__ cnt) {
  int e = blockIdx.x * 256 + threadIdx.x;
  if (e < NEDGES) atomicAdd(&cnt[dst[e]], 1);
}

__global__ __launch_bounds__(256) void offsets_k(const int* __restrict__ cnt, int* __restrict__ offs,
                                                 int* __restrict__ cursor, int* __restrict__ total) {
  int i = blockIdx.x * 256 + threadIdx.x;
  int lane = threadIdx.x & 63;
  int c = (i < NNODES) ? cnt[i] : 0;
  int incl = c;
  #pragma unroll
  for (int d = 1; d < 64; d <<= 1) {
    int t = __shfl_up(incl, d, 64);
    if (lane >= d) incl += t;
  }
  int wtotal = __shfl(incl, 63, 64);
  int base = 0;
  if (lane == 63) base = atomicAdd(total, wtotal);
  base = __shfl(base, 63, 64);
  int off = base + incl - c;
  if (i < NNODES) { offs[i] = off; cursor[i] = off; }
}

__global__ __launch_bounds__(256) void scatter_k(const int* __restrict__ src, const int* __restrict__ dst,
                                                 const float* __restrict__ ea, int* __restrict__ cursor,
                                                 int2* __restrict__ epair) {
  int e = blockIdx.x * 256 + threadIdx.x;
  if (e >= NEDGES) return;
  int d = dst[e];
  int p = atomicAdd(&cursor[d], 1);
  int2 v; v.x = src[e]; v.y = __float_as_int(ea[e]);
  epair[p] = v;
}

// ---------------- prep ----------------

__global__ __launch_bounds__(256) void cvt_bf_k(const float* __restrict__ in, u16* __restrict__ out, int total) {
  int i = (blockIdx.x * 256 + threadIdx.x) * 4;
  if (i >= total) return;
  float4 v = *reinterpret_cast<const float4*>(in + i);
  uint2 pk;
  pk.x = (unsigned)f2bf(v.x) | ((unsigned)f2bf(v.y) << 16);
  pk.y = (unsigned)f2bf(v.z) | ((unsigned)f2bf(v.w) << 16);
  *reinterpret_cast<uint2*>(out + i) = pk;
}

__global__ __launch_bounds__(256) void prep_all_k(
    const float* __restrict__ Wl1, const float* __restrict__ Wr1,
    const float* __restrict__ bl1, const float* __restrict__ br1,
    const float* __restrict__ Wl2, const float* __restrict__ Wr2,
    const float* __restrict__ bl2, const float* __restrict__ br2,
    const float* __restrict__ skW, const float* __restrict__ skb,
    u16* __restrict__ Wt1, float* __restrict__ bias1,
    u16* __restrict__ Wt2, float* __restrict__ bias2,
    u16* __restrict__ Wts, float* __restrict__ biasS) {
  int idx = blockIdx.x * 256 + threadIdx.x;
  int which = blockIdx.y;
  if (which == 0) {                         // K=128, NH=256, NTOT=512
    if (idx < 512) bias1[idx] = (idx < 256) ? bl1[idx] : br1[idx - 256];
    int n = idx >> 7, k = idx & 127;
    float v = (n < 256) ? Wl1[k * 256 + n] : Wr1[k * 256 + (n - 256)];
    Wt1[idx] = f2bf(v);
  } else if (which == 1) {                  // K=256, NH=128, NTOT=256
    if (idx < 256) bias2[idx] = (idx < 128) ? bl2[idx] : br2[idx - 128];
    int n = idx >> 8, k = idx & 255;
    float v = (n < 128) ? Wl2[k * 128 + n] : Wr2[k * 128 + (n - 128)];
    Wt2[idx] = f2bf(v);
  } else {                                  // K=128, N=128
    if (idx < 128) biasS[idx] = skb[idx];
    if (idx < 128 * 128) {
      int n = idx >> 7, k = idx & 127;
      Wts[idx] = f2bf(skW[k * 128 + n]);
    }
  }
}

// ---------------- MFMA GEMM (unchanged from round 4) ----------------

template<int K, int NH, int NTOT, bool OUT_BF16>
__global__ __launch_bounds__(512) void gemm_mfma(
    const u16* __restrict__ A, const u16* __restrict__ Wt, const float* __restrict__ bias,
    void* __restrict__ C0v, void* __restrict__ C1v) {
  constexpr int LDA = K + 8;
  constexpr int LD1 = (NTOT - NH) > 0 ? (NTOT - NH) : 1;
  constexpr int CSTR = OUT_BF16 ? 136 : 132;
  constexpr size_t ABYTES = (size_t)64 * LDA * 2;
  constexpr size_t CBYTES = (size_t)64 * CSTR * (OUT_BF16 ? 2 : 4);
  constexpr size_t SBYTES = ABYTES > CBYTES ? ABYTES : CBYTES;
  __shared__ __align__(16) char smem[SBYTES];
  u16* As = (u16*)smem;
  const int row0 = blockIdx.x * 64;
  const int tid = threadIdx.x;
  #pragma unroll
  for (int it = 0; it < K / 32; ++it) {
    int chunk = it * 512 + tid;
    int row = (chunk * 4) / K;
    int col = (chunk * 4) % K;
    uint2 v; v.x = 0u; v.y = 0u;
    int gr = row0 + row;
    if (gr < NNODES) v = *reinterpret_cast<const uint2*>(A + (size_t)gr * K + col);
    *reinterpret_cast<uint2*>(&As[row * LDA + col]) = v;
  }
  __syncthreads();
  const int w = tid >> 6, lane = tid & 63, q = lane >> 4, l16 = lane & 15;
  const int tc = w * 16 + l16;
  const int ncol = blockIdx.y * 128 + tc;
  f32x4 acc[4];
  #pragma unroll
  for (int rt = 0; rt < 4; ++rt) acc[rt] = (f32x4){0.f, 0.f, 0.f, 0.f};
  const u16* wp = Wt + (size_t)ncol * K + q * 8;
  #pragma unroll
  for (int ks = 0; ks < K / 32; ++ks) {
    bf16x8 b = *reinterpret_cast<const bf16x8*>(wp + ks * 32);
    #pragma unroll
    for (int rt = 0; rt < 4; ++rt) {
      bf16x8 a = *reinterpret_cast<const bf16x8*>(&As[(rt * 16 + l16) * LDA + ks * 32 + q * 8]);
      acc[rt] = __builtin_amdgcn_mfma_f32_16x16x32_bf16(a, b, acc[rt], 0, 0, 0);
    }
  }
  const float bval = bias[ncol];
  __syncthreads();
  if constexpr (OUT_BF16) {
    u16* Cs = (u16*)smem;
    #pragma unroll
    for (int rt = 0; rt < 4; ++rt)
      #pragma unroll
      for (int r = 0; r < 4; ++r)
        Cs[(rt * 16 + q * 4 + r) * CSTR + tc] = f2bf(acc[rt][r] + bval);
  } else {
    float* Cs = (float*)smem;
    #pragma unroll
    for (int rt = 0; rt < 4; ++rt)
      #pragma unroll
      for (int r = 0; r < 4; ++r)
        Cs[(rt * 16 + q * 4 + r) * CSTR + tc] = acc[rt][r] + bval;
  }
  __syncthreads();
  const int cb = blockIdx.y * 128;
  const bool first = (cb < NH);
  const int LD = first ? NH : LD1;
  const int cc = first ? cb : (cb - NH);
  if constexpr (OUT_BF16) {
    u16* Cg = (u16*)(first ? C0v : C1v);
    constexpr int CPR = 16;
    #pragma unroll
    for (int it = 0; it < 64 * CPR / 512; ++it) {
      int ch = it * 512 + tid;
      int row = ch / CPR, co = (ch % CPR) * 8;
      int grow = row0 + row;
      if (grow < NNODES) {
        uint4 v = *reinterpret_cast<const uint4*>(&((u16*)smem)[row * CSTR + co]);
        *reinterpret_cast<uint4*>(Cg + (size_t)grow * LD + cc + co) = v;
      }
    }
  } else {
    float* Cg = (float*)(first ? C0v : C1v);
    constexpr int CPR = 32;
    #pragma unroll
    for (int it = 0; it < 64 * CPR / 512; ++it) {
      int ch = it * 512 + tid;
      int row = ch / CPR, co = (ch % CPR) * 4;
      int grow = row0 + row;
      if (grow < NNODES) {
        float4 v = *reinterpret_cast<const float4*>(&((float*)smem)[row * CSTR + co]);
        *reinterpret_cast<float4*>(Cg + (size_t)grow * LD + cc + co) = v;
      }
    }
  }
}

// ---------------- GATv2 edge pass: 4 edges per wave (16 lanes per edge) ----------------
// Wave = 1 dst node. Group g (lanes 16g..16g+15) processes edges j = 4i+g.
// Lane owns CPL = HC/16 consecutive channels. Head cluster = CHAN/CPL lanes.
// e masked to 0 for clamped tail edges; group partials combined via shfl_xor(16,32).

template<int HEADS, int CHAN>
__global__ __launch_bounds__(256) void gat_edge(
    const int* __restrict__ offs, const int* __restrict__ cnt,
    const int2* __restrict__ epair,
    const u16* __restrict__ xl, const u16* __restrict__ xr,
    const float* __restrict__ att, const float* __restrict__ We,
    const float* __restrict__ cb, u16* __restrict__ hout) {
  constexpr int HC  = HEADS * CHAN;
  constexpr int CPL = HC / 16;        // channels per lane (16 or 8)
  constexpr int NCH = CPL / 8;        // uint4 chunks per lane (2 or 1)
  constexpr int LPH = CHAN / CPL;     // lanes per head cluster (4 or 16)
  static_assert(NCH * 8 == CPL && LPH * CPL == CHAN, "layout");

  int node = __builtin_amdgcn_readfirstlane((int)(blockIdx.x * 4 + (threadIdx.x >> 6)));
  if (node >= NNODES) return;
  const int lane = threadIdx.x & 63;
  const int g    = lane >> 4;
  const int l16  = lane & 15;
  const int cbase = l16 * CPL;

  float xrv[CPL], attv[CPL], wev[CPL];
  {
    const uint4* xrp = reinterpret_cast<const uint4*>(xr + (size_t)node * HC + cbase);
    #pragma unroll
    for (int c = 0; c < NCH; ++c) dec8(xrp[c], &xrv[c * 8]);
    #pragma unroll
    for (int c = 0; c < CPL / 4; ++c) {
      float4 a = *reinterpret_cast<const float4*>(att + cbase + c * 4);
      float4 w = *reinterpret_cast<const float4*>(We  + cbase + c * 4);
      attv[c*4+0] = a.x; attv[c*4+1] = a.y; attv[c*4+2] = a.z; attv[c*4+3] = a.w;
      wev [c*4+0] = w.x; wev [c*4+1] = w.y; wev [c*4+2] = w.z; wev [c*4+3] = w.w;
    }
  }
  const int off = __builtin_amdgcn_readfirstlane(offs[node]);
  const int deg = __builtin_amdgcn_readfirstlane(cnt[node]);

  float den = 0.f;
  float accv[CPL];
  #pragma unroll
  for (int j = 0; j < CPL; ++j) accv[j] = 0.f;

  if (deg > 0) {
    const int last = deg - 1;
    auto midx = [&](int i) { int j = i * 4 + g; return off + (j < last ? j : last); };
    auto rowp = [&](int s) { return reinterpret_cast<const uint4*>(xl + (size_t)s * HC + cbase); };
    const int niter = (deg + 3) >> 2;
    int2 p_cur = epair[midx(0)];
    int2 p_nxt = epair[midx(1)];
    uint4 r_cur[NCH], r_nxt[NCH];
    { const uint4* rp = rowp(p_cur.x);
      #pragma unroll
      for (int c = 0; c < NCH; ++c) r_cur[c] = rp[c]; }
    for (int i = 0; i < niter; ++i) {
      int2 p_n2 = epair[midx(i + 2)];
      { const uint4* rp = rowp(p_nxt.x);
        #pragma unroll
        for (int c = 0; c < NCH; ++c) r_nxt[c] = rp[c]; }
      float ea = __int_as_float(p_cur.y);
      float xlv[CPL];
      #pragma unroll
      for (int c = 0; c < NCH; ++c) dec8(r_cur[c], &xlv[c * 8]);
      float part = 0.f;
      #pragma unroll
      for (int jj = 0; jj < CPL; ++jj) {
        float m = xlv[jj] + xrv[jj] + ea * wev[jj];
        m = m > 0.f ? m : 0.2f * m;
        part += m * attv[jj];
      }
      #pragma unroll
      for (int d = 1; d < LPH; d <<= 1) part += __shfl_xor(part, d, 64);
      float valid = (i * 4 + g <= last) ? 1.f : 0.f;
      float e = __expf(part) * valid;
      den += e;
      #pragma unroll
      for (int jj = 0; jj < CPL; ++jj) accv[jj] += e * xlv[jj];
      p_cur = p_nxt; p_nxt = p_n2;
      #pragma unroll
      for (int c = 0; c < NCH; ++c) r_cur[c] = r_nxt[c];
    }
  }
  // combine the 4 groups (butterfly over lane bits 16, 32)
  den += __shfl_xor(den, 16, 64);
  den += __shfl_xor(den, 32, 64);
  #pragma unroll
  for (int jj = 0; jj < CPL; ++jj) {
    accv[jj] += __shfl_xor(accv[jj], 16, 64);
    accv[jj] += __shfl_xor(accv[jj], 32, 64);
  }
  if (g == 0) {
    float inv = 1.0f / (den + 1e-16f);
    float ov[CPL];
    #pragma unroll
    for (int c = 0; c < CPL / 4; ++c) {
      float4 cv = *reinterpret_cast<const float4*>(cb + cbase + c * 4);
      ov[c*4+0] = accv[c*4+0] * inv + cv.x;
      ov[c*4+1] = accv[c*4+1] * inv + cv.y;
      ov[c*4+2] = accv[c*4+2] * inv + cv.z;
      ov[c*4+3] = accv[c*4+3] * inv + cv.w;
    }
    uint4* op = reinterpret_cast<uint4*>(hout + (size_t)node * HC + cbase);
    #pragma unroll
    for (int c = 0; c < NCH; ++c) op[c] = pack8(&ov[c * 8]);
  }
}

// ---------------- BatchNorm ----------------

template<int NC>
__global__ void bn_stats_bf(const u16* __restrict__ h, float* __restrict__ sum, float* __restrict__ sq) {
  int c = threadIdx.x;
  float s = 0.f, q = 0.f;
  for (int r = blockIdx.x; r < NNODES; r += gridDim.x) {
    float v = bf2f(h[(size_t)r * NC + c]);
    s += v; q += v * v;
  }
  atomicAdd(&sum[c], s);
  atomicAdd(&sq[c], q);
}

template<int NC>
__global__ __launch_bounds__(256) void bn_prelu_apply(
    const u16* __restrict__ h, const float* __restrict__ sum, const float* __restrict__ sq,
    const float* __restrict__ g, const float* __restrict__ bb_,
    const float* __restrict__ pap, u16* __restrict__ outp, int total) {
  int i = (blockIdx.x * 256 + threadIdx.x) * 4;
  if (i >= total) return;
  const float invN = 1.0f / (float)NNODES;
  float pa = pap[0];
  int c = i & (NC - 1);
  float4 sm = *reinterpret_cast<const float4*>(sum + c);
  float4 qq = *reinterpret_cast<const float4*>(sq + c);
  float4 gg = *reinterpret_cast<const float4*>(g + c);
  float4 bb = *reinterpret_cast<const float4*>(bb_ + c);
  float mu, var, sc[4], sh[4];
  mu = sm.x * invN; var = qq.x * invN - mu * mu; sc[0] = gg.x * rsqrtf(var + 1e-5f); sh[0] = bb.x - mu * sc[0];
  mu = sm.y * invN; var = qq.y * invN - mu * mu; sc[1] = gg.y * rsqrtf(var + 1e-5f); sh[1] = bb.y - mu * sc[1];
  mu = sm.z * invN; var = qq.z * invN - mu * mu; sc[2] = gg.z * rsqrtf(var + 1e-5f); sh[2] = bb.z - mu * sc[2];
  mu = sm.w * invN; var = qq.w * invN - mu * mu; sc[3] = gg.w * rsqrtf(var + 1e-5f); sh[3] = bb.w - mu * sc[3];
  uint2 raw = *reinterpret_cast<const uint2*>(h + i);
  float v0 = bf2f(raw.x & 0xffffu), v1 = bf2f(raw.x >> 16);
  float v2 = bf2f(raw.y & 0xffffu), v3 = bf2f(raw.y >> 16);
  float o0 = v0 * sc[0] + sh[0]; o0 = o0 > 0.f ? o0 : pa * o0;
  float o1 = v1 * sc[1] + sh[1]; o1 = o1 > 0.f ? o1 : pa * o1;
  float o2 = v2 * sc[2] + sh[2]; o2 = o2 > 0.f ? o2 : pa * o2;
  float o3 = v3 * sc[3] + sh[3]; o3 = o3 > 0.f ? o3 : pa * o3;
  uint2 pk;
  pk.x = (unsigned)f2bf(o0) | ((unsigned)f2bf(o1) << 16);
  pk.y = (unsigned)f2bf(o2) | ((unsigned)f2bf(o3) << 16);
  *reinterpret_cast<uint2*>(outp + i) = pk;
}

__global__ __launch_bounds__(256) void final_out_k(
    const u16* __restrict__ h2, const float* __restrict__ skip,
    const float* __restrict__ sum, const float* __restrict__ sq,
    const float* __restrict__ g, const float* __restrict__ bb_,
    const float* __restrict__ pap, float* __restrict__ outp, int total) {
  int i = (blockIdx.x * 256 + threadIdx.x) * 4;
  if (i >= total) return;
  const float invN = 1.0f / (float)NNODES;
  float pa = pap[0];
  int c = i & 127;
  float4 sm = *reinterpret_cast<const float4*>(sum + c);
  float4 qq = *reinterpret_cast<const float4*>(sq + c);
  float4 gg = *reinterpret_cast<const float4*>(g + c);
  float4 bb = *reinterpret_cast<const float4*>(bb_ + c);
  float mu, var, sc[4], sh[4];
  mu = sm.x * invN; var = qq.x * invN - mu * mu; sc[0] = gg.x * rsqrtf(var + 1e-5f); sh[0] = bb.x - mu * sc[0];
  mu = sm.y * invN; var = qq.y * invN - mu * mu; sc[1] = gg.y * rsqrtf(var + 1e-5f); sh[1] = bb.y - mu * sc[1];
  mu = sm.z * invN; var = qq.z * invN - mu * mu; sc[2] = gg.z * rsqrtf(var + 1e-5f); sh[2] = bb.z - mu * sc[2];
  mu = sm.w * invN; var = qq.w * invN - mu * mu; sc[3] = gg.w * rsqrtf(var + 1e-5f); sh[3] = bb.w - mu * sc[3];
  uint2 raw = *reinterpret_cast<const uint2*>(h2 + i);
  float v0 = bf2f(raw.x & 0xffffu), v1 = bf2f(raw.x >> 16);
  float v2 = bf2f(raw.y & 0xffffu), v3 = bf2f(raw.y >> 16);
  float4 sk = *reinterpret_cast<const float4*>(skip + i);
  float4 o;
  o.x = v0 * sc[0] + sh[0]; o.x = (o.x > 0.f ? o.x : pa * o.x) + sk.x;
  o.y = v1 * sc[1] + sh[1]; o.y = (o.y > 0.f ? o.y : pa * o.y) + sk.y;
  o.z = v2 * sc[2] + sh[2]; o.z = (o.z > 0.f ? o.z : pa * o.z) + sk.z;
  o.w = v3 * sc[3] + sh[3]; o.w = (o.w > 0.f ? o.w : pa * o.w) + sk.w;
  *reinterpret_cast<float4*>(outp + i) = o;
}

// ---------------- launch ----------------

extern "C" void kernel_launch(void* const* d_in, const int* in_sizes, int n_in,
                              void* d_out, int out_size, void* d_ws, size_t ws_size,
                              hipStream_t stream) {
  (void)in_sizes; (void)n_in; (void)out_size; (void)ws_size;
  const float* x    = (const float*)d_in[0];
  const int*   ei   = (const int*)d_in[1];
  const float* ea   = (const float*)d_in[2];
  const float* Wl1  = (const float*)d_in[3];
  const float* bl1  = (const float*)d_in[4];
  const float* Wr1  = (const float*)d_in[5];
  const float* br1  = (const float*)d_in[6];
  const float* We1  = (const float*)d_in[7];
  const float* att1 = (const float*)d_in[8];
  const float* cb1  = (const float*)d_in[9];
  const float* bng1 = (const float*)d_in[10];
  const float* bnb1 = (const float*)d_in[11];
  const float* pa   = (const float*)d_in[12];
  const float* Wl2  = (const float*)d_in[13];
  const float* bl2  = (const float*)d_in[14];
  const float* Wr2  = (const float*)d_in[15];
  const float* br2  = (const float*)d_in[16];
  const float* We2  = (const float*)d_in[17];
  const float* att2 = (const float*)d_in[18];
  const float* cb2  = (const float*)d_in[19];
  const float* bng2 = (const float*)d_in[20];
  const float* bnb2 = (const float*)d_in[21];
  const float* skW  = (const float*)d_in[22];
  const float* skb  = (const float*)d_in[23];
  const int* srcp = ei;
  const int* dstp = ei + NEDGES;

  char* base = (char*)d_ws;
  size_t off = 0;
  auto alloc = [&](size_t bytes) -> char* {
    char* p = base + off;
    off = (off + bytes + 255) & ~(size_t)255;
    return p;
  };
  size_t zero_ints = 1 + NNODES + 256 + 256 + 128 + 128;
  char* zbase = alloc(zero_ints * 4);
  int*   totalp = (int*)zbase;
  int*   cnt    = totalp + 1;
  float* bnsum1 = (float*)(cnt + NNODES);
  float* bnsq1  = bnsum1 + 256;
  float* bnsum2 = bnsq1 + 256;
  float* bnsq2  = bnsum2 + 128;

  int*   offs    = (int*)alloc((size_t)NNODES * 4);
  int*   cursor  = (int*)alloc((size_t)NNODES * 4);
  int2*  epair   = (int2*)alloc((size_t)NEDGES * 8);
  const size_t RBYTES = (size_t)NNODES * DH1 * 2;  // 25.6 MB
  char* regionA = alloc(RBYTES);   // xl1(bf16) -> h1p(bf16) -> h2(bf16)
  char* regionB = alloc(RBYTES);   // xr1(bf16) -> skipbuf(f32)
  char* regionC = alloc(RBYTES);   // h1(bf16)  -> xl2+xr2(bf16)
  u16*   xbf    = (u16*)alloc((size_t)NNODES * 128 * 2);
  u16*   Wt1    = (u16*)alloc(512 * 128 * 2);
  u16*   Wt2    = (u16*)alloc(256 * 256 * 2);
  u16*   Wts    = (u16*)alloc(128 * 128 * 2);
  float* bias1  = (float*)alloc(512 * 4);
  float* bias2  = (float*)alloc(256 * 4);
  float* biasS  = (float*)alloc(128 * 4);

  u16*   xl1     = (u16*)regionA;
  u16*   xr1     = (u16*)regionB;
  u16*   h1      = (u16*)regionC;
  u16*   h1p     = (u16*)regionA;
  u16*   xl2     = (u16*)regionC;
  u16*   xr2     = (u16*)(regionC + (size_t)NNODES * DOUT * 2);
  float* skipbuf = (float*)regionB;
  u16*   h2      = (u16*)regionA;

  hipMemsetAsync(zbase, 0, zero_ints * 4, stream);

  const int EB = (NEDGES + 255) / 256;
  const int NB = (NNODES + 255) / 256;
  count_k<<<EB, 256, 0, stream>>>(dstp, cnt);
  offsets_k<<<NB, 256, 0, stream>>>(cnt, offs, cursor, totalp);
  scatter_k<<<EB, 256, 0, stream>>>(srcp, dstp, ea, cursor, epair);

  cvt_bf_k<<<(NNODES * 128 / 4 + 255) / 256, 256, 0, stream>>>(x, xbf, NNODES * 128);
  prep_all_k<<<dim3(256, 3), 256, 0, stream>>>(Wl1, Wr1, bl1, br1, Wl2, Wr2, bl2, br2,
                                               skW, skb, Wt1, bias1, Wt2, bias2, Wts, biasS);

  const int MB64 = (NNODES + 63) / 64;
  // layer 1
  gemm_mfma<128, 256, 512, true><<<dim3(MB64, 4), 512, 0, stream>>>(
      xbf, Wt1, bias1, (void*)xl1, (void*)xr1);
  gat_edge<4, 64><<<(NNODES + 3) / 4, 256, 0, stream>>>(
      offs, cnt, epair, xl1, xr1, att1, We1, cb1, h1);
  bn_stats_bf<256><<<800, 256, 0, stream>>>(h1, bnsum1, bnsq1);
  bn_prelu_apply<256><<<(NNODES * DH1 / 4 + 255) / 256, 256, 0, stream>>>(
      h1, bnsum1, bnsq1, bng1, bnb1, pa, h1p, NNODES * DH1);

  // layer 2 + skip
  gemm_mfma<256, 128, 256, true><<<dim3(MB64, 2), 512, 0, stream>>>(
      h1p, Wt2, bias2, (void*)xl2, (void*)xr2);
  gemm_mfma<128, 128, 128, false><<<dim3(MB64, 1), 512, 0, stream>>>(
      xbf, Wts, biasS, (void*)skipbuf, (void*)skipbuf);
  gat_edge<1, 128><<<(NNODES + 3) / 4, 256, 0, stream>>>(
      offs, cnt, epair, xl2, xr2, att2, We2, cb2, h2);
  bn_stats_bf<128><<<800, 128, 0, stream>>>(h2, bnsum2, bnsq2);
  final_out_k<<<(NNODES * DOUT / 4 + 255) / 256, 256, 0, stream>>>(
      h2, skipbuf, bnsum2, bnsq2, bng2, bnb2, pa, (float*)d_out, NNODES * DOUT);
}

// Round 7
// 491.858 us; speedup vs baseline: 1.7796x; 1.0581x over previous
//
#include <hip/hip_runtime.h>
#include <cstdint>
#include <cstddef>

#define NNODES 50000
#define NEDGES 800000
#define DH1    256   // H*HID = 4*64
#define DOUT   128

typedef unsigned short u16;
typedef __bf16 bf16x8 __attribute__((ext_vector_type(8)));
typedef float  f32x4  __attribute__((ext_vector_type(4)));

__device__ __forceinline__ float bf2f(unsigned int u) {
  union { unsigned int i; float f; } x; x.i = u << 16; return x.f;
}
__device__ __forceinline__ u16 f2bf(float f) {
  union { float f; unsigned int i; } x; x.f = f;
  unsigned int r = x.i + 0x7fffu + ((x.i >> 16) & 1u);  // round-to-nearest-even
  return (u16)(r >> 16);
}
__device__ __forceinline__ void dec8(uint4 r, float* o) {
  o[0] = bf2f(r.x & 0xffffu); o[1] = bf2f(r.x >> 16);
  o[2] = bf2f(r.y & 0xffffu); o[3] = bf2f(r.y >> 16);
  o[4] = bf2f(r.z & 0xffffu); o[5] = bf2f(r.z >> 16);
  o[6] = bf2f(r.w & 0xffffu); o[7] = bf2f(r.w >> 16);
}
__device__ __forceinline__ uint4 pack8(const float* v) {
  uint4 p;
  p.x = (unsigned)f2bf(v[0]) | ((unsigned)f2bf(v[1]) << 16);
  p.y = (unsigned)f2bf(v[2]) | ((unsigned)f2bf(v[3]) << 16);
  p.z = (unsigned)f2bf(v[4]) | ((unsigned)f2bf(v[5]) << 16);
  p.w = (unsigned)f2bf(v[6]) | ((unsigned)f2bf(v[7]) << 16);
  return p;
}

// ---------------- setup: count + cvt + weight-prep + att*We scalars ----------------

#define CNT_BLKS 3125
#define CVT_BLKS 6250
#define W1_BLKS  320
#define W2_BLKS  256

__global__ __launch_bounds__(256) void setup_k(
    const int* __restrict__ dst, int* __restrict__ cnt,
    const float* __restrict__ x, u16* __restrict__ xbf,
    const float* __restrict__ Wl1, const float* __restrict__ Wr1,
    const float* __restrict__ bl1, const float* __restrict__ br1,
    const float* __restrict__ Wl2, const float* __restrict__ Wr2,
    const float* __restrict__ bl2, const float* __restrict__ br2,
    const float* __restrict__ skW, const float* __restrict__ skb,
    const float* __restrict__ att1, const float* __restrict__ We1,
    const float* __restrict__ att2, const float* __restrict__ We2,
    u16* __restrict__ Wcat1, float* __restrict__ bias1,
    u16* __restrict__ Wt2, float* __restrict__ bias2,
    float* __restrict__ axw) {
  int b = blockIdx.x, t = threadIdx.x;
  if (b < CNT_BLKS) {
    int e = b * 256 + t;
    if (e < NEDGES) atomicAdd(&cnt[dst[e]], 1);
  } else if (b < CNT_BLKS + CVT_BLKS) {
    int i = ((b - CNT_BLKS) * 256 + t) * 4;
    float4 v = *reinterpret_cast<const float4*>(x + i);
    uint2 pk;
    pk.x = (unsigned)f2bf(v.x) | ((unsigned)f2bf(v.y) << 16);
    pk.y = (unsigned)f2bf(v.z) | ((unsigned)f2bf(v.w) << 16);
    *reinterpret_cast<uint2*>(xbf + i) = pk;
  } else if (b < CNT_BLKS + CVT_BLKS + W1_BLKS) {
    int idx = (b - CNT_BLKS - CVT_BLKS) * 256 + t;   // 640 x 128
    if (idx < 640) bias1[idx] = idx < 256 ? bl1[idx] : idx < 512 ? br1[idx - 256] : skb[idx - 512];
    int n = idx >> 7, k = idx & 127;
    float v = n < 256 ? Wl1[k * 256 + n] : n < 512 ? Wr1[k * 256 + (n - 256)] : skW[k * 128 + (n - 512)];
    Wcat1[idx] = f2bf(v);
  } else if (b < CNT_BLKS + CVT_BLKS + W1_BLKS + W2_BLKS) {
    int idx = (b - CNT_BLKS - CVT_BLKS - W1_BLKS) * 256 + t;  // 256 x 256
    if (idx < 256) bias2[idx] = idx < 128 ? bl2[idx] : br2[idx - 128];
    int n = idx >> 8, k = idx & 255;
    float v = n < 128 ? Wl2[k * 128 + n] : Wr2[k * 128 + (n - 128)];
    Wt2[idx] = f2bf(v);
  } else {
    if (t < 4) {
      float s = 0.f;
      for (int c = 0; c < 64; ++c) s += att1[t * 64 + c] * We1[t * 64 + c];
      axw[t] = s;
    } else if (t == 4) {
      float s = 0.f;
      for (int c = 0; c < 128; ++c) s += att2[c] * We2[c];
      axw[4] = s;
    }
  }
}

// ---------------- CSR ----------------

__global__ __launch_bounds__(256) void offsets_k(const int* __restrict__ cnt, int* __restrict__ offs,
                                                 int* __restrict__ cursor, int* __restrict__ total) {
  int i = blockIdx.x * 256 + threadIdx.x;
  int lane = threadIdx.x & 63;
  int c = (i < NNODES) ? cnt[i] : 0;
  int incl = c;
  #pragma unroll
  for (int d = 1; d < 64; d <<= 1) {
    int t = __shfl_up(incl, d, 64);
    if (lane >= d) incl += t;
  }
  int wtotal = __shfl(incl, 63, 64);
  int base = 0;
  if (lane == 63) base = atomicAdd(total, wtotal);
  base = __shfl(base, 63, 64);
  int off = base + incl - c;
  if (i < NNODES) { offs[i] = off; cursor[i] = off; }
}

__global__ __launch_bounds__(256) void scatter_k(const int* __restrict__ src, const int* __restrict__ dst,
                                                 const float* __restrict__ ea, int* __restrict__ cursor,
                                                 int2* __restrict__ epair) {
  int e = blockIdx.x * 256 + threadIdx.x;
  if (e >= NEDGES) return;
  int d = dst[e];
  int p = atomicAdd(&cursor[d], 1);
  int2 v; v.x = src[e]; v.y = __float_as_int(ea[e]);
  epair[p] = v;
}

// ---------------- MFMA GEMM with fused att-dot epilogue ----------------
// C routing by col-block: [0,B1)->C0, [B1,B2)->C1, [B2,..)->C2. All bf16 out.
// If DO_ATT and cb<B2: also emits ax = att . C_row per head (SPAN cols/head).

template<int K, int B1, int B2, int LDC0, int LDC1, int LDC2, int SPAN, int ATTLEN, bool DO_ATT>
__global__ __launch_bounds__(512) void gemm_mfma(
    const u16* __restrict__ A, const u16* __restrict__ Wt, const float* __restrict__ bias,
    u16* __restrict__ C0, u16* __restrict__ C1, u16* __restrict__ C2,
    const float* __restrict__ att, float* __restrict__ axl, float* __restrict__ axr) {
  constexpr int LDA = K + 8;
  constexpr int CSTR = 136;
  constexpr size_t ABYTES = (size_t)64 * LDA * 2;
  constexpr size_t CBYTES = (size_t)64 * CSTR * 2;
  constexpr size_t SBYTES = ABYTES > CBYTES ? ABYTES : CBYTES;
  __shared__ __align__(16) char smem[SBYTES];
  __shared__ float attS[128];
  u16* As = (u16*)smem;
  const int row0 = blockIdx.x * 64;
  const int tid = threadIdx.x;
  #pragma unroll
  for (int it = 0; it < K / 32; ++it) {
    int chunk = it * 512 + tid;
    int row = (chunk * 4) / K;
    int col = (chunk * 4) % K;
    uint2 v; v.x = 0u; v.y = 0u;
    int gr = row0 + row;
    if (gr < NNODES) v = *reinterpret_cast<const uint2*>(A + (size_t)gr * K + col);
    *reinterpret_cast<uint2*>(&As[row * LDA + col]) = v;
  }
  __syncthreads();
  const int w = tid >> 6, lane = tid & 63, q = lane >> 4, l16 = lane & 15;
  const int tc = w * 16 + l16;
  const int cb = blockIdx.y * 128;
  const int ncol = cb + tc;
  f32x4 acc[4];
  #pragma unroll
  for (int rt = 0; rt < 4; ++rt) acc[rt] = (f32x4){0.f, 0.f, 0.f, 0.f};
  const u16* wp = Wt + (size_t)ncol * K + q * 8;
  #pragma unroll
  for (int ks = 0; ks < K / 32; ++ks) {
    bf16x8 b = *reinterpret_cast<const bf16x8*>(wp + ks * 32);
    #pragma unroll
    for (int rt = 0; rt < 4; ++rt) {
      bf16x8 a = *reinterpret_cast<const bf16x8*>(&As[(rt * 16 + l16) * LDA + ks * 32 + q * 8]);
      acc[rt] = __builtin_amdgcn_mfma_f32_16x16x32_bf16(a, b, acc[rt], 0, 0, 0);
    }
  }
  const float bval = bias[ncol];
  __syncthreads();
  u16* Cs = (u16*)smem;
  #pragma unroll
  for (int rt = 0; rt < 4; ++rt)
    #pragma unroll
    for (int r = 0; r < 4; ++r)
      Cs[(rt * 16 + q * 4 + r) * CSTR + tc] = f2bf(acc[rt][r] + bval);
  __syncthreads();
  // coalesced C store
  {
    u16* Cg; int LD, cc;
    if (cb < B1)      { Cg = C0; LD = LDC0; cc = cb; }
    else if (cb < B2) { Cg = C1; LD = LDC1; cc = cb - B1; }
    else              { Cg = C2; LD = LDC2; cc = cb - B2; }
    #pragma unroll
    for (int it = 0; it < 2; ++it) {
      int ch = it * 512 + tid;
      int row = ch / 16, co = (ch % 16) * 8;
      int grow = row0 + row;
      if (grow < NNODES) {
        uint4 v = *reinterpret_cast<const uint4*>(&Cs[row * CSTR + co]);
        *reinterpret_cast<uint4*>(Cg + (size_t)grow * LD + cc + co) = v;
      }
    }
  }
  if constexpr (DO_ATT) {
    if (cb < B2) {
      if (tid < 128) attS[tid] = att[(cb + tid) % ATTLEN];
      __syncthreads();
      constexpr int TPR = 128 / SPAN;
      constexpr int HEADS = B1 / SPAN;
      if (tid < 64 * TPR) {
        int row = tid / TPR, hb = tid % TPR;
        const u16* cr = Cs + row * CSTR + hb * SPAN;
        float s = 0.f;
        for (int c = 0; c < SPAN; ++c) s += bf2f(cr[c]) * attS[hb * SPAN + c];
        int grow = row0 + row;
        if (grow < NNODES) {
          int cbl = cb < B1 ? cb : cb - B1;
          int lh = cbl / SPAN + hb;
          float* dstp = (cb < B1) ? axl : axr;
          dstp[grow * HEADS + lh] = s;
        }
      }
    }
  }
}

// ---------------- GATv2 edge pass: EPW edges/wave, CPL=8 channels/lane ----------------
// s = 0.6*(axl[src]+axr[dst]+ea*aWe) + 0.4*sum(att*|m|)   (exact LeakyReLU identity)

template<int HEADS, int CHAN, int EPW>
__global__ __launch_bounds__(256) void gat_edge(
    const int* __restrict__ offs, const int* __restrict__ cnt,
    const int2* __restrict__ epair,
    const u16* __restrict__ xl, const u16* __restrict__ xr,
    const float* __restrict__ att, const float* __restrict__ We,
    const float* __restrict__ cb,
    const float* __restrict__ axl, const float* __restrict__ axr,
    const float* __restrict__ aWep, u16* __restrict__ hout) {
  constexpr int HC  = HEADS * CHAN;
  constexpr int GSZ = 64 / EPW;       // lanes per edge group
  constexpr int CPL = HC / GSZ;       // channels per lane
  constexpr int LPH = CHAN / CPL;     // lanes per head cluster
  static_assert(CPL == 8, "layout");

  int node = __builtin_amdgcn_readfirstlane((int)(blockIdx.x * 4 + (threadIdx.x >> 6)));
  if (node >= NNODES) return;
  const int lane = threadIdx.x & 63;
  const int g    = lane / GSZ;
  const int lgs  = lane & (GSZ - 1);
  const int h    = lgs / LPH;
  const int cbase = lgs * CPL;

  float xrv[8], attv[8], wev[8];
  {
    uint4 xrr = *reinterpret_cast<const uint4*>(xr + (size_t)node * HC + cbase);
    dec8(xrr, xrv);
    float4 a0 = *reinterpret_cast<const float4*>(att + cbase);
    float4 a1 = *reinterpret_cast<const float4*>(att + cbase + 4);
    float4 w0 = *reinterpret_cast<const float4*>(We + cbase);
    float4 w1 = *reinterpret_cast<const float4*>(We + cbase + 4);
    attv[0]=a0.x; attv[1]=a0.y; attv[2]=a0.z; attv[3]=a0.w;
    attv[4]=a1.x; attv[5]=a1.y; attv[6]=a1.z; attv[7]=a1.w;
    wev[0]=w0.x; wev[1]=w0.y; wev[2]=w0.z; wev[3]=w0.w;
    wev[4]=w1.x; wev[5]=w1.y; wev[6]=w1.z; wev[7]=w1.w;
  }
  const float aWe = aWep[h];
  const float axr_n = axr[node * HEADS + h];
  const int off = __builtin_amdgcn_readfirstlane(offs[node]);
  const int deg = __builtin_amdgcn_readfirstlane(cnt[node]);

  float den = 0.f;
  float accv[8];
  #pragma unroll
  for (int c = 0; c < 8; ++c) accv[c] = 0.f;

  if (deg > 0) {
    const int last = deg - 1;
    auto midx = [&](int i) { int j = i * EPW + g; return off + (j < last ? j : last); };
    int2 p_cur = epair[midx(0)];
    int2 p_nxt = epair[midx(1)];
    uint4 r_cur; float ax_cur;
    { int s = p_cur.x;
      r_cur = *reinterpret_cast<const uint4*>(xl + (size_t)s * HC + cbase);
      ax_cur = axl[s * HEADS + h]; }
    const int niter = (deg + EPW - 1) / EPW;
    for (int i = 0; i < niter; ++i) {
      int2 p_n2 = epair[midx(i + 2)];
      uint4 r_n; float ax_n;
      { int s = p_nxt.x;
        r_n = *reinterpret_cast<const uint4*>(xl + (size_t)s * HC + cbase);
        ax_n = axl[s * HEADS + h]; }
      float ea = __int_as_float(p_cur.y);
      float xlv[8];
      dec8(r_cur, xlv);
      float part2 = 0.f;
      #pragma unroll
      for (int c = 0; c < 8; ++c) {
        float m = xlv[c] + fmaf(ea, wev[c], xrv[c]);
        part2 = fmaf(fabsf(m), attv[c], part2);
      }
      #pragma unroll
      for (int d = 1; d < LPH; d <<= 1) part2 += __shfl_xor(part2, d, 64);
      float ssum = ax_cur + fmaf(ea, aWe, axr_n);
      float sc = fmaf(0.4f, part2, 0.6f * ssum);
      float e = __expf(sc);
      e = (i * EPW + g <= last) ? e : 0.f;
      den += e;
      #pragma unroll
      for (int c = 0; c < 8; ++c) accv[c] = fmaf(e, xlv[c], accv[c]);
      p_cur = p_nxt; p_nxt = p_n2; r_cur = r_n; ax_cur = ax_n;
    }
  }
  #pragma unroll
  for (int d = GSZ; d < 64; d <<= 1) {
    den += __shfl_xor(den, d, 64);
    #pragma unroll
    for (int c = 0; c < 8; ++c) accv[c] += __shfl_xor(accv[c], d, 64);
  }
  if (g == 0) {
    float inv = 1.0f / (den + 1e-16f);
    float4 c0 = *reinterpret_cast<const float4*>(cb + cbase);
    float4 c1 = *reinterpret_cast<const float4*>(cb + cbase + 4);
    float ov[8];
    ov[0] = accv[0] * inv + c0.x; ov[1] = accv[1] * inv + c0.y;
    ov[2] = accv[2] * inv + c0.z; ov[3] = accv[3] * inv + c0.w;
    ov[4] = accv[4] * inv + c1.x; ov[5] = accv[5] * inv + c1.y;
    ov[6] = accv[6] * inv + c1.z; ov[7] = accv[7] * inv + c1.w;
    *reinterpret_cast<uint4*>(hout + (size_t)node * HC + cbase) = pack8(ov);
  }
}

// ---------------- BatchNorm ----------------

template<int NC>
__global__ void bn_stats_bf(const u16* __restrict__ h, float* __restrict__ sum, float* __restrict__ sq) {
  int c = threadIdx.x;
  float s = 0.f, q = 0.f;
  for (int r = blockIdx.x; r < NNODES; r += gridDim.x) {
    float v = bf2f(h[(size_t)r * NC + c]);
    s += v; q += v * v;
  }
  atomicAdd(&sum[c], s);
  atomicAdd(&sq[c], q);
}

template<int NC>
__global__ __launch_bounds__(256) void bn_prelu_apply(
    const u16* __restrict__ h, const float* __restrict__ sum, const float* __restrict__ sq,
    const float* __restrict__ g, const float* __restrict__ bb_,
    const float* __restrict__ pap, u16* __restrict__ outp, int total) {
  int i = (blockIdx.x * 256 + threadIdx.x) * 4;
  if (i >= total) return;
  const float invN = 1.0f / (float)NNODES;
  float pa = pap[0];
  int c = i & (NC - 1);
  float4 sm = *reinterpret_cast<const float4*>(sum + c);
  float4 qq = *reinterpret_cast<const float4*>(sq + c);
  float4 gg = *reinterpret_cast<const float4*>(g + c);
  float4 bb = *reinterpret_cast<const float4*>(bb_ + c);
  float mu, var, sc[4], sh[4];
  mu = sm.x * invN; var = qq.x * invN - mu * mu; sc[0] = gg.x * rsqrtf(var + 1e-5f); sh[0] = bb.x - mu * sc[0];
  mu = sm.y * invN; var = qq.y * invN - mu * mu; sc[1] = gg.y * rsqrtf(var + 1e-5f); sh[1] = bb.y - mu * sc[1];
  mu = sm.z * invN; var = qq.z * invN - mu * mu; sc[2] = gg.z * rsqrtf(var + 1e-5f); sh[2] = bb.z - mu * sc[2];
  mu = sm.w * invN; var = qq.w * invN - mu * mu; sc[3] = gg.w * rsqrtf(var + 1e-5f); sh[3] = bb.w - mu * sc[3];
  uint2 raw = *reinterpret_cast<const uint2*>(h + i);
  float v0 = bf2f(raw.x & 0xffffu), v1 = bf2f(raw.x >> 16);
  float v2 = bf2f(raw.y & 0xffffu), v3 = bf2f(raw.y >> 16);
  float o0 = v0 * sc[0] + sh[0]; o0 = o0 > 0.f ? o0 : pa * o0;
  float o1 = v1 * sc[1] + sh[1]; o1 = o1 > 0.f ? o1 : pa * o1;
  float o2 = v2 * sc[2] + sh[2]; o2 = o2 > 0.f ? o2 : pa * o2;
  float o3 = v3 * sc[3] + sh[3]; o3 = o3 > 0.f ? o3 : pa * o3;
  uint2 pk;
  pk.x = (unsigned)f2bf(o0) | ((unsigned)f2bf(o1) << 16);
  pk.y = (unsigned)f2bf(o2) | ((unsigned)f2bf(o3) << 16);
  *reinterpret_cast<uint2*>(outp + i) = pk;
}

__global__ __launch_bounds__(256) void final_out_k(
    const u16* __restrict__ h2, const u16* __restrict__ skip,
    const float* __restrict__ sum, const float* __restrict__ sq,
    const float* __restrict__ g, const float* __restrict__ bb_,
    const float* __restrict__ pap, float* __restrict__ outp, int total) {
  int i = (blockIdx.x * 256 + threadIdx.x) * 4;
  if (i >= total) return;
  const float invN = 1.0f / (float)NNODES;
  float pa = pap[0];
  int c = i & 127;
  float4 sm = *reinterpret_cast<const float4*>(sum + c);
  float4 qq = *reinterpret_cast<const float4*>(sq + c);
  float4 gg = *reinterpret_cast<const float4*>(g + c);
  float4 bb = *reinterpret_cast<const float4*>(bb_ + c);
  float mu, var, sc[4], sh[4];
  mu = sm.x * invN; var = qq.x * invN - mu * mu; sc[0] = gg.x * rsqrtf(var + 1e-5f); sh[0] = bb.x - mu * sc[0];
  mu = sm.y * invN; var = qq.y * invN - mu * mu; sc[1] = gg.y * rsqrtf(var + 1e-5f); sh[1] = bb.y - mu * sc[1];
  mu = sm.z * invN; var = qq.z * invN - mu * mu; sc[2] = gg.z * rsqrtf(var + 1e-5f); sh[2] = bb.z - mu * sc[2];
  mu = sm.w * invN; var = qq.w * invN - mu * mu; sc[3] = gg.w * rsqrtf(var + 1e-5f); sh[3] = bb.w - mu * sc[3];
  uint2 raw = *reinterpret_cast<const uint2*>(h2 + i);
  float v0 = bf2f(raw.x & 0xffffu), v1 = bf2f(raw.x >> 16);
  float v2 = bf2f(raw.y & 0xffffu), v3 = bf2f(raw.y >> 16);
  uint2 skr = *reinterpret_cast<const uint2*>(skip + i);
  float s0 = bf2f(skr.x & 0xffffu), s1 = bf2f(skr.x >> 16);
  float s2 = bf2f(skr.y & 0xffffu), s3 = bf2f(skr.y >> 16);
  float4 o;
  o.x = v0 * sc[0] + sh[0]; o.x = (o.x > 0.f ? o.x : pa * o.x) + s0;
  o.y = v1 * sc[1] + sh[1]; o.y = (o.y > 0.f ? o.y : pa * o.y) + s1;
  o.z = v2 * sc[2] + sh[2]; o.z = (o.z > 0.f ? o.z : pa * o.z) + s2;
  o.w = v3 * sc[3] + sh[3]; o.w = (o.w > 0.f ? o.w : pa * o.w) + s3;
  *reinterpret_cast<float4*>(outp + i) = o;
}

// ---------------- launch ----------------

extern "C" void kernel_launch(void* const* d_in, const int* in_sizes, int n_in,
                              void* d_out, int out_size, void* d_ws, size_t ws_size,
                              hipStream_t stream) {
  (void)in_sizes; (void)n_in; (void)out_size; (void)ws_size;
  const float* x    = (const float*)d_in[0];
  const int*   ei   = (const int*)d_in[1];
  const float* ea   = (const float*)d_in[2];
  const float* Wl1  = (const float*)d_in[3];
  const float* bl1  = (const float*)d_in[4];
  const float* Wr1  = (const float*)d_in[5];
  const float* br1  = (const float*)d_in[6];
  const float* We1  = (const float*)d_in[7];
  const float* att1 = (const float*)d_in[8];
  const float* cb1  = (const float*)d_in[9];
  const float* bng1 = (const float*)d_in[10];
  const float* bnb1 = (const float*)d_in[11];
  const float* pa   = (const float*)d_in[12];
  const float* Wl2  = (const float*)d_in[13];
  const float* bl2  = (const float*)d_in[14];
  const float* Wr2  = (const float*)d_in[15];
  const float* br2  = (const float*)d_in[16];
  const float* We2  = (const float*)d_in[17];
  const float* att2 = (const float*)d_in[18];
  const float* cb2  = (const float*)d_in[19];
  const float* bng2 = (const float*)d_in[20];
  const float* bnb2 = (const float*)d_in[21];
  const float* skW  = (const float*)d_in[22];
  const float* skb  = (const float*)d_in[23];
  const int* srcp = ei;
  const int* dstp = ei + NEDGES;

  char* base = (char*)d_ws;
  size_t off = 0;
  auto alloc = [&](size_t bytes) -> char* {
    char* p = base + off;
    off = (off + bytes + 255) & ~(size_t)255;
    return p;
  };
  size_t zero_ints = 1 + NNODES + 256 + 256 + 128 + 128;
  char* zbase = alloc(zero_ints * 4);
  int*   totalp = (int*)zbase;
  int*   cnt    = totalp + 1;
  float* bnsum1 = (float*)(cnt + NNODES);
  float* bnsq1  = bnsum1 + 256;
  float* bnsum2 = bnsq1 + 256;
  float* bnsq2  = bnsum2 + 128;

  int*   offs    = (int*)alloc((size_t)NNODES * 4);
  int*   cursor  = (int*)alloc((size_t)NNODES * 4);
  int2*  epair   = (int2*)alloc((size_t)NEDGES * 8);
  const size_t RBYTES = (size_t)NNODES * DH1 * 2;  // 25.6 MB
  char* regionA = alloc(RBYTES);   // xl1(bf16) -> h1p(bf16) -> h2(bf16)
  char* regionB = alloc(RBYTES);   // xr1(bf16)
  char* regionC = alloc(RBYTES);   // h1(bf16)  -> xl2+xr2(bf16)
  u16*   xbf    = (u16*)alloc((size_t)NNODES * 128 * 2);
  u16*   skipbf = (u16*)alloc((size_t)NNODES * 128 * 2);
  u16*   Wcat1  = (u16*)alloc(640 * 128 * 2);
  u16*   Wt2    = (u16*)alloc(256 * 256 * 2);
  float* bias1  = (float*)alloc(640 * 4);
  float* bias2  = (float*)alloc(256 * 4);
  float* axw    = (float*)alloc(8 * 4);
  float* axl1   = (float*)alloc((size_t)NNODES * 4 * 4);
  float* axr1   = (float*)alloc((size_t)NNODES * 4 * 4);
  float* axl2   = (float*)alloc((size_t)NNODES * 4);
  float* axr2   = (float*)alloc((size_t)NNODES * 4);

  u16*   xl1     = (u16*)regionA;
  u16*   xr1     = (u16*)regionB;
  u16*   h1      = (u16*)regionC;
  u16*   h1p     = (u16*)regionA;
  u16*   xl2     = (u16*)regionC;
  u16*   xr2     = (u16*)(regionC + (size_t)NNODES * DOUT * 2);
  u16*   h2      = (u16*)regionA;

  hipMemsetAsync(zbase, 0, zero_ints * 4, stream);

  const int EB = (NEDGES + 255) / 256;
  const int NB = (NNODES + 255) / 256;
  setup_k<<<CNT_BLKS + CVT_BLKS + W1_BLKS + W2_BLKS + 1, 256, 0, stream>>>(
      dstp, cnt, x, xbf, Wl1, Wr1, bl1, br1, Wl2, Wr2, bl2, br2, skW, skb,
      att1, We1, att2, We2, Wcat1, bias1, Wt2, bias2, axw);
  offsets_k<<<NB, 256, 0, stream>>>(cnt, offs, cursor, totalp);
  scatter_k<<<EB, 256, 0, stream>>>(srcp, dstp, ea, cursor, epair);

  const int MB64 = (NNODES + 63) / 64;
  // layer 1 + skip: cols [0,256)=xl1, [256,512)=xr1, [512,640)=skip
  gemm_mfma<128, 256, 512, 256, 256, 128, 64, 256, true><<<dim3(MB64, 5), 512, 0, stream>>>(
      xbf, Wcat1, bias1, xl1, xr1, skipbf, att1, axl1, axr1);
  gat_edge<4, 64, 2><<<(NNODES + 3) / 4, 256, 0, stream>>>(
      offs, cnt, epair, xl1, xr1, att1, We1, cb1, axl1, axr1, axw, h1);
  bn_stats_bf<256><<<800, 256, 0, stream>>>(h1, bnsum1, bnsq1);
  bn_prelu_apply<256><<<(NNODES * DH1 / 4 + 255) / 256, 256, 0, stream>>>(
      h1, bnsum1, bnsq1, bng1, bnb1, pa, h1p, NNODES * DH1);

  // layer 2: cols [0,128)=xl2, [128,256)=xr2
  gemm_mfma<256, 128, 256, 128, 128, 1, 128, 128, true><<<dim3(MB64, 2), 512, 0, stream>>>(
      h1p, Wt2, bias2, xl2, xr2, (u16*)0, att2, axl2, axr2);
  gat_edge<1, 128, 4><<<(NNODES + 3) / 4, 256, 0, stream>>>(
      offs, cnt, epair, xl2, xr2, att2, We2, cb2, axl2, axr2, axw + 4, h2);
  bn_stats_bf<128><<<800, 128, 0, stream>>>(h2, bnsum2, bnsq2);
  final_out_k<<<(NNODES * DOUT / 4 + 255) / 256, 256, 0, stream>>>(
      h2, skipbf, bnsum2, bnsq2, bng2, bnb2, pa, (float*)d_out, NNODES * DOUT);
}

// Round 8
// 471.769 us; speedup vs baseline: 1.8554x; 1.0426x over previous
//
#include <hip/hip_runtime.h>
#include <cstdint>
#include <cstddef>

#define NNODES 50000
#define NEDGES 800000
#define DH1    256   // H*HID = 4*64
#define DOUT   128

typedef unsigned short u16;
typedef __bf16 bf16x8 __attribute__((ext_vector_type(8)));
typedef float  f32x4  __attribute__((ext_vector_type(4)));

__device__ __forceinline__ float bf2f(unsigned int u) {
  union { unsigned int i; float f; } x; x.i = u << 16; return x.f;
}
__device__ __forceinline__ u16 f2bf(float f) {
  union { float f; unsigned int i; } x; x.f = f;
  unsigned int r = x.i + 0x7fffu + ((x.i >> 16) & 1u);  // round-to-nearest-even
  return (u16)(r >> 16);
}
__device__ __forceinline__ uint4 pack8(const float* v) {
  uint4 p;
  p.x = (unsigned)f2bf(v[0]) | ((unsigned)f2bf(v[1]) << 16);
  p.y = (unsigned)f2bf(v[2]) | ((unsigned)f2bf(v[3]) << 16);
  p.z = (unsigned)f2bf(v[4]) | ((unsigned)f2bf(v[5]) << 16);
  p.w = (unsigned)f2bf(v[6]) | ((unsigned)f2bf(v[7]) << 16);
  return p;
}

// ---- packed fp32 (VOP3P, full-rate on CDNA2+) ----
__device__ __forceinline__ float2 pkfma(float2 a, float2 b, float2 c) {
  float2 d;
  asm("v_pk_fma_f32 %0, %1, %2, %3" : "=v"(d) : "v"(a), "v"(b), "v"(c));
  return d;
}
__device__ __forceinline__ float2 pkadd(float2 a, float2 b) {
  float2 d;
  asm("v_pk_add_f32 %0, %1, %2" : "=v"(d) : "v"(a), "v"(b));
  return d;
}
__device__ __forceinline__ float2 abs2(float2 a) {
  union { float2 f; uint2 u; } x; x.f = a;
  x.u.x &= 0x7fffffffu; x.u.y &= 0x7fffffffu;
  return x.f;
}
// decode one u32 (2 packed bf16) -> float2 {lo, hi}
__device__ __forceinline__ float2 dec2(unsigned u) {
  union { unsigned i; float f; } lo, hi;
  lo.i = u << 16; hi.i = u & 0xffff0000u;
  float2 d; d.x = lo.f; d.y = hi.f; return d;
}

// ---------------- setup: rank-count + cvt + weight-prep + att*We scalars ----------------

#define CNT_BLKS 3125
#define CVT_BLKS 6250
#define W1_BLKS  320
#define W2_BLKS  256

__global__ __launch_bounds__(256) void setup_k(
    const int* __restrict__ dst, int* __restrict__ cnt, int* __restrict__ rank,
    const float* __restrict__ x, u16* __restrict__ xbf,
    const float* __restrict__ Wl1, const float* __restrict__ Wr1,
    const float* __restrict__ bl1, const float* __restrict__ br1,
    const float* __restrict__ Wl2, const float* __restrict__ Wr2,
    const float* __restrict__ bl2, const float* __restrict__ br2,
    const float* __restrict__ skW, const float* __restrict__ skb,
    const float* __restrict__ att1, const float* __restrict__ We1,
    const float* __restrict__ att2, const float* __restrict__ We2,
    u16* __restrict__ Wcat1, float* __restrict__ bias1,
    u16* __restrict__ Wt2, float* __restrict__ bias2,
    float* __restrict__ axw) {
  int b = blockIdx.x, t = threadIdx.x;
  if (b < CNT_BLKS) {
    int e = b * 256 + t;
    if (e < NEDGES) rank[e] = atomicAdd(&cnt[dst[e]], 1);
  } else if (b < CNT_BLKS + CVT_BLKS) {
    int i = ((b - CNT_BLKS) * 256 + t) * 4;
    float4 v = *reinterpret_cast<const float4*>(x + i);
    uint2 pk;
    pk.x = (unsigned)f2bf(v.x) | ((unsigned)f2bf(v.y) << 16);
    pk.y = (unsigned)f2bf(v.z) | ((unsigned)f2bf(v.w) << 16);
    *reinterpret_cast<uint2*>(xbf + i) = pk;
  } else if (b < CNT_BLKS + CVT_BLKS + W1_BLKS) {
    int idx = (b - CNT_BLKS - CVT_BLKS) * 256 + t;   // 640 x 128
    if (idx < 640) bias1[idx] = idx < 256 ? bl1[idx] : idx < 512 ? br1[idx - 256] : skb[idx - 512];
    int n = idx >> 7, k = idx & 127;
    float v = n < 256 ? Wl1[k * 256 + n] : n < 512 ? Wr1[k * 256 + (n - 256)] : skW[k * 128 + (n - 512)];
    Wcat1[idx] = f2bf(v);
  } else if (b < CNT_BLKS + CVT_BLKS + W1_BLKS + W2_BLKS) {
    int idx = (b - CNT_BLKS - CVT_BLKS - W1_BLKS) * 256 + t;  // 256 x 256
    if (idx < 256) bias2[idx] = idx < 128 ? bl2[idx] : br2[idx - 128];
    int n = idx >> 8, k = idx & 255;
    float v = n < 128 ? Wl2[k * 128 + n] : Wr2[k * 128 + (n - 128)];
    Wt2[idx] = f2bf(v);
  } else {
    if (t < 4) {
      float s = 0.f;
      for (int c = 0; c < 64; ++c) s += att1[t * 64 + c] * We1[t * 64 + c];
      axw[t] = s;
    } else if (t == 4) {
      float s = 0.f;
      for (int c = 0; c < 128; ++c) s += att2[c] * We2[c];
      axw[4] = s;
    }
  }
}

// ---------------- CSR ----------------

__global__ __launch_bounds__(256) void offsets_k(const int* __restrict__ cnt, int* __restrict__ offs,
                                                 int* __restrict__ total) {
  int i = blockIdx.x * 256 + threadIdx.x;
  int lane = threadIdx.x & 63;
  int c = (i < NNODES) ? cnt[i] : 0;
  int incl = c;
  #pragma unroll
  for (int d = 1; d < 64; d <<= 1) {
    int t = __shfl_up(incl, d, 64);
    if (lane >= d) incl += t;
  }
  int wtotal = __shfl(incl, 63, 64);
  int base = 0;
  if (lane == 63) base = atomicAdd(total, wtotal);
  base = __shfl(base, 63, 64);
  int off = base + incl - c;
  if (i < NNODES) offs[i] = off;
}

// atomic-free scatter: position = offs[dst] + rank (stable within segment)
__global__ __launch_bounds__(256) void scatter_k(const int* __restrict__ src, const int* __restrict__ dst,
                                                 const float* __restrict__ ea, const int* __restrict__ offs,
                                                 const int* __restrict__ rank, int2* __restrict__ epair) {
  int e = blockIdx.x * 256 + threadIdx.x;
  if (e >= NEDGES) return;
  int p = offs[dst[e]] + rank[e];
  int2 v; v.x = src[e]; v.y = __float_as_int(ea[e]);
  epair[p] = v;
}

// ---------------- MFMA GEMM with fused att-dot epilogue ----------------

template<int K, int B1, int B2, int LDC0, int LDC1, int LDC2, int SPAN, int ATTLEN, bool DO_ATT>
__global__ __launch_bounds__(512) void gemm_mfma(
    const u16* __restrict__ A, const u16* __restrict__ Wt, const float* __restrict__ bias,
    u16* __restrict__ C0, u16* __restrict__ C1, u16* __restrict__ C2,
    const float* __restrict__ att, float* __restrict__ axl, float* __restrict__ axr) {
  constexpr int LDA = K + 8;
  constexpr int CSTR = 136;
  constexpr size_t ABYTES = (size_t)64 * LDA * 2;
  constexpr size_t CBYTES = (size_t)64 * CSTR * 2;
  constexpr size_t SBYTES = ABYTES > CBYTES ? ABYTES : CBYTES;
  __shared__ __align__(16) char smem[SBYTES];
  __shared__ float attS[128];
  u16* As = (u16*)smem;
  const int row0 = blockIdx.x * 64;
  const int tid = threadIdx.x;
  #pragma unroll
  for (int it = 0; it < K / 32; ++it) {
    int chunk = it * 512 + tid;
    int row = (chunk * 4) / K;
    int col = (chunk * 4) % K;
    uint2 v; v.x = 0u; v.y = 0u;
    int gr = row0 + row;
    if (gr < NNODES) v = *reinterpret_cast<const uint2*>(A + (size_t)gr * K + col);
    *reinterpret_cast<uint2*>(&As[row * LDA + col]) = v;
  }
  __syncthreads();
  const int w = tid >> 6, lane = tid & 63, q = lane >> 4, l16 = lane & 15;
  const int tc = w * 16 + l16;
  const int cb = blockIdx.y * 128;
  const int ncol = cb + tc;
  f32x4 acc[4];
  #pragma unroll
  for (int rt = 0; rt < 4; ++rt) acc[rt] = (f32x4){0.f, 0.f, 0.f, 0.f};
  const u16* wp = Wt + (size_t)ncol * K + q * 8;
  #pragma unroll
  for (int ks = 0; ks < K / 32; ++ks) {
    bf16x8 b = *reinterpret_cast<const bf16x8*>(wp + ks * 32);
    #pragma unroll
    for (int rt = 0; rt < 4; ++rt) {
      bf16x8 a = *reinterpret_cast<const bf16x8*>(&As[(rt * 16 + l16) * LDA + ks * 32 + q * 8]);
      acc[rt] = __builtin_amdgcn_mfma_f32_16x16x32_bf16(a, b, acc[rt], 0, 0, 0);
    }
  }
  const float bval = bias[ncol];
  __syncthreads();
  u16* Cs = (u16*)smem;
  #pragma unroll
  for (int rt = 0; rt < 4; ++rt)
    #pragma unroll
    for (int r = 0; r < 4; ++r)
      Cs[(rt * 16 + q * 4 + r) * CSTR + tc] = f2bf(acc[rt][r] + bval);
  __syncthreads();
  {
    u16* Cg; int LD, cc;
    if (cb < B1)      { Cg = C0; LD = LDC0; cc = cb; }
    else if (cb < B2) { Cg = C1; LD = LDC1; cc = cb - B1; }
    else              { Cg = C2; LD = LDC2; cc = cb - B2; }
    #pragma unroll
    for (int it = 0; it < 2; ++it) {
      int ch = it * 512 + tid;
      int row = ch / 16, co = (ch % 16) * 8;
      int grow = row0 + row;
      if (grow < NNODES) {
        uint4 v = *reinterpret_cast<const uint4*>(&Cs[row * CSTR + co]);
        *reinterpret_cast<uint4*>(Cg + (size_t)grow * LD + cc + co) = v;
      }
    }
  }
  if constexpr (DO_ATT) {
    if (cb < B2) {
      if (tid < 128) attS[tid] = att[(cb + tid) % ATTLEN];
      __syncthreads();
      constexpr int TPR = 128 / SPAN;
      constexpr int HEADS = B1 / SPAN;
      if (tid < 64 * TPR) {
        int row = tid / TPR, hb = tid % TPR;
        const u16* cr = Cs + row * CSTR + hb * SPAN;
        float s = 0.f;
        for (int c = 0; c < SPAN; ++c) s += bf2f(cr[c]) * attS[hb * SPAN + c];
        int grow = row0 + row;
        if (grow < NNODES) {
          int cbl = cb < B1 ? cb : cb - B1;
          int lh = cbl / SPAN + hb;
          float* dstp = (cb < B1) ? axl : axr;
          dstp[grow * HEADS + lh] = s;
        }
      }
    }
  }
}

// ---------------- GATv2 edge pass: EPW edges/wave, CPL=8, packed-f32 math ----------------
// s = 0.6*(axl[src]+axr[dst]+ea*aWe) + 0.4*sum(att*|m|)   (exact LeakyReLU identity)

template<int HEADS, int CHAN, int EPW>
__global__ __launch_bounds__(256) void gat_edge(
    const int* __restrict__ offs, const int* __restrict__ cnt,
    const int2* __restrict__ epair,
    const u16* __restrict__ xl, const u16* __restrict__ xr,
    const float* __restrict__ att, const float* __restrict__ We,
    const float* __restrict__ cb,
    const float* __restrict__ axl, const float* __restrict__ axr,
    const float* __restrict__ aWep, u16* __restrict__ hout) {
  constexpr int HC  = HEADS * CHAN;
  constexpr int GSZ = 64 / EPW;       // lanes per edge group
  constexpr int CPL = HC / GSZ;       // channels per lane
  constexpr int LPH = CHAN / CPL;     // lanes per head cluster
  static_assert(CPL == 8, "layout");

  int node = __builtin_amdgcn_readfirstlane((int)(blockIdx.x * 4 + (threadIdx.x >> 6)));
  if (node >= NNODES) return;
  const int lane = threadIdx.x & 63;
  const int g    = lane / GSZ;
  const int lgs  = lane & (GSZ - 1);
  const int h    = lgs / LPH;
  const int cbase = lgs * CPL;

  float2 xrv2[4], attv2[4], wev2[4];
  {
    uint4 xrr = *reinterpret_cast<const uint4*>(xr + (size_t)node * HC + cbase);
    xrv2[0] = dec2(xrr.x); xrv2[1] = dec2(xrr.y);
    xrv2[2] = dec2(xrr.z); xrv2[3] = dec2(xrr.w);
    float4 a0 = *reinterpret_cast<const float4*>(att + cbase);
    float4 a1 = *reinterpret_cast<const float4*>(att + cbase + 4);
    float4 w0 = *reinterpret_cast<const float4*>(We + cbase);
    float4 w1 = *reinterpret_cast<const float4*>(We + cbase + 4);
    attv2[0].x=a0.x; attv2[0].y=a0.y; attv2[1].x=a0.z; attv2[1].y=a0.w;
    attv2[2].x=a1.x; attv2[2].y=a1.y; attv2[3].x=a1.z; attv2[3].y=a1.w;
    wev2[0].x=w0.x; wev2[0].y=w0.y; wev2[1].x=w0.z; wev2[1].y=w0.w;
    wev2[2].x=w1.x; wev2[2].y=w1.y; wev2[3].x=w1.z; wev2[3].y=w1.w;
  }
  const float aWe = aWep[h];
  const float axr_n = axr[node * HEADS + h];
  const int off = __builtin_amdgcn_readfirstlane(offs[node]);
  const int deg = __builtin_amdgcn_readfirstlane(cnt[node]);

  float den = 0.f;
  float2 acc2[4];
  #pragma unroll
  for (int c = 0; c < 4; ++c) { acc2[c].x = 0.f; acc2[c].y = 0.f; }

  if (deg > 0) {
    const int last = deg - 1;
    auto midx = [&](int i) { int j = i * EPW + g; return off + (j < last ? j : last); };
    int2 p_cur = epair[midx(0)];
    int2 p_nxt = epair[midx(1)];
    uint4 r_cur; float ax_cur;
    { int s = p_cur.x;
      r_cur = *reinterpret_cast<const uint4*>(xl + (size_t)s * HC + cbase);
      ax_cur = axl[s * HEADS + h]; }
    const int niter = (deg + EPW - 1) / EPW;
    for (int i = 0; i < niter; ++i) {
      int2 p_n2 = epair[midx(i + 2)];
      uint4 r_n; float ax_n;
      { int s = p_nxt.x;
        r_n = *reinterpret_cast<const uint4*>(xl + (size_t)s * HC + cbase);
        ax_n = axl[s * HEADS + h]; }
      float ea = __int_as_float(p_cur.y);
      float2 xl2[4];
      xl2[0] = dec2(r_cur.x); xl2[1] = dec2(r_cur.y);
      xl2[2] = dec2(r_cur.z); xl2[3] = dec2(r_cur.w);
      float2 ea2; ea2.x = ea; ea2.y = ea;
      float2 dot2; dot2.x = 0.f; dot2.y = 0.f;
      #pragma unroll
      for (int c = 0; c < 4; ++c) {
        float2 m = pkadd(xl2[c], pkfma(ea2, wev2[c], xrv2[c]));
        dot2 = pkfma(abs2(m), attv2[c], dot2);
      }
      float part2 = dot2.x + dot2.y;
      #pragma unroll
      for (int d = 1; d < LPH; d <<= 1) part2 += __shfl_xor(part2, d, 64);
      float ssum = ax_cur + fmaf(ea, aWe, axr_n);
      float sc = fmaf(0.4f, part2, 0.6f * ssum);
      float e = __expf(sc);
      e = (i * EPW + g <= last) ? e : 0.f;
      den += e;
      float2 e2; e2.x = e; e2.y = e;
      #pragma unroll
      for (int c = 0; c < 4; ++c) acc2[c] = pkfma(e2, xl2[c], acc2[c]);
      p_cur = p_nxt; p_nxt = p_n2; r_cur = r_n; ax_cur = ax_n;
    }
  }
  #pragma unroll
  for (int d = GSZ; d < 64; d <<= 1) {
    den += __shfl_xor(den, d, 64);
    #pragma unroll
    for (int c = 0; c < 4; ++c) {
      acc2[c].x += __shfl_xor(acc2[c].x, d, 64);
      acc2[c].y += __shfl_xor(acc2[c].y, d, 64);
    }
  }
  if (g == 0) {
    float inv = 1.0f / (den + 1e-16f);
    float4 c0 = *reinterpret_cast<const float4*>(cb + cbase);
    float4 c1 = *reinterpret_cast<const float4*>(cb + cbase + 4);
    float ov[8];
    ov[0] = acc2[0].x * inv + c0.x; ov[1] = acc2[0].y * inv + c0.y;
    ov[2] = acc2[1].x * inv + c0.z; ov[3] = acc2[1].y * inv + c0.w;
    ov[4] = acc2[2].x * inv + c1.x; ov[5] = acc2[2].y * inv + c1.y;
    ov[6] = acc2[3].x * inv + c1.z; ov[7] = acc2[3].y * inv + c1.w;
    *reinterpret_cast<uint4*>(hout + (size_t)node * HC + cbase) = pack8(ov);
  }
}

// ---------------- BatchNorm ----------------

template<int NC>
__global__ void bn_stats_bf(const u16* __restrict__ h, float* __restrict__ sum, float* __restrict__ sq) {
  int c = threadIdx.x;
  float s = 0.f, q = 0.f;
  for (int r = blockIdx.x; r < NNODES; r += gridDim.x) {
    float v = bf2f(h[(size_t)r * NC + c]);
    s += v; q += v * v;
  }
  atomicAdd(&sum[c], s);
  atomicAdd(&sq[c], q);
}

template<int NC>
__global__ __launch_bounds__(256) void bn_prelu_apply(
    const u16* __restrict__ h, const float* __restrict__ sum, const float* __restrict__ sq,
    const float* __restrict__ g, const float* __restrict__ bb_,
    const float* __restrict__ pap, u16* __restrict__ outp, int total) {
  int i = (blockIdx.x * 256 + threadIdx.x) * 4;
  if (i >= total) return;
  const float invN = 1.0f / (float)NNODES;
  float pa = pap[0];
  int c = i & (NC - 1);
  float4 sm = *reinterpret_cast<const float4*>(sum + c);
  float4 qq = *reinterpret_cast<const float4*>(sq + c);
  float4 gg = *reinterpret_cast<const float4*>(g + c);
  float4 bb = *reinterpret_cast<const float4*>(bb_ + c);
  float mu, var, sc[4], sh[4];
  mu = sm.x * invN; var = qq.x * invN - mu * mu; sc[0] = gg.x * rsqrtf(var + 1e-5f); sh[0] = bb.x - mu * sc[0];
  mu = sm.y * invN; var = qq.y * invN - mu * mu; sc[1] = gg.y * rsqrtf(var + 1e-5f); sh[1] = bb.y - mu * sc[1];
  mu = sm.z * invN; var = qq.z * invN - mu * mu; sc[2] = gg.z * rsqrtf(var + 1e-5f); sh[2] = bb.z - mu * sc[2];
  mu = sm.w * invN; var = qq.w * invN - mu * mu; sc[3] = gg.w * rsqrtf(var + 1e-5f); sh[3] = bb.w - mu * sc[3];
  uint2 raw = *reinterpret_cast<const uint2*>(h + i);
  float v0 = bf2f(raw.x & 0xffffu), v1 = bf2f(raw.x >> 16);
  float v2 = bf2f(raw.y & 0xffffu), v3 = bf2f(raw.y >> 16);
  float o0 = v0 * sc[0] + sh[0]; o0 = o0 > 0.f ? o0 : pa * o0;
  float o1 = v1 * sc[1] + sh[1]; o1 = o1 > 0.f ? o1 : pa * o1;
  float o2 = v2 * sc[2] + sh[2]; o2 = o2 > 0.f ? o2 : pa * o2;
  float o3 = v3 * sc[3] + sh[3]; o3 = o3 > 0.f ? o3 : pa * o3;
  uint2 pk;
  pk.x = (unsigned)f2bf(o0) | ((unsigned)f2bf(o1) << 16);
  pk.y = (unsigned)f2bf(o2) | ((unsigned)f2bf(o3) << 16);
  *reinterpret_cast<uint2*>(outp + i) = pk;
}

__global__ __launch_bounds__(256) void final_out_k(
    const u16* __restrict__ h2, const u16* __restrict__ skip,
    const float* __restrict__ sum, const float* __restrict__ sq,
    const float* __restrict__ g, const float* __restrict__ bb_,
    const float* __restrict__ pap, float* __restrict__ outp, int total) {
  int i = (blockIdx.x * 256 + threadIdx.x) * 4;
  if (i >= total) return;
  const float invN = 1.0f / (float)NNODES;
  float pa = pap[0];
  int c = i & 127;
  float4 sm = *reinterpret_cast<const float4*>(sum + c);
  float4 qq = *reinterpret_cast<const float4*>(sq + c);
  float4 gg = *reinterpret_cast<const float4*>(g + c);
  float4 bb = *reinterpret_cast<const float4*>(bb_ + c);
  float mu, var, sc[4], sh[4];
  mu = sm.x * invN; var = qq.x * invN - mu * mu; sc[0] = gg.x * rsqrtf(var + 1e-5f); sh[0] = bb.x - mu * sc[0];
  mu = sm.y * invN; var = qq.y * invN - mu * mu; sc[1] = gg.y * rsqrtf(var + 1e-5f); sh[1] = bb.y - mu * sc[1];
  mu = sm.z * invN; var = qq.z * invN - mu * mu; sc[2] = gg.z * rsqrtf(var + 1e-5f); sh[2] = bb.z - mu * sc[2];
  mu = sm.w * invN; var = qq.w * invN - mu * mu; sc[3] = gg.w * rsqrtf(var + 1e-5f); sh[3] = bb.w - mu * sc[3];
  uint2 raw = *reinterpret_cast<const uint2*>(h2 + i);
  float v0 = bf2f(raw.x & 0xffffu), v1 = bf2f(raw.x >> 16);
  float v2 = bf2f(raw.y & 0xffffu), v3 = bf2f(raw.y >> 16);
  uint2 skr = *reinterpret_cast<const uint2*>(skip + i);
  float s0 = bf2f(skr.x & 0xffffu), s1 = bf2f(skr.x >> 16);
  float s2 = bf2f(skr.y & 0xffffu), s3 = bf2f(skr.y >> 16);
  float4 o;
  o.x = v0 * sc[0] + sh[0]; o.x = (o.x > 0.f ? o.x : pa * o.x) + s0;
  o.y = v1 * sc[1] + sh[1]; o.y = (o.y > 0.f ? o.y : pa * o.y) + s1;
  o.z = v2 * sc[2] + sh[2]; o.z = (o.z > 0.f ? o.z : pa * o.z) + s2;
  o.w = v3 * sc[3] + sh[3]; o.w = (o.w > 0.f ? o.w : pa * o.w) + s3;
  *reinterpret_cast<float4*>(outp + i) = o;
}

// ---------------- launch ----------------

extern "C" void kernel_launch(void* const* d_in, const int* in_sizes, int n_in,
                              void* d_out, int out_size, void* d_ws, size_t ws_size,
                              hipStream_t stream) {
  (void)in_sizes; (void)n_in; (void)out_size; (void)ws_size;
  const float* x    = (const float*)d_in[0];
  const int*   ei   = (const int*)d_in[1];
  const float* ea   = (const float*)d_in[2];
  const float* Wl1  = (const float*)d_in[3];
  const float* bl1  = (const float*)d_in[4];
  const float* Wr1  = (const float*)d_in[5];
  const float* br1  = (const float*)d_in[6];
  const float* We1  = (const float*)d_in[7];
  const float* att1 = (const float*)d_in[8];
  const float* cb1  = (const float*)d_in[9];
  const float* bng1 = (const float*)d_in[10];
  const float* bnb1 = (const float*)d_in[11];
  const float* pa   = (const float*)d_in[12];
  const float* Wl2  = (const float*)d_in[13];
  const float* bl2  = (const float*)d_in[14];
  const float* Wr2  = (const float*)d_in[15];
  const float* br2  = (const float*)d_in[16];
  const float* We2  = (const float*)d_in[17];
  const float* att2 = (const float*)d_in[18];
  const float* cb2  = (const float*)d_in[19];
  const float* bng2 = (const float*)d_in[20];
  const float* bnb2 = (const float*)d_in[21];
  const float* skW  = (const float*)d_in[22];
  const float* skb  = (const float*)d_in[23];
  const int* srcp = ei;
  const int* dstp = ei + NEDGES;

  char* base = (char*)d_ws;
  size_t off = 0;
  auto alloc = [&](size_t bytes) -> char* {
    char* p = base + off;
    off = (off + bytes + 255) & ~(size_t)255;
    return p;
  };
  size_t zero_ints = 1 + NNODES + 256 + 256 + 128 + 128;
  char* zbase = alloc(zero_ints * 4);
  int*   totalp = (int*)zbase;
  int*   cnt    = totalp + 1;
  float* bnsum1 = (float*)(cnt + NNODES);
  float* bnsq1  = bnsum1 + 256;
  float* bnsum2 = bnsq1 + 256;
  float* bnsq2  = bnsum2 + 128;

  int*   offs    = (int*)alloc((size_t)NNODES * 4);
  int*   rank    = (int*)alloc((size_t)NEDGES * 4);
  int2*  epair   = (int2*)alloc((size_t)NEDGES * 8);
  const size_t RBYTES = (size_t)NNODES * DH1 * 2;  // 25.6 MB
  char* regionA = alloc(RBYTES);   // xl1(bf16) -> h1p(bf16) -> h2(bf16)
  char* regionB = alloc(RBYTES);   // xr1(bf16)
  char* regionC = alloc(RBYTES);   // h1(bf16)  -> xl2+xr2(bf16)
  u16*   xbf    = (u16*)alloc((size_t)NNODES * 128 * 2);
  u16*   skipbf = (u16*)alloc((size_t)NNODES * 128 * 2);
  u16*   Wcat1  = (u16*)alloc(640 * 128 * 2);
  u16*   Wt2    = (u16*)alloc(256 * 256 * 2);
  float* bias1  = (float*)alloc(640 * 4);
  float* bias2  = (float*)alloc(256 * 4);
  float* axw    = (float*)alloc(8 * 4);
  float* axl1   = (float*)alloc((size_t)NNODES * 4 * 4);
  float* axr1   = (float*)alloc((size_t)NNODES * 4 * 4);
  float* axl2   = (float*)alloc((size_t)NNODES * 4);
  float* axr2   = (float*)alloc((size_t)NNODES * 4);

  u16*   xl1     = (u16*)regionA;
  u16*   xr1     = (u16*)regionB;
  u16*   h1      = (u16*)regionC;
  u16*   h1p     = (u16*)regionA;
  u16*   xl2     = (u16*)regionC;
  u16*   xr2     = (u16*)(regionC + (size_t)NNODES * DOUT * 2);
  u16*   h2      = (u16*)regionA;

  hipMemsetAsync(zbase, 0, zero_ints * 4, stream);

  const int EB = (NEDGES + 255) / 256;
  const int NB = (NNODES + 255) / 256;
  setup_k<<<CNT_BLKS + CVT_BLKS + W1_BLKS + W2_BLKS + 1, 256, 0, stream>>>(
      dstp, cnt, rank, x, xbf, Wl1, Wr1, bl1, br1, Wl2, Wr2, bl2, br2, skW, skb,
      att1, We1, att2, We2, Wcat1, bias1, Wt2, bias2, axw);
  offsets_k<<<NB, 256, 0, stream>>>(cnt, offs, totalp);
  scatter_k<<<EB, 256, 0, stream>>>(srcp, dstp, ea, offs, rank, epair);

  const int MB64 = (NNODES + 63) / 64;
  // layer 1 + skip: cols [0,256)=xl1, [256,512)=xr1, [512,640)=skip
  gemm_mfma<128, 256, 512, 256, 256, 128, 64, 256, true><<<dim3(MB64, 5), 512, 0, stream>>>(
      xbf, Wcat1, bias1, xl1, xr1, skipbf, att1, axl1, axr1);
  gat_edge<4, 64, 2><<<(NNODES + 3) / 4, 256, 0, stream>>>(
      offs, cnt, epair, xl1, xr1, att1, We1, cb1, axl1, axr1, axw, h1);
  bn_stats_bf<256><<<800, 256, 0, stream>>>(h1, bnsum1, bnsq1);
  bn_prelu_apply<256><<<(NNODES * DH1 / 4 + 255) / 256, 256, 0, stream>>>(
      h1, bnsum1, bnsq1, bng1, bnb1, pa, h1p, NNODES * DH1);

  // layer 2: cols [0,128)=xl2, [128,256)=xr2
  gemm_mfma<256, 128, 256, 128, 128, 1, 128, 128, true><<<dim3(MB64, 2), 512, 0, stream>>>(
      h1p, Wt2, bias2, xl2, xr2, (u16*)0, att2, axl2, axr2);
  gat_edge<1, 128, 4><<<(NNODES + 3) / 4, 256, 0, stream>>>(
      offs, cnt, epair, xl2, xr2, att2, We2, cb2, axl2, axr2, axw + 4, h2);
  bn_stats_bf<128><<<800, 128, 0, stream>>>(h2, bnsum2, bnsq2);
  final_out_k<<<(NNODES * DOUT / 4 + 255) / 256, 256, 0, stream>>>(
      h2, skipbf, bnsum2, bnsq2, bng2, bnb2, pa, (float*)d_out, NNODES * DOUT);
}

// Round 9
// 448.213 us; speedup vs baseline: 1.9529x; 1.0526x over previous
//
#include <hip/hip_runtime.h>
#include <cstdint>
#include <cstddef>

#define NNODES 50000
#define NEDGES 800000
#define DH1    256   // H*HID = 4*64
#define DOUT   128

typedef unsigned short u16;
typedef __bf16 bf16x8 __attribute__((ext_vector_type(8)));
typedef float  f32x4  __attribute__((ext_vector_type(4)));

__device__ __forceinline__ float bf2f(unsigned int u) {
  union { unsigned int i; float f; } x; x.i = u << 16; return x.f;
}
__device__ __forceinline__ u16 f2bf(float f) {
  union { float f; unsigned int i; } x; x.f = f;
  unsigned int r = x.i + 0x7fffu + ((x.i >> 16) & 1u);  // round-to-nearest-even
  return (u16)(r >> 16);
}
__device__ __forceinline__ void dec8(uint4 r, float* o) {
  o[0] = bf2f(r.x & 0xffffu); o[1] = bf2f(r.x >> 16);
  o[2] = bf2f(r.y & 0xffffu); o[3] = bf2f(r.y >> 16);
  o[4] = bf2f(r.z & 0xffffu); o[5] = bf2f(r.z >> 16);
  o[6] = bf2f(r.w & 0xffffu); o[7] = bf2f(r.w >> 16);
}
__device__ __forceinline__ uint4 pack8(const float* v) {
  uint4 p;
  p.x = (unsigned)f2bf(v[0]) | ((unsigned)f2bf(v[1]) << 16);
  p.y = (unsigned)f2bf(v[2]) | ((unsigned)f2bf(v[3]) << 16);
  p.z = (unsigned)f2bf(v[4]) | ((unsigned)f2bf(v[5]) << 16);
  p.w = (unsigned)f2bf(v[6]) | ((unsigned)f2bf(v[7]) << 16);
  return p;
}

// ---------------- setup: rank-count + cvt + weight-prep + att*We scalars ----------------

#define CNT_BLKS 3125
#define CVT_BLKS 6250
#define W1_BLKS  320
#define W2_BLKS  256

__global__ __launch_bounds__(256) void setup_k(
    const int* __restrict__ dst, int* __restrict__ cnt, int* __restrict__ rank,
    const float* __restrict__ x, u16* __restrict__ xbf,
    const float* __restrict__ Wl1, const float* __restrict__ Wr1,
    const float* __restrict__ bl1, const float* __restrict__ br1,
    const float* __restrict__ Wl2, const float* __restrict__ Wr2,
    const float* __restrict__ bl2, const float* __restrict__ br2,
    const float* __restrict__ skW, const float* __restrict__ skb,
    const float* __restrict__ att1, const float* __restrict__ We1,
    const float* __restrict__ att2, const float* __restrict__ We2,
    u16* __restrict__ Wcat1, float* __restrict__ bias1,
    u16* __restrict__ Wt2, float* __restrict__ bias2,
    float* __restrict__ axw) {
  int b = blockIdx.x, t = threadIdx.x;
  if (b < CNT_BLKS) {
    int e = b * 256 + t;
    if (e < NEDGES) rank[e] = atomicAdd(&cnt[dst[e]], 1);
  } else if (b < CNT_BLKS + CVT_BLKS) {
    int i = ((b - CNT_BLKS) * 256 + t) * 4;
    float4 v = *reinterpret_cast<const float4*>(x + i);
    uint2 pk;
    pk.x = (unsigned)f2bf(v.x) | ((unsigned)f2bf(v.y) << 16);
    pk.y = (unsigned)f2bf(v.z) | ((unsigned)f2bf(v.w) << 16);
    *reinterpret_cast<uint2*>(xbf + i) = pk;
  } else if (b < CNT_BLKS + CVT_BLKS + W1_BLKS) {
    int idx = (b - CNT_BLKS - CVT_BLKS) * 256 + t;   // 640 x 128
    if (idx < 640) bias1[idx] = idx < 256 ? bl1[idx] : idx < 512 ? br1[idx - 256] : skb[idx - 512];
    int n = idx >> 7, k = idx & 127;
    float v = n < 256 ? Wl1[k * 256 + n] : n < 512 ? Wr1[k * 256 + (n - 256)] : skW[k * 128 + (n - 512)];
    Wcat1[idx] = f2bf(v);
  } else if (b < CNT_BLKS + CVT_BLKS + W1_BLKS + W2_BLKS) {
    int idx = (b - CNT_BLKS - CVT_BLKS - W1_BLKS) * 256 + t;  // 256 x 256
    if (idx < 256) bias2[idx] = idx < 128 ? bl2[idx] : br2[idx - 128];
    int n = idx >> 8, k = idx & 255;
    float v = n < 128 ? Wl2[k * 128 + n] : Wr2[k * 128 + (n - 128)];
    Wt2[idx] = f2bf(v);
  } else {
    if (t < 4) {
      float s = 0.f;
      for (int c = 0; c < 64; ++c) s += att1[t * 64 + c] * We1[t * 64 + c];
      axw[t] = s;
    } else if (t == 4) {
      float s = 0.f;
      for (int c = 0; c < 128; ++c) s += att2[c] * We2[c];
      axw[4] = s;
    }
  }
}

// ---------------- CSR ----------------

__global__ __launch_bounds__(256) void offsets_k(const int* __restrict__ cnt, int* __restrict__ offs,
                                                 int* __restrict__ total) {
  int i = blockIdx.x * 256 + threadIdx.x;
  int lane = threadIdx.x & 63;
  int c = (i < NNODES) ? cnt[i] : 0;
  int incl = c;
  #pragma unroll
  for (int d = 1; d < 64; d <<= 1) {
    int t = __shfl_up(incl, d, 64);
    if (lane >= d) incl += t;
  }
  int wtotal = __shfl(incl, 63, 64);
  int base = 0;
  if (lane == 63) base = atomicAdd(total, wtotal);
  base = __shfl(base, 63, 64);
  int off = base + incl - c;
  if (i < NNODES) offs[i] = off;
}

// atomic-free scatter: position = offs[dst] + rank
__global__ __launch_bounds__(256) void scatter_k(const int* __restrict__ src, const int* __restrict__ dst,
                                                 const float* __restrict__ ea, const int* __restrict__ offs,
                                                 const int* __restrict__ rank, int2* __restrict__ epair) {
  int e = blockIdx.x * 256 + threadIdx.x;
  if (e >= NEDGES) return;
  int p = offs[dst[e]] + rank[e];
  int2 v; v.x = src[e]; v.y = __float_as_int(ea[e]);
  epair[p] = v;
}

// ---------------- MFMA GEMM with fused att-dot epilogue ----------------

template<int K, int B1, int B2, int LDC0, int LDC1, int LDC2, int SPAN, int ATTLEN, bool DO_ATT>
__global__ __launch_bounds__(512) void gemm_mfma(
    const u16* __restrict__ A, const u16* __restrict__ Wt, const float* __restrict__ bias,
    u16* __restrict__ C0, u16* __restrict__ C1, u16* __restrict__ C2,
    const float* __restrict__ att, float* __restrict__ axl, float* __restrict__ axr) {
  constexpr int LDA = K + 8;
  constexpr int CSTR = 136;
  constexpr size_t ABYTES = (size_t)64 * LDA * 2;
  constexpr size_t CBYTES = (size_t)64 * CSTR * 2;
  constexpr size_t SBYTES = ABYTES > CBYTES ? ABYTES : CBYTES;
  __shared__ __align__(16) char smem[SBYTES];
  __shared__ float attS[128];
  u16* As = (u16*)smem;
  const int row0 = blockIdx.x * 64;
  const int tid = threadIdx.x;
  #pragma unroll
  for (int it = 0; it < K / 32; ++it) {
    int chunk = it * 512 + tid;
    int row = (chunk * 4) / K;
    int col = (chunk * 4) % K;
    uint2 v; v.x = 0u; v.y = 0u;
    int gr = row0 + row;
    if (gr < NNODES) v = *reinterpret_cast<const uint2*>(A + (size_t)gr * K + col);
    *reinterpret_cast<uint2*>(&As[row * LDA + col]) = v;
  }
  __syncthreads();
  const int w = tid >> 6, lane = tid & 63, q = lane >> 4, l16 = lane & 15;
  const int tc = w * 16 + l16;
  const int cb = blockIdx.y * 128;
  const int ncol = cb + tc;
  f32x4 acc[4];
  #pragma unroll
  for (int rt = 0; rt < 4; ++rt) acc[rt] = (f32x4){0.f, 0.f, 0.f, 0.f};
  const u16* wp = Wt + (size_t)ncol * K + q * 8;
  #pragma unroll
  for (int ks = 0; ks < K / 32; ++ks) {
    bf16x8 b = *reinterpret_cast<const bf16x8*>(wp + ks * 32);
    #pragma unroll
    for (int rt = 0; rt < 4; ++rt) {
      bf16x8 a = *reinterpret_cast<const bf16x8*>(&As[(rt * 16 + l16) * LDA + ks * 32 + q * 8]);
      acc[rt] = __builtin_amdgcn_mfma_f32_16x16x32_bf16(a, b, acc[rt], 0, 0, 0);
    }
  }
  const float bval = bias[ncol];
  __syncthreads();
  u16* Cs = (u16*)smem;
  #pragma unroll
  for (int rt = 0; rt < 4; ++rt)
    #pragma unroll
    for (int r = 0; r < 4; ++r)
      Cs[(rt * 16 + q * 4 + r) * CSTR + tc] = f2bf(acc[rt][r] + bval);
  __syncthreads();
  {
    u16* Cg; int LD, cc;
    if (cb < B1)      { Cg = C0; LD = LDC0; cc = cb; }
    else if (cb < B2) { Cg = C1; LD = LDC1; cc = cb - B1; }
    else              { Cg = C2; LD = LDC2; cc = cb - B2; }
    #pragma unroll
    for (int it = 0; it < 2; ++it) {
      int ch = it * 512 + tid;
      int row = ch / 16, co = (ch % 16) * 8;
      int grow = row0 + row;
      if (grow < NNODES) {
        uint4 v = *reinterpret_cast<const uint4*>(&Cs[row * CSTR + co]);
        *reinterpret_cast<uint4*>(Cg + (size_t)grow * LD + cc + co) = v;
      }
    }
  }
  if constexpr (DO_ATT) {
    if (cb < B2) {
      if (tid < 128) attS[tid] = att[(cb + tid) % ATTLEN];
      __syncthreads();
      constexpr int TPR = 128 / SPAN;
      constexpr int HEADS = B1 / SPAN;
      if (tid < 64 * TPR) {
        int row = tid / TPR, hb = tid % TPR;
        const u16* cr = Cs + row * CSTR + hb * SPAN;
        float s = 0.f;
        for (int c = 0; c < SPAN; ++c) s += bf2f(cr[c]) * attS[hb * SPAN + c];
        int grow = row0 + row;
        if (grow < NNODES) {
          int cbl = cb < B1 ? cb : cb - B1;
          int lh = cbl / SPAN + hb;
          float* dstp = (cb < B1) ? axl : axr;
          dstp[grow * HEADS + lh] = s;
        }
      }
    }
  }
}

// ---------------- gemm2 with fused BN1+PReLU on the A path ----------------
// A = raw h1 (bf16); BN scale/shift computed per block from raw sums; rest = gemm_mfma.

__global__ __launch_bounds__(512) void gemm2_bn(
    const u16* __restrict__ A, const u16* __restrict__ Wt, const float* __restrict__ bias,
    u16* __restrict__ C0, u16* __restrict__ C1,
    const float* __restrict__ att, float* __restrict__ axl, float* __restrict__ axr,
    const float* __restrict__ bnsum, const float* __restrict__ bnsq,
    const float* __restrict__ bng, const float* __restrict__ bnb,
    const float* __restrict__ pap) {
  constexpr int K = 256, B1 = 128;
  constexpr int LDA = K + 8;
  constexpr int CSTR = 136;
  __shared__ __align__(16) char smem[(size_t)64 * LDA * 2];
  __shared__ float attS[128];
  __shared__ float scS[256], shS[256];
  u16* As = (u16*)smem;
  const int tid = threadIdx.x;
  const int row0 = blockIdx.x * 64;
  const float pa = pap[0];
  if (tid < 256) {
    const float invN = 1.0f / (float)NNODES;
    float mu = bnsum[tid] * invN;
    float var = bnsq[tid] * invN - mu * mu;
    float s = bng[tid] * rsqrtf(var + 1e-5f);
    scS[tid] = s;
    shS[tid] = bnb[tid] - mu * s;
  }
  __syncthreads();
  #pragma unroll
  for (int it = 0; it < K / 32; ++it) {
    int chunk = it * 512 + tid;
    int row = chunk / 64;
    int col = (chunk % 64) * 4;
    uint2 v; v.x = 0u; v.y = 0u;
    int gr = row0 + row;
    if (gr < NNODES) v = *reinterpret_cast<const uint2*>(A + (size_t)gr * K + col);
    float o0 = bf2f(v.x & 0xffffu) * scS[col]     + shS[col];
    float o1 = bf2f(v.x >> 16)     * scS[col + 1] + shS[col + 1];
    float o2 = bf2f(v.y & 0xffffu) * scS[col + 2] + shS[col + 2];
    float o3 = bf2f(v.y >> 16)     * scS[col + 3] + shS[col + 3];
    o0 = o0 > 0.f ? o0 : pa * o0;
    o1 = o1 > 0.f ? o1 : pa * o1;
    o2 = o2 > 0.f ? o2 : pa * o2;
    o3 = o3 > 0.f ? o3 : pa * o3;
    uint2 pk;
    pk.x = (unsigned)f2bf(o0) | ((unsigned)f2bf(o1) << 16);
    pk.y = (unsigned)f2bf(o2) | ((unsigned)f2bf(o3) << 16);
    *reinterpret_cast<uint2*>(&As[row * LDA + col]) = pk;
  }
  __syncthreads();
  const int w = tid >> 6, lane = tid & 63, q = lane >> 4, l16 = lane & 15;
  const int tc = w * 16 + l16;
  const int cb = blockIdx.y * 128;
  const int ncol = cb + tc;
  f32x4 acc[4];
  #pragma unroll
  for (int rt = 0; rt < 4; ++rt) acc[rt] = (f32x4){0.f, 0.f, 0.f, 0.f};
  const u16* wp = Wt + (size_t)ncol * K + q * 8;
  #pragma unroll
  for (int ks = 0; ks < K / 32; ++ks) {
    bf16x8 b = *reinterpret_cast<const bf16x8*>(wp + ks * 32);
    #pragma unroll
    for (int rt = 0; rt < 4; ++rt) {
      bf16x8 a = *reinterpret_cast<const bf16x8*>(&As[(rt * 16 + l16) * LDA + ks * 32 + q * 8]);
      acc[rt] = __builtin_amdgcn_mfma_f32_16x16x32_bf16(a, b, acc[rt], 0, 0, 0);
    }
  }
  const float bval = bias[ncol];
  __syncthreads();
  u16* Cs = (u16*)smem;
  #pragma unroll
  for (int rt = 0; rt < 4; ++rt)
    #pragma unroll
    for (int r = 0; r < 4; ++r)
      Cs[(rt * 16 + q * 4 + r) * CSTR + tc] = f2bf(acc[rt][r] + bval);
  __syncthreads();
  {
    u16* Cg = (cb < B1) ? C0 : C1;
    int cc = (cb < B1) ? cb : cb - B1;
    #pragma unroll
    for (int it = 0; it < 2; ++it) {
      int ch = it * 512 + tid;
      int row = ch / 16, co = (ch % 16) * 8;
      int grow = row0 + row;
      if (grow < NNODES) {
        uint4 v = *reinterpret_cast<const uint4*>(&Cs[row * CSTR + co]);
        *reinterpret_cast<uint4*>(Cg + (size_t)grow * 128 + cc + co) = v;
      }
    }
  }
  {
    if (tid < 128) attS[tid] = att[(cb + tid) % 128];
    __syncthreads();
    if (tid < 64) {
      int row = tid;
      const u16* cr = Cs + row * CSTR;
      float s = 0.f;
      for (int c = 0; c < 128; ++c) s += bf2f(cr[c]) * attS[c];
      int grow = row0 + row;
      if (grow < NNODES) {
        float* dstp = (cb < B1) ? axl : axr;
        dstp[grow] = s;
      }
    }
  }
}

// ---------------- GATv2 edge pass: EPW edges/wave, CPL=8, scalar fma (abs folds) ----------------
// s = 0.6*(axl[src]+axr[dst]+ea*aWe) + 0.4*sum(att*|m|)   (exact LeakyReLU identity)

template<int HEADS, int CHAN, int EPW>
__global__ __launch_bounds__(256) void gat_edge(
    const int* __restrict__ offs, const int* __restrict__ cnt,
    const int2* __restrict__ epair,
    const u16* __restrict__ xl, const u16* __restrict__ xr,
    const float* __restrict__ att, const float* __restrict__ We,
    const float* __restrict__ cb,
    const float* __restrict__ axl, const float* __restrict__ axr,
    const float* __restrict__ aWep, u16* __restrict__ hout) {
  constexpr int HC  = HEADS * CHAN;
  constexpr int GSZ = 64 / EPW;       // lanes per edge group
  constexpr int CPL = HC / GSZ;       // channels per lane
  constexpr int LPH = CHAN / CPL;     // lanes per head cluster
  static_assert(CPL == 8, "layout");

  int node = __builtin_amdgcn_readfirstlane((int)(blockIdx.x * 4 + (threadIdx.x >> 6)));
  if (node >= NNODES) return;
  const int lane = threadIdx.x & 63;
  const int g    = lane / GSZ;
  const int lgs  = lane & (GSZ - 1);
  const int h    = lgs / LPH;
  const int cbase = lgs * CPL;

  float xrv[8], attv[8], wev[8];
  {
    uint4 xrr = *reinterpret_cast<const uint4*>(xr + (size_t)node * HC + cbase);
    dec8(xrr, xrv);
    float4 a0 = *reinterpret_cast<const float4*>(att + cbase);
    float4 a1 = *reinterpret_cast<const float4*>(att + cbase + 4);
    float4 w0 = *reinterpret_cast<const float4*>(We + cbase);
    float4 w1 = *reinterpret_cast<const float4*>(We + cbase + 4);
    attv[0]=a0.x; attv[1]=a0.y; attv[2]=a0.z; attv[3]=a0.w;
    attv[4]=a1.x; attv[5]=a1.y; attv[6]=a1.z; attv[7]=a1.w;
    wev[0]=w0.x; wev[1]=w0.y; wev[2]=w0.z; wev[3]=w0.w;
    wev[4]=w1.x; wev[5]=w1.y; wev[6]=w1.z; wev[7]=w1.w;
  }
  const float aWe = aWep[h];
  const float axr_n = axr[node * HEADS + h];
  const int off = __builtin_amdgcn_readfirstlane(offs[node]);
  const int deg = __builtin_amdgcn_readfirstlane(cnt[node]);

  float den = 0.f;
  float accv[8];
  #pragma unroll
  for (int c = 0; c < 8; ++c) accv[c] = 0.f;

  if (deg > 0) {
    const int last = deg - 1;
    auto midx = [&](int i) { int j = i * EPW + g; return off + (j < last ? j : last); };
    int2 p_cur = epair[midx(0)];
    int2 p_nxt = epair[midx(1)];
    uint4 r_cur; float ax_cur;
    { int s = p_cur.x;
      r_cur = *reinterpret_cast<const uint4*>(xl + (size_t)s * HC + cbase);
      ax_cur = axl[s * HEADS + h]; }
    const int niter = (deg + EPW - 1) / EPW;
    for (int i = 0; i < niter; ++i) {
      int2 p_n2 = epair[midx(i + 2)];
      uint4 r_n; float ax_n;
      { int s = p_nxt.x;
        r_n = *reinterpret_cast<const uint4*>(xl + (size_t)s * HC + cbase);
        ax_n = axl[s * HEADS + h]; }
      float ea = __int_as_float(p_cur.y);
      float xlv[8];
      dec8(r_cur, xlv);
      float part2 = 0.f;
      #pragma unroll
      for (int c = 0; c < 8; ++c) {
        float m = xlv[c] + fmaf(ea, wev[c], xrv[c]);
        part2 = fmaf(fabsf(m), attv[c], part2);
      }
      #pragma unroll
      for (int d = 1; d < LPH; d <<= 1) part2 += __shfl_xor(part2, d, 64);
      float ssum = ax_cur + fmaf(ea, aWe, axr_n);
      float sc = fmaf(0.4f, part2, 0.6f * ssum);
      float e = __expf(sc);
      e = (i * EPW + g <= last) ? e : 0.f;
      den += e;
      #pragma unroll
      for (int c = 0; c < 8; ++c) accv[c] = fmaf(e, xlv[c], accv[c]);
      p_cur = p_nxt; p_nxt = p_n2; r_cur = r_n; ax_cur = ax_n;
    }
  }
  #pragma unroll
  for (int d = GSZ; d < 64; d <<= 1) {
    den += __shfl_xor(den, d, 64);
    #pragma unroll
    for (int c = 0; c < 8; ++c) accv[c] += __shfl_xor(accv[c], d, 64);
  }
  if (g == 0) {
    float inv = 1.0f / (den + 1e-16f);
    float4 c0 = *reinterpret_cast<const float4*>(cb + cbase);
    float4 c1 = *reinterpret_cast<const float4*>(cb + cbase + 4);
    float ov[8];
    ov[0] = accv[0] * inv + c0.x; ov[1] = accv[1] * inv + c0.y;
    ov[2] = accv[2] * inv + c0.z; ov[3] = accv[3] * inv + c0.w;
    ov[4] = accv[4] * inv + c1.x; ov[5] = accv[5] * inv + c1.y;
    ov[6] = accv[6] * inv + c1.z; ov[7] = accv[7] * inv + c1.w;
    *reinterpret_cast<uint4*>(hout + (size_t)node * HC + cbase) = pack8(ov);
  }
}

// ---------------- BatchNorm ----------------

template<int NC>
__global__ void bn_stats_bf(const u16* __restrict__ h, float* __restrict__ sum, float* __restrict__ sq) {
  int c = threadIdx.x;
  float s = 0.f, q = 0.f;
  for (int r = blockIdx.x; r < NNODES; r += gridDim.x) {
    float v = bf2f(h[(size_t)r * NC + c]);
    s += v; q += v * v;
  }
  atomicAdd(&sum[c], s);
  atomicAdd(&sq[c], q);
}

__global__ __launch_bounds__(256) void final_out_k(
    const u16* __restrict__ h2, const u16* __restrict__ skip,
    const float* __restrict__ sum, const float* __restrict__ sq,
    const float* __restrict__ g, const float* __restrict__ bb_,
    const float* __restrict__ pap, float* __restrict__ outp, int total) {
  int i = (blockIdx.x * 256 + threadIdx.x) * 4;
  if (i >= total) return;
  const float invN = 1.0f / (float)NNODES;
  float pa = pap[0];
  int c = i & 127;
  float4 sm = *reinterpret_cast<const float4*>(sum + c);
  float4 qq = *reinterpret_cast<const float4*>(sq + c);
  float4 gg = *reinterpret_cast<const float4*>(g + c);
  float4 bb = *reinterpret_cast<const float4*>(bb_ + c);
  float mu, var, sc[4], sh[4];
  mu = sm.x * invN; var = qq.x * invN - mu * mu; sc[0] = gg.x * rsqrtf(var + 1e-5f); sh[0] = bb.x - mu * sc[0];
  mu = sm.y * invN; var = qq.y * invN - mu * mu; sc[1] = gg.y * rsqrtf(var + 1e-5f); sh[1] = bb.y - mu * sc[1];
  mu = sm.z * invN; var = qq.z * invN - mu * mu; sc[2] = gg.z * rsqrtf(var + 1e-5f); sh[2] = bb.z - mu * sc[2];
  mu = sm.w * invN; var = qq.w * invN - mu * mu; sc[3] = gg.w * rsqrtf(var + 1e-5f); sh[3] = bb.w - mu * sc[3];
  uint2 raw = *reinterpret_cast<const uint2*>(h2 + i);
  float v0 = bf2f(raw.x & 0xffffu), v1 = bf2f(raw.x >> 16);
  float v2 = bf2f(raw.y & 0xffffu), v3 = bf2f(raw.y >> 16);
  uint2 skr = *reinterpret_cast<const uint2*>(skip + i);
  float s0 = bf2f(skr.x & 0xffffu), s1 = bf2f(skr.x >> 16);
  float s2 = bf2f(skr.y & 0xffffu), s3 = bf2f(skr.y >> 16);
  float4 o;
  o.x = v0 * sc[0] + sh[0]; o.x = (o.x > 0.f ? o.x : pa * o.x) + s0;
  o.y = v1 * sc[1] + sh[1]; o.y = (o.y > 0.f ? o.y : pa * o.y) + s1;
  o.z = v2 * sc[2] + sh[2]; o.z = (o.z > 0.f ? o.z : pa * o.z) + s2;
  o.w = v3 * sc[3] + sh[3]; o.w = (o.w > 0.f ? o.w : pa * o.w) + s3;
  *reinterpret_cast<float4*>(outp + i) = o;
}

// ---------------- launch ----------------

extern "C" void kernel_launch(void* const* d_in, const int* in_sizes, int n_in,
                              void* d_out, int out_size, void* d_ws, size_t ws_size,
                              hipStream_t stream) {
  (void)in_sizes; (void)n_in; (void)out_size; (void)ws_size;
  const float* x    = (const float*)d_in[0];
  const int*   ei   = (const int*)d_in[1];
  const float* ea   = (const float*)d_in[2];
  const float* Wl1  = (const float*)d_in[3];
  const float* bl1  = (const float*)d_in[4];
  const float* Wr1  = (const float*)d_in[5];
  const float* br1  = (const float*)d_in[6];
  const float* We1  = (const float*)d_in[7];
  const float* att1 = (const float*)d_in[8];
  const float* cb1  = (const float*)d_in[9];
  const float* bng1 = (const float*)d_in[10];
  const float* bnb1 = (const float*)d_in[11];
  const float* pa   = (const float*)d_in[12];
  const float* Wl2  = (const float*)d_in[13];
  const float* bl2  = (const float*)d_in[14];
  const float* Wr2  = (const float*)d_in[15];
  const float* br2  = (const float*)d_in[16];
  const float* We2  = (const float*)d_in[17];
  const float* att2 = (const float*)d_in[18];
  const float* cb2  = (const float*)d_in[19];
  const float* bng2 = (const float*)d_in[20];
  const float* bnb2 = (const float*)d_in[21];
  const float* skW  = (const float*)d_in[22];
  const float* skb  = (const float*)d_in[23];
  const int* srcp = ei;
  const int* dstp = ei + NEDGES;

  char* base = (char*)d_ws;
  size_t off = 0;
  auto alloc = [&](size_t bytes) -> char* {
    char* p = base + off;
    off = (off + bytes + 255) & ~(size_t)255;
    return p;
  };
  size_t zero_ints = 1 + NNODES + 256 + 256 + 128 + 128;
  char* zbase = alloc(zero_ints * 4);
  int*   totalp = (int*)zbase;
  int*   cnt    = totalp + 1;
  float* bnsum1 = (float*)(cnt + NNODES);
  float* bnsq1  = bnsum1 + 256;
  float* bnsum2 = bnsq1 + 256;
  float* bnsq2  = bnsum2 + 128;

  int*   offs    = (int*)alloc((size_t)NNODES * 4);
  int*   rank    = (int*)alloc((size_t)NEDGES * 4);
  int2*  epair   = (int2*)alloc((size_t)NEDGES * 8);
  const size_t RBYTES = (size_t)NNODES * DH1 * 2;  // 25.6 MB
  char* regionA = alloc(RBYTES);   // xl1(bf16) -> h2(bf16)
  char* regionB = alloc(RBYTES);   // xr1(bf16) -> xl2+xr2(bf16)
  char* regionC = alloc(RBYTES);   // h1(bf16)
  u16*   xbf    = (u16*)alloc((size_t)NNODES * 128 * 2);
  u16*   skipbf = (u16*)alloc((size_t)NNODES * 128 * 2);
  u16*   Wcat1  = (u16*)alloc(640 * 128 * 2);
  u16*   Wt2    = (u16*)alloc(256 * 256 * 2);
  float* bias1  = (float*)alloc(640 * 4);
  float* bias2  = (float*)alloc(256 * 4);
  float* axw    = (float*)alloc(8 * 4);
  float* axl1   = (float*)alloc((size_t)NNODES * 4 * 4);
  float* axr1   = (float*)alloc((size_t)NNODES * 4 * 4);
  float* axl2   = (float*)alloc((size_t)NNODES * 4);
  float* axr2   = (float*)alloc((size_t)NNODES * 4);

  u16*   xl1     = (u16*)regionA;
  u16*   xr1     = (u16*)regionB;
  u16*   h1      = (u16*)regionC;
  u16*   xl2     = (u16*)regionB;
  u16*   xr2     = (u16*)(regionB + (size_t)NNODES * DOUT * 2);
  u16*   h2      = (u16*)regionA;

  hipMemsetAsync(zbase, 0, zero_ints * 4, stream);

  const int EB = (NEDGES + 255) / 256;
  const int NB = (NNODES + 255) / 256;
  setup_k<<<CNT_BLKS + CVT_BLKS + W1_BLKS + W2_BLKS + 1, 256, 0, stream>>>(
      dstp, cnt, rank, x, xbf, Wl1, Wr1, bl1, br1, Wl2, Wr2, bl2, br2, skW, skb,
      att1, We1, att2, We2, Wcat1, bias1, Wt2, bias2, axw);
  offsets_k<<<NB, 256, 0, stream>>>(cnt, offs, totalp);
  scatter_k<<<EB, 256, 0, stream>>>(srcp, dstp, ea, offs, rank, epair);

  const int MB64 = (NNODES + 63) / 64;
  // layer 1 + skip: cols [0,256)=xl1, [256,512)=xr1, [512,640)=skip
  gemm_mfma<128, 256, 512, 256, 256, 128, 64, 256, true><<<dim3(MB64, 5), 512, 0, stream>>>(
      xbf, Wcat1, bias1, xl1, xr1, skipbf, att1, axl1, axr1);
  gat_edge<4, 64, 2><<<(NNODES + 3) / 4, 256, 0, stream>>>(
      offs, cnt, epair, xl1, xr1, att1, We1, cb1, axl1, axr1, axw, h1);
  bn_stats_bf<256><<<800, 256, 0, stream>>>(h1, bnsum1, bnsq1);

  // layer 2 (BN1+PReLU fused into A-staging): cols [0,128)=xl2, [128,256)=xr2
  gemm2_bn<<<dim3(MB64, 2), 512, 0, stream>>>(
      h1, Wt2, bias2, xl2, xr2, att2, axl2, axr2, bnsum1, bnsq1, bng1, bnb1, pa);
  gat_edge<1, 128, 4><<<(NNODES + 3) / 4, 256, 0, stream>>>(
      offs, cnt, epair, xl2, xr2, att2, We2, cb2, axl2, axr2, axw + 4, h2);
  bn_stats_bf<128><<<800, 128, 0, stream>>>(h2, bnsum2, bnsq2);
  final_out_k<<<(NNODES * DOUT / 4 + 255) / 256, 256, 0, stream>>>(
      h2, skipbf, bnsum2, bnsq2, bng2, bnb2, pa, (float*)d_out, NNODES * DOUT);
}

// Round 10
// 444.496 us; speedup vs baseline: 1.9693x; 1.0084x over previous
//
#include <hip/hip_runtime.h>
#include <cstdint>
#include <cstddef>

#define NNODES 50000
#define NEDGES 800000
#define DH1    256   // H*HID = 4*64
#define DOUT   128

typedef unsigned short u16;
typedef __bf16 bf16x8 __attribute__((ext_vector_type(8)));
typedef float  f32x4  __attribute__((ext_vector_type(4)));

__device__ __forceinline__ float bf2f(unsigned int u) {
  union { unsigned int i; float f; } x; x.i = u << 16; return x.f;
}
__device__ __forceinline__ u16 f2bf(float f) {
  union { float f; unsigned int i; } x; x.f = f;
  unsigned int r = x.i + 0x7fffu + ((x.i >> 16) & 1u);  // round-to-nearest-even
  return (u16)(r >> 16);
}
__device__ __forceinline__ void dec8(uint4 r, float* o) {
  o[0] = bf2f(r.x & 0xffffu); o[1] = bf2f(r.x >> 16);
  o[2] = bf2f(r.y & 0xffffu); o[3] = bf2f(r.y >> 16);
  o[4] = bf2f(r.z & 0xffffu); o[5] = bf2f(r.z >> 16);
  o[6] = bf2f(r.w & 0xffffu); o[7] = bf2f(r.w >> 16);
}
__device__ __forceinline__ uint4 pack8(const float* v) {
  uint4 p;
  p.x = (unsigned)f2bf(v[0]) | ((unsigned)f2bf(v[1]) << 16);
  p.y = (unsigned)f2bf(v[2]) | ((unsigned)f2bf(v[3]) << 16);
  p.z = (unsigned)f2bf(v[4]) | ((unsigned)f2bf(v[5]) << 16);
  p.w = (unsigned)f2bf(v[6]) | ((unsigned)f2bf(v[7]) << 16);
  return p;
}
// xor-lane swizzle with immediate (no address-setup VALU, unlike ds_bpermute)
template<int IMM>
__device__ __forceinline__ float swz(float v) {
  return __int_as_float(__builtin_amdgcn_ds_swizzle(__float_as_int(v), IMM));
}

// ---------------- setup: rank-count + cvt + weight-prep + att*We + epair pad ----------------

#define CNT_BLKS 3125
#define CVT_BLKS 6250
#define W1_BLKS  320
#define W2_BLKS  256

__global__ __launch_bounds__(256) void setup_k(
    const int* __restrict__ dst, int* __restrict__ cnt, int* __restrict__ rank,
    const float* __restrict__ x, u16* __restrict__ xbf,
    const float* __restrict__ Wl1, const float* __restrict__ Wr1,
    const float* __restrict__ bl1, const float* __restrict__ br1,
    const float* __restrict__ Wl2, const float* __restrict__ Wr2,
    const float* __restrict__ bl2, const float* __restrict__ br2,
    const float* __restrict__ skW, const float* __restrict__ skb,
    const float* __restrict__ att1, const float* __restrict__ We1,
    const float* __restrict__ att2, const float* __restrict__ We2,
    u16* __restrict__ Wcat1, float* __restrict__ bias1,
    u16* __restrict__ Wt2, float* __restrict__ bias2,
    float* __restrict__ axw, int2* __restrict__ epair) {
  int b = blockIdx.x, t = threadIdx.x;
  if (b < CNT_BLKS) {
    int e = b * 256 + t;
    if (e < NEDGES) rank[e] = atomicAdd(&cnt[dst[e]], 1);
  } else if (b < CNT_BLKS + CVT_BLKS) {
    int i = ((b - CNT_BLKS) * 256 + t) * 4;
    float4 v = *reinterpret_cast<const float4*>(x + i);
    uint2 pk;
    pk.x = (unsigned)f2bf(v.x) | ((unsigned)f2bf(v.y) << 16);
    pk.y = (unsigned)f2bf(v.z) | ((unsigned)f2bf(v.w) << 16);
    *reinterpret_cast<uint2*>(xbf + i) = pk;
  } else if (b < CNT_BLKS + CVT_BLKS + W1_BLKS) {
    int idx = (b - CNT_BLKS - CVT_BLKS) * 256 + t;   // 640 x 128
    if (idx < 640) bias1[idx] = idx < 256 ? bl1[idx] : idx < 512 ? br1[idx - 256] : skb[idx - 512];
    int n = idx >> 7, k = idx & 127;
    float v = n < 256 ? Wl1[k * 256 + n] : n < 512 ? Wr1[k * 256 + (n - 256)] : skW[k * 128 + (n - 512)];
    Wcat1[idx] = f2bf(v);
  } else if (b < CNT_BLKS + CVT_BLKS + W1_BLKS + W2_BLKS) {
    int idx = (b - CNT_BLKS - CVT_BLKS - W1_BLKS) * 256 + t;  // 256 x 256
    if (idx < 256) bias2[idx] = idx < 128 ? bl2[idx] : br2[idx - 128];
    int n = idx >> 8, k = idx & 255;
    float v = n < 128 ? Wl2[k * 128 + n] : Wr2[k * 128 + (n - 128)];
    Wt2[idx] = f2bf(v);
  } else if (b == CNT_BLKS + CVT_BLKS + W1_BLKS + W2_BLKS) {
    if (t < 4) {
      float s = 0.f;
      for (int c = 0; c < 64; ++c) s += att1[t * 64 + c] * We1[t * 64 + c];
      axw[t] = s;
    } else if (t == 4) {
      float s = 0.f;
      for (int c = 0; c < 128; ++c) s += att2[c] * We2[c];
      axw[4] = s;
    }
  } else {
    // zero the epair padding (enables clamp-free prefetch in gat_edge)
    int2 z; z.x = 0; z.y = 0;
    epair[NEDGES + t] = z;
  }
}

// ---------------- CSR ----------------

__global__ __launch_bounds__(256) void offsets_k(const int* __restrict__ cnt, int* __restrict__ offs,
                                                 int* __restrict__ total) {
  int i = blockIdx.x * 256 + threadIdx.x;
  int lane = threadIdx.x & 63;
  int c = (i < NNODES) ? cnt[i] : 0;
  int incl = c;
  #pragma unroll
  for (int d = 1; d < 64; d <<= 1) {
    int t = __shfl_up(incl, d, 64);
    if (lane >= d) incl += t;
  }
  int wtotal = __shfl(incl, 63, 64);
  int base = 0;
  if (lane == 63) base = atomicAdd(total, wtotal);
  base = __shfl(base, 63, 64);
  int off = base + incl - c;
  if (i < NNODES) offs[i] = off;
}

__global__ __launch_bounds__(256) void scatter_k(const int* __restrict__ src, const int* __restrict__ dst,
                                                 const float* __restrict__ ea, const int* __restrict__ offs,
                                                 const int* __restrict__ rank, int2* __restrict__ epair) {
  int e = blockIdx.x * 256 + threadIdx.x;
  if (e >= NEDGES) return;
  int p = offs[dst[e]] + rank[e];
  int2 v; v.x = src[e]; v.y = __float_as_int(ea[e]);
  epair[p] = v;
}

// ---------------- MFMA GEMM: stage A once, loop NPASS col-blocks internally ----------------
// C routing: [0,B1)->C0, [B1,B2)->C1, [B2,..)->C2 (bf16). Optional fused BN+PReLU on A.
// Optional att-dot epilogue (cols < B2): ax[row, head] = sum att[c]*C[row,c] per SPAN block.

template<int K, int NPASS, int B1, int B2, int LDC0, int LDC1, int LDC2,
         int SPAN, int ATTLEN, bool DO_ATT, bool FUSE_BN>
__global__ __launch_bounds__(512) void gemm_fused(
    const u16* __restrict__ A, const u16* __restrict__ Wt, const float* __restrict__ bias,
    u16* __restrict__ C0, u16* __restrict__ C1, u16* __restrict__ C2,
    const float* __restrict__ att, float* __restrict__ axl, float* __restrict__ axr,
    const float* __restrict__ bnsum, const float* __restrict__ bnsq,
    const float* __restrict__ bng, const float* __restrict__ bnb,
    const float* __restrict__ pap) {
  constexpr int LDA = K + 8;
  constexpr int CSTR = 136;
  __shared__ __align__(16) u16 As[64 * LDA];
  __shared__ __align__(16) u16 Cs[64 * CSTR];
  __shared__ float attS[128];
  __shared__ float scS[K], shS[K];
  const int tid = threadIdx.x;
  const int row0 = blockIdx.x * 64;

  if constexpr (FUSE_BN) {
    if (tid < K) {
      const float invN = 1.0f / (float)NNODES;
      float mu = bnsum[tid] * invN;
      float var = bnsq[tid] * invN - mu * mu;
      float s = bng[tid] * rsqrtf(var + 1e-5f);
      scS[tid] = s;
      shS[tid] = bnb[tid] - mu * s;
    }
    __syncthreads();
  }
  const float pa = FUSE_BN ? pap[0] : 0.f;
  // stage A (64 x K bf16)
  #pragma unroll
  for (int it = 0; it < K / 32; ++it) {
    int chunk = it * 512 + tid;
    int row = chunk / (K / 4);
    int col = (chunk % (K / 4)) * 4;
    uint2 v; v.x = 0u; v.y = 0u;
    int gr = row0 + row;
    if (gr < NNODES) v = *reinterpret_cast<const uint2*>(A + (size_t)gr * K + col);
    if constexpr (FUSE_BN) {
      float o0 = bf2f(v.x & 0xffffu) * scS[col]     + shS[col];
      float o1 = bf2f(v.x >> 16)     * scS[col + 1] + shS[col + 1];
      float o2 = bf2f(v.y & 0xffffu) * scS[col + 2] + shS[col + 2];
      float o3 = bf2f(v.y >> 16)     * scS[col + 3] + shS[col + 3];
      o0 = o0 > 0.f ? o0 : pa * o0;
      o1 = o1 > 0.f ? o1 : pa * o1;
      o2 = o2 > 0.f ? o2 : pa * o2;
      o3 = o3 > 0.f ? o3 : pa * o3;
      v.x = (unsigned)f2bf(o0) | ((unsigned)f2bf(o1) << 16);
      v.y = (unsigned)f2bf(o2) | ((unsigned)f2bf(o3) << 16);
    }
    *reinterpret_cast<uint2*>(&As[row * LDA + col]) = v;
  }
  __syncthreads();

  const int w = tid >> 6, lane = tid & 63, q = lane >> 4, l16 = lane & 15;
  const int tc = w * 16 + l16;

  #pragma unroll
  for (int p = 0; p < NPASS; ++p) {
    const int cb = p * 128;
    const int ncol = cb + tc;
    f32x4 acc[4];
    #pragma unroll
    for (int rt = 0; rt < 4; ++rt) acc[rt] = (f32x4){0.f, 0.f, 0.f, 0.f};
    const u16* wp = Wt + (size_t)ncol * K + q * 8;
    #pragma unroll
    for (int ks = 0; ks < K / 32; ++ks) {
      bf16x8 b = *reinterpret_cast<const bf16x8*>(wp + ks * 32);
      #pragma unroll
      for (int rt = 0; rt < 4; ++rt) {
        bf16x8 a = *reinterpret_cast<const bf16x8*>(&As[(rt * 16 + l16) * LDA + ks * 32 + q * 8]);
        acc[rt] = __builtin_amdgcn_mfma_f32_16x16x32_bf16(a, b, acc[rt], 0, 0, 0);
      }
    }
    const float bval = bias[ncol];
    #pragma unroll
    for (int rt = 0; rt < 4; ++rt)
      #pragma unroll
      for (int r = 0; r < 4; ++r)
        Cs[(rt * 16 + q * 4 + r) * CSTR + tc] = f2bf(acc[rt][r] + bval);
    if (DO_ATT && cb < B2 && tid < 128) attS[tid] = att[(cb + tid) % ATTLEN];
    __syncthreads();
    // coalesced C store
    {
      u16* Cg; int LD, cc;
      if (cb < B1)      { Cg = C0; LD = LDC0; cc = cb; }
      else if (cb < B2) { Cg = C1; LD = LDC1; cc = cb - B1; }
      else              { Cg = C2; LD = LDC2; cc = cb - B2; }
      #pragma unroll
      for (int it = 0; it < 2; ++it) {
        int ch = it * 512 + tid;
        int row = ch / 16, co = (ch % 16) * 8;
        int grow = row0 + row;
        if (grow < NNODES) {
          uint4 v = *reinterpret_cast<const uint4*>(&Cs[row * CSTR + co]);
          *reinterpret_cast<uint4*>(Cg + (size_t)grow * LD + cc + co) = v;
        }
      }
    }
    // att-dot: parallel (SPAN/16 threads per (row, head)), shfl-reduced
    if constexpr (DO_ATT) {
      if (cb < B2) {
        constexpr int TPU = SPAN / 16;     // threads per unit (4 or 8)
        constexpr int HIT = 128 / SPAN;    // heads in tile (2 or 1)
        constexpr int HEADS = B1 / SPAN;
        int unit = tid / TPU, sub = tid % TPU;
        int row = unit / HIT, hb = unit % HIT;
        int c0 = hb * SPAN + sub * 16;
        float s = 0.f;
        #pragma unroll
        for (int c = 0; c < 16; ++c)
          s += bf2f(Cs[row * CSTR + c0 + c]) * attS[c0 + c];
        #pragma unroll
        for (int d = 1; d < TPU; d <<= 1) s += __shfl_xor(s, d, 64);
        int grow = row0 + row;
        if (sub == 0 && grow < NNODES) {
          int cbl = cb < B1 ? cb : cb - B1;
          int head = cbl / SPAN + hb;
          float* dstp = (cb < B1) ? axl : axr;
          dstp[grow * HEADS + head] = s;
        }
      }
    }
    __syncthreads();   // Cs reused next pass
  }
}

// ---------------- GATv2 edge pass: EPW edges/wave, CPL=8, clamp-free pipeline ----------------
// s = 0.6*(axl[src]+axr[dst]+ea*aWe) + 0.4*sum(att*|m|)   (exact LeakyReLU identity)

template<int HEADS, int CHAN, int EPW>
__global__ __launch_bounds__(256) void gat_edge(
    const int* __restrict__ offs, const int* __restrict__ cnt,
    const int2* __restrict__ epair,
    const u16* __restrict__ xl, const u16* __restrict__ xr,
    const float* __restrict__ att, const float* __restrict__ We,
    const float* __restrict__ cb,
    const float* __restrict__ axl, const float* __restrict__ axr,
    const float* __restrict__ aWep, u16* __restrict__ hout) {
  constexpr int HC  = HEADS * CHAN;
  constexpr int GSZ = 64 / EPW;       // lanes per edge group
  constexpr int CPL = HC / GSZ;       // channels per lane
  constexpr int LPH = CHAN / CPL;     // lanes per head cluster
  static_assert(CPL == 8, "layout");

  int node = __builtin_amdgcn_readfirstlane((int)(blockIdx.x * 4 + (threadIdx.x >> 6)));
  if (node >= NNODES) return;
  const int lane = threadIdx.x & 63;
  const int g    = lane / GSZ;
  const int lgs  = lane & (GSZ - 1);
  const int h    = lgs / LPH;
  const int cbase = lgs * CPL;

  float xrv[8], attv[8], wev[8];
  {
    uint4 xrr = *reinterpret_cast<const uint4*>(xr + (size_t)node * HC + cbase);
    dec8(xrr, xrv);
    float4 a0 = *reinterpret_cast<const float4*>(att + cbase);
    float4 a1 = *reinterpret_cast<const float4*>(att + cbase + 4);
    float4 w0 = *reinterpret_cast<const float4*>(We + cbase);
    float4 w1 = *reinterpret_cast<const float4*>(We + cbase + 4);
    attv[0]=a0.x; attv[1]=a0.y; attv[2]=a0.z; attv[3]=a0.w;
    attv[4]=a1.x; attv[5]=a1.y; attv[6]=a1.z; attv[7]=a1.w;
    wev[0]=w0.x; wev[1]=w0.y; wev[2]=w0.z; wev[3]=w0.w;
    wev[4]=w1.x; wev[5]=w1.y; wev[6]=w1.z; wev[7]=w1.w;
  }
  const float aWe = aWep[h];
  const float axr_n = axr[node * HEADS + h];
  const int off = __builtin_amdgcn_readfirstlane(offs[node]);
  const int deg = __builtin_amdgcn_readfirstlane(cnt[node]);

  float den = 0.f;
  float accv[8];
  #pragma unroll
  for (int c = 0; c < 8; ++c) accv[c] = 0.f;

  {
    const int last = deg - 1;
    const int2* pp = epair + off + g;       // lane's edge stream; over-reads land in zeroed pad
    int2 p_cur = pp[0];
    int2 p_nxt = pp[EPW];
    uint4 r_cur; float ax_cur;
    { int s = p_cur.x;
      r_cur = *reinterpret_cast<const uint4*>(xl + (size_t)s * HC + cbase);
      ax_cur = axl[s * HEADS + h]; }
    const int niter = (deg + EPW - 1) / EPW;
    for (int i = 0; i < niter; ++i) {
      int2 p_n2 = pp[(i + 2) * EPW];
      uint4 r_n; float ax_n;
      { int s = p_nxt.x;
        r_n = *reinterpret_cast<const uint4*>(xl + (size_t)s * HC + cbase);
        ax_n = axl[s * HEADS + h]; }
      float ea = __int_as_float(p_cur.y);
      float xlv[8];
      dec8(r_cur, xlv);
      float part2 = 0.f;
      #pragma unroll
      for (int c = 0; c < 8; ++c) {
        float m = xlv[c] + fmaf(ea, wev[c], xrv[c]);
        part2 = fmaf(fabsf(m), attv[c], part2);
      }
      if constexpr (LPH >= 2)  part2 += swz<0x041F>(part2);
      if constexpr (LPH >= 4)  part2 += swz<0x081F>(part2);
      if constexpr (LPH >= 8)  part2 += swz<0x101F>(part2);
      if constexpr (LPH >= 16) part2 += swz<0x201F>(part2);
      float ssum = ax_cur + fmaf(ea, aWe, axr_n);
      float sc = fmaf(0.4f, part2, 0.6f * ssum);
      float e = __expf(sc);
      e = (i * EPW + g <= last) ? e : 0.f;
      den += e;
      #pragma unroll
      for (int c = 0; c < 8; ++c) accv[c] = fmaf(e, xlv[c], accv[c]);
      p_cur = p_nxt; p_nxt = p_n2; r_cur = r_n; ax_cur = ax_n;
    }
  }
  #pragma unroll
  for (int d = GSZ; d < 64; d <<= 1) {
    den += __shfl_xor(den, d, 64);
    #pragma unroll
    for (int c = 0; c < 8; ++c) accv[c] += __shfl_xor(accv[c], d, 64);
  }
  if (g == 0) {
    float inv = 1.0f / (den + 1e-16f);
    float4 c0 = *reinterpret_cast<const float4*>(cb + cbase);
    float4 c1 = *reinterpret_cast<const float4*>(cb + cbase + 4);
    float ov[8];
    ov[0] = accv[0] * inv + c0.x; ov[1] = accv[1] * inv + c0.y;
    ov[2] = accv[2] * inv + c0.z; ov[3] = accv[3] * inv + c0.w;
    ov[4] = accv[4] * inv + c1.x; ov[5] = accv[5] * inv + c1.y;
    ov[6] = accv[6] * inv + c1.z; ov[7] = accv[7] * inv + c1.w;
    *reinterpret_cast<uint4*>(hout + (size_t)node * HC + cbase) = pack8(ov);
  }
}

// ---------------- BatchNorm ----------------

template<int NC>
__global__ void bn_stats_bf(const u16* __restrict__ h, float* __restrict__ sum, float* __restrict__ sq) {
  int c = threadIdx.x;
  float s = 0.f, q = 0.f;
  for (int r = blockIdx.x; r < NNODES; r += gridDim.x) {
    float v = bf2f(h[(size_t)r * NC + c]);
    s += v; q += v * v;
  }
  atomicAdd(&sum[c], s);
  atomicAdd(&sq[c], q);
}

__global__ __launch_bounds__(256) void final_out_k(
    const u16* __restrict__ h2, const u16* __restrict__ skip,
    const float* __restrict__ sum, const float* __restrict__ sq,
    const float* __restrict__ g, const float* __restrict__ bb_,
    const float* __restrict__ pap, float* __restrict__ outp, int total) {
  int i = (blockIdx.x * 256 + threadIdx.x) * 4;
  if (i >= total) return;
  const float invN = 1.0f / (float)NNODES;
  float pa = pap[0];
  int c = i & 127;
  float4 sm = *reinterpret_cast<const float4*>(sum + c);
  float4 qq = *reinterpret_cast<const float4*>(sq + c);
  float4 gg = *reinterpret_cast<const float4*>(g + c);
  float4 bb = *reinterpret_cast<const float4*>(bb_ + c);
  float mu, var, sc[4], sh[4];
  mu = sm.x * invN; var = qq.x * invN - mu * mu; sc[0] = gg.x * rsqrtf(var + 1e-5f); sh[0] = bb.x - mu * sc[0];
  mu = sm.y * invN; var = qq.y * invN - mu * mu; sc[1] = gg.y * rsqrtf(var + 1e-5f); sh[1] = bb.y - mu * sc[1];
  mu = sm.z * invN; var = qq.z * invN - mu * mu; sc[2] = gg.z * rsqrtf(var + 1e-5f); sh[2] = bb.z - mu * sc[2];
  mu = sm.w * invN; var = qq.w * invN - mu * mu; sc[3] = gg.w * rsqrtf(var + 1e-5f); sh[3] = bb.w - mu * sc[3];
  uint2 raw = *reinterpret_cast<const uint2*>(h2 + i);
  float v0 = bf2f(raw.x & 0xffffu), v1 = bf2f(raw.x >> 16);
  float v2 = bf2f(raw.y & 0xffffu), v3 = bf2f(raw.y >> 16);
  uint2 skr = *reinterpret_cast<const uint2*>(skip + i);
  float s0 = bf2f(skr.x & 0xffffu), s1 = bf2f(skr.x >> 16);
  float s2 = bf2f(skr.y & 0xffffu), s3 = bf2f(skr.y >> 16);
  float4 o;
  o.x = v0 * sc[0] + sh[0]; o.x = (o.x > 0.f ? o.x : pa * o.x) + s0;
  o.y = v1 * sc[1] + sh[1]; o.y = (o.y > 0.f ? o.y : pa * o.y) + s1;
  o.z = v2 * sc[2] + sh[2]; o.z = (o.z > 0.f ? o.z : pa * o.z) + s2;
  o.w = v3 * sc[3] + sh[3]; o.w = (o.w > 0.f ? o.w : pa * o.w) + s3;
  *reinterpret_cast<float4*>(outp + i) = o;
}

// ---------------- launch ----------------

extern "C" void kernel_launch(void* const* d_in, const int* in_sizes, int n_in,
                              void* d_out, int out_size, void* d_ws, size_t ws_size,
                              hipStream_t stream) {
  (void)in_sizes; (void)n_in; (void)out_size; (void)ws_size;
  const float* x    = (const float*)d_in[0];
  const int*   ei   = (const int*)d_in[1];
  const float* ea   = (const float*)d_in[2];
  const float* Wl1  = (const float*)d_in[3];
  const float* bl1  = (const float*)d_in[4];
  const float* Wr1  = (const float*)d_in[5];
  const float* br1  = (const float*)d_in[6];
  const float* We1  = (const float*)d_in[7];
  const float* att1 = (const float*)d_in[8];
  const float* cb1  = (const float*)d_in[9];
  const float* bng1 = (const float*)d_in[10];
  const float* bnb1 = (const float*)d_in[11];
  const float* pa   = (const float*)d_in[12];
  const float* Wl2  = (const float*)d_in[13];
  const float* bl2  = (const float*)d_in[14];
  const float* Wr2  = (const float*)d_in[15];
  const float* br2  = (const float*)d_in[16];
  const float* We2  = (const float*)d_in[17];
  const float* att2 = (const float*)d_in[18];
  const float* cb2  = (const float*)d_in[19];
  const float* bng2 = (const float*)d_in[20];
  const float* bnb2 = (const float*)d_in[21];
  const float* skW  = (const float*)d_in[22];
  const float* skb  = (const float*)d_in[23];
  const int* srcp = ei;
  const int* dstp = ei + NEDGES;

  char* base = (char*)d_ws;
  size_t off = 0;
  auto alloc = [&](size_t bytes) -> char* {
    char* p = base + off;
    off = (off + bytes + 255) & ~(size_t)255;
    return p;
  };
  size_t zero_ints = 1 + NNODES + 256 + 256 + 128 + 128;
  char* zbase = alloc(zero_ints * 4);
  int*   totalp = (int*)zbase;
  int*   cnt    = totalp + 1;
  float* bnsum1 = (float*)(cnt + NNODES);
  float* bnsq1  = bnsum1 + 256;
  float* bnsum2 = bnsq1 + 256;
  float* bnsq2  = bnsum2 + 128;

  int*   offs    = (int*)alloc((size_t)NNODES * 4);
  int*   rank    = (int*)alloc((size_t)NEDGES * 4);
  int2*  epair   = (int2*)alloc(((size_t)NEDGES + 256) * 8);
  const size_t RBYTES = (size_t)NNODES * DH1 * 2;  // 25.6 MB
  char* regionA = alloc(RBYTES);   // xl1(bf16) -> h2(bf16)
  char* regionB = alloc(RBYTES);   // xr1(bf16) -> xl2+xr2(bf16)
  char* regionC = alloc(RBYTES);   // h1(bf16)
  u16*   xbf    = (u16*)alloc((size_t)NNODES * 128 * 2);
  u16*   skipbf = (u16*)alloc((size_t)NNODES * 128 * 2);
  u16*   Wcat1  = (u16*)alloc(640 * 128 * 2);
  u16*   Wt2    = (u16*)alloc(256 * 256 * 2);
  float* bias1  = (float*)alloc(640 * 4);
  float* bias2  = (float*)alloc(256 * 4);
  float* axw    = (float*)alloc(8 * 4);
  float* axl1   = (float*)alloc((size_t)NNODES * 4 * 4);
  float* axr1   = (float*)alloc((size_t)NNODES * 4 * 4);
  float* axl2   = (float*)alloc((size_t)NNODES * 4);
  float* axr2   = (float*)alloc((size_t)NNODES * 4);

  u16*   xl1     = (u16*)regionA;
  u16*   xr1     = (u16*)regionB;
  u16*   h1      = (u16*)regionC;
  u16*   xl2     = (u16*)regionB;
  u16*   xr2     = (u16*)(regionB + (size_t)NNODES * DOUT * 2);
  u16*   h2      = (u16*)regionA;

  hipMemsetAsync(zbase, 0, zero_ints * 4, stream);

  const int EB = (NEDGES + 255) / 256;
  const int NB = (NNODES + 255) / 256;
  setup_k<<<CNT_BLKS + CVT_BLKS + W1_BLKS + W2_BLKS + 2, 256, 0, stream>>>(
      dstp, cnt, rank, x, xbf, Wl1, Wr1, bl1, br1, Wl2, Wr2, bl2, br2, skW, skb,
      att1, We1, att2, We2, Wcat1, bias1, Wt2, bias2, axw, epair);
  offsets_k<<<NB, 256, 0, stream>>>(cnt, offs, totalp);
  scatter_k<<<EB, 256, 0, stream>>>(srcp, dstp, ea, offs, rank, epair);

  const int MB64 = (NNODES + 63) / 64;
  // layer 1 + skip: cols [0,256)=xl1, [256,512)=xr1, [512,640)=skip
  gemm_fused<128, 5, 256, 512, 256, 256, 128, 64, 256, true, false><<<MB64, 512, 0, stream>>>(
      xbf, Wcat1, bias1, xl1, xr1, skipbf, att1, axl1, axr1,
      (const float*)0, (const float*)0, (const float*)0, (const float*)0, (const float*)0);
  gat_edge<4, 64, 2><<<(NNODES + 3) / 4, 256, 0, stream>>>(
      offs, cnt, epair, xl1, xr1, att1, We1, cb1, axl1, axr1, axw, h1);
  bn_stats_bf<256><<<800, 256, 0, stream>>>(h1, bnsum1, bnsq1);

  // layer 2 (BN1+PReLU fused into A-staging): cols [0,128)=xl2, [128,256)=xr2
  gemm_fused<256, 2, 128, 256, 128, 128, 1, 128, 128, true, true><<<MB64, 512, 0, stream>>>(
      h1, Wt2, bias2, xl2, xr2, (u16*)0, att2, axl2, axr2,
      bnsum1, bnsq1, bng1, bnb1, pa);
  gat_edge<1, 128, 4><<<(NNODES + 3) / 4, 256, 0, stream>>>(
      offs, cnt, epair, xl2, xr2, att2, We2, cb2, axl2, axr2, axw + 4, h2);
  bn_stats_bf<128><<<800, 128, 0, stream>>>(h2, bnsum2, bnsq2);
  final_out_k<<<(NNODES * DOUT / 4 + 255) / 256, 256, 0, stream>>>(
      h2, skipbf, bnsum2, bnsq2, bng2, bnb2, pa, (float*)d_out, NNODES * DOUT);
}